// Round 4
// baseline (797.788 us; speedup 1.0000x reference)
//
#include <hip/hip_runtime.h>
#include <math.h>

#define HDIM 64
#define GN_EPS 1e-5f
#define MAXNB 512          // supports N <= 131072 (bucket = 256 nodes)

__device__ __forceinline__ int lower_bound_i(const int* a, int n, int key){
  int lo = 0, hi = n;
  while (lo < hi){ int mid = (lo + hi) >> 1; if (a[mid] < key) lo = mid + 1; else hi = mid; }
  return lo;
}

// ordered-uint encoding for float atomicMax
__device__ __forceinline__ unsigned fenc(float x){
  unsigned b = __float_as_uint(x);
  return (b & 0x80000000u) ? ~b : (b | 0x80000000u);
}
__device__ __forceinline__ float fdec(unsigned u){
  unsigned b = (u & 0x80000000u) ? (u ^ 0x80000000u) : ~u;
  return __uint_as_float(b);
}

// ---------------- CSR build, pass A: bucket histogram (bucket = dst>>8) ----------
__global__ void k_bhist(const int* __restrict__ dst, int* __restrict__ bcount, int E, int NB){
  __shared__ int lh[MAXNB];
  int tid = threadIdx.x;
  for (int b = tid; b < NB; b += blockDim.x) lh[b] = 0;
  __syncthreads();
  for (int i = blockIdx.x * blockDim.x + tid; i < E; i += gridDim.x * blockDim.x)
    atomicAdd(&lh[dst[i] >> 8], 1);
  __syncthreads();
  for (int b = tid; b < NB; b += blockDim.x){ int c = lh[b]; if (c) atomicAdd(&bcount[b], c); }
}

// ---------------- pass B: scan bucket counts ----------------
__global__ void k_bscan(const int* __restrict__ bcount, int* __restrict__ bbase,
                        int* __restrict__ bcursor, int NB){
  __shared__ int sd[MAXNB];
  int tid = threadIdx.x;   // 512 threads
  int v = (tid < NB) ? bcount[tid] : 0;
  sd[tid] = v; __syncthreads();
  for (int o = 1; o < MAXNB; o <<= 1){
    int t = (tid >= o) ? sd[tid - o] : 0;
    __syncthreads();
    sd[tid] += t;
    __syncthreads();
  }
  int excl = sd[tid] - v;
  if (tid < NB){ bbase[tid] = excl; bcursor[tid] = excl; }
  if (tid == NB - 1) bbase[NB] = excl + v;
}

// ---------------- pass C: reorder edges into bucket-grouped ebuf ----------------
#define RCHUNK 8192
__global__ void k_breorder(const int* __restrict__ src, const int* __restrict__ dst,
                           int* __restrict__ bcursor, int2* __restrict__ ebuf, int E, int NB){
  __shared__ int lh[MAXNB];
  __shared__ int lbase[MAXNB];
  int tid = threadIdx.x;   // 256
  int c0 = blockIdx.x * RCHUNK;
  for (int b = tid; b < NB; b += 256) lh[b] = 0;
  __syncthreads();
  for (int j = 0; j < RCHUNK / 256; j++){
    int i = c0 + j * 256 + tid;
    if (i < E) atomicAdd(&lh[dst[i] >> 8], 1);
  }
  __syncthreads();
  for (int b = tid; b < NB; b += 256){
    int c = lh[b];
    lbase[b] = c ? atomicAdd(&bcursor[b], c) : 0;
    lh[b] = 0;
  }
  __syncthreads();
  for (int j = 0; j < RCHUNK / 256; j++){
    int i = c0 + j * 256 + tid;
    if (i < E){
      int d = dst[i]; int b = d >> 8;
      int r = atomicAdd(&lh[b], 1);
      ebuf[lbase[b] + r] = make_int2(src[i], d);
    }
  }
}

// ---------------- pass D: per-bucket counting sort -> csr/deg/offs ----------------
__global__ void k_bucket_csr(const int2* __restrict__ ebuf, const int* __restrict__ bbase,
                             int* __restrict__ deg, int* __restrict__ offs,
                             int* __restrict__ csr, int N){
  __shared__ int lh[256];
  __shared__ int lsc[256];
  int b = blockIdx.x;
  int lo = b << 8;
  int nn = min(256, N - lo);
  int tid = threadIdx.x;   // 256
  lh[tid] = 0; __syncthreads();
  int es = bbase[b], ee = bbase[b + 1];
  for (int i = es + tid; i < ee; i += 256) atomicAdd(&lh[ebuf[i].y - lo], 1);
  __syncthreads();
  int v = lh[tid];
  lsc[tid] = v; __syncthreads();
  for (int o = 1; o < 256; o <<= 1){
    int t = (tid >= o) ? lsc[tid - o] : 0;
    __syncthreads();
    lsc[tid] += t;
    __syncthreads();
  }
  int excl = lsc[tid] - v;
  if (tid < nn){ deg[lo + tid] = v; offs[lo + tid] = es + excl; }
  __syncthreads();
  lh[tid] = es + excl;     // reuse as cursor
  __syncthreads();
  for (int i = es + tid; i < ee; i += 256){
    int2 e = ebuf[i];
    int pos = atomicAdd(&lh[e.y - lo], 1);
    csr[pos] = e.x;
  }
}

// graph start offsets (batch is sorted)
__global__ void k_gstart(const int* __restrict__ batch, int n, int* __restrict__ gs, int B){
  int g = blockIdx.x * blockDim.x + threadIdx.x;
  if (g <= B) gs[g] = lower_bound_i(batch, n, g);
}

// ================= fused layer: agg -> mlp -> GN stats =================
// 64-node tile per 256-thread block. As[k][node] transposed LDS tile, pitch 68.
__global__ __launch_bounds__(256, 3) void k_layer(
    const float* __restrict__ P, const int* __restrict__ csr,
    const int* __restrict__ offs, const int* __restrict__ deg,
    const int* __restrict__ batch,
    const float* __restrict__ W1, const float* __restrict__ B1,
    const float* __restrict__ W2, const float* __restrict__ B2,
    float* __restrict__ Y, float* __restrict__ stats, int N){
  __shared__ float As[64 * 68];    // 17.0 KiB
  __shared__ float W1s[64 * 64];   // 16 KiB
  __shared__ float W2s[64 * 64];   // 16 KiB
  int tid = threadIdx.x;
  int t0 = blockIdx.x << 6;

  // stage weights (once per block)
  for (int i = tid; i < 1024; i += 256){
    ((float4*)W1s)[i] = ((const float4*)W1)[i];
    ((float4*)W2s)[i] = ((const float4*)W2)[i];
  }

  // ---- stage 1: GIN aggregation, wave per 16 nodes, lane = input feature ----
  int lane = tid & 63;
  int w = tid >> 6;
  for (int i = 0; i < 16; ++i){
    int nl = (w << 4) + i;
    int node = t0 + nl;
    float val = 0.f;
    if (node < N){
      int st = offs[node], cnt = deg[node];
      float a0 = P[(size_t)node * HDIM + lane], a1 = 0.f, a2 = 0.f, a3 = 0.f;
      for (int base = 0; base < cnt; base += 64){
        int rem = cnt - base;
        int s = (lane < rem) ? csr[st + base + lane] : 0;
        int m = min(rem, 64);
        int j = 0;
        for (; j + 4 <= m; j += 4){
          int s0 = __shfl(s, j), s1 = __shfl(s, j + 1);
          int s2 = __shfl(s, j + 2), s3 = __shfl(s, j + 3);
          a0 += P[(size_t)s0 * HDIM + lane];
          a1 += P[(size_t)s1 * HDIM + lane];
          a2 += P[(size_t)s2 * HDIM + lane];
          a3 += P[(size_t)s3 * HDIM + lane];
        }
        for (; j < m; ++j){ int sj = __shfl(s, j); a0 += P[(size_t)sj * HDIM + lane]; }
      }
      val = (a0 + a1) + (a2 + a3);
    }
    As[lane * 68 + nl] = val;
  }
  __syncthreads();

  // ---- stage 2: GEMM1, thread = 4 nodes x 4 feats ----
  int f0 = (tid & 15) << 2;
  int n0 = (tid >> 4) << 2;
  float t[4][4];
  {
    float4 b1v = *(const float4*)(B1 + f0);
    #pragma unroll
    for (int i = 0; i < 4; i++){ t[i][0] = b1v.x; t[i][1] = b1v.y; t[i][2] = b1v.z; t[i][3] = b1v.w; }
  }
  #pragma unroll 8
  for (int k = 0; k < 64; ++k){
    float4 a = *(const float4*)(As + k * 68 + n0);
    float4 b = *(const float4*)(W1s + k * 64 + f0);
    float av[4] = {a.x, a.y, a.z, a.w};
    float bv[4] = {b.x, b.y, b.z, b.w};
    #pragma unroll
    for (int i = 0; i < 4; i++)
      #pragma unroll
      for (int j = 0; j < 4; j++) t[i][j] += av[i] * bv[j];
  }
  __syncthreads();
  // relu + transpose back into As (reused): As[f][node]
  #pragma unroll
  for (int j = 0; j < 4; ++j){
    float4 v = make_float4(fmaxf(t[0][j], 0.f), fmaxf(t[1][j], 0.f),
                           fmaxf(t[2][j], 0.f), fmaxf(t[3][j], 0.f));
    *(float4*)(As + (f0 + j) * 68 + n0) = v;
  }
  __syncthreads();

  // ---- stage 3: GEMM2 ----
  float o[4][4];
  {
    float4 b2v = *(const float4*)(B2 + f0);
    #pragma unroll
    for (int i = 0; i < 4; i++){ o[i][0] = b2v.x; o[i][1] = b2v.y; o[i][2] = b2v.z; o[i][3] = b2v.w; }
  }
  #pragma unroll 8
  for (int k = 0; k < 64; ++k){
    float4 a = *(const float4*)(As + k * 68 + n0);
    float4 b = *(const float4*)(W2s + k * 64 + f0);
    float av[4] = {a.x, a.y, a.z, a.w};
    float bv[4] = {b.x, b.y, b.z, b.w};
    #pragma unroll
    for (int i = 0; i < 4; i++)
      #pragma unroll
      for (int j = 0; j < 4; j++) o[i][j] += av[i] * bv[j];
  }

  // ---- write Y ----
  #pragma unroll
  for (int i = 0; i < 4; ++i){
    int node = t0 + n0 + i;
    if (node < N)
      *(float4*)(Y + (size_t)node * HDIM + f0) = make_float4(o[i][0], o[i][1], o[i][2], o[i][3]);
  }

  // ---- stats epilogue: per-graph sum / sumsq of Y ----
  int lastn = min(t0 + 63, N - 1);
  int g0 = batch[t0];
  int g1 = batch[lastn];
  __syncthreads();   // all GEMM2 reads of As done
  if (g0 == g1 && t0 + 63 < N){
    if (tid < 128) As[tid] = 0.f;
    __syncthreads();
    #pragma unroll
    for (int j = 0; j < 4; j++){
      float s  = o[0][j] + o[1][j] + o[2][j] + o[3][j];
      float s2 = o[0][j]*o[0][j] + o[1][j]*o[1][j] + o[2][j]*o[2][j] + o[3][j]*o[3][j];
      atomicAdd(&As[f0 + j], s);
      atomicAdd(&As[64 + f0 + j], s2);
    }
    __syncthreads();
    if (tid < 64){
      atomicAdd(&stats[g0 * 128 + tid], As[tid]);
      atomicAdd(&stats[g0 * 128 + 64 + tid], As[64 + tid]);
    }
  } else {
    #pragma unroll
    for (int i = 0; i < 4; i++){
      int node = t0 + n0 + i;
      if (node < N){
        int g = batch[node];
        #pragma unroll
        for (int j = 0; j < 4; j++){
          atomicAdd(&stats[g * 128 + f0 + j], o[i][j]);
          atomicAdd(&stats[g * 128 + 64 + f0 + j], o[i][j] * o[i][j]);
        }
      }
    }
  }
}

// ---------------- GraphNorm finalize: mean*ms and scale ----------------
__global__ void k_gn_finalize(const float* __restrict__ stats, const int* __restrict__ gs,
                              const float* __restrict__ w, const float* __restrict__ ms,
                              float* __restrict__ meanms, float* __restrict__ scale, int B){
  int i = blockIdx.x * blockDim.x + threadIdx.x;
  if (i >= B * 64) return;
  int g = i >> 6, f = i & 63;
  float cnt = (float)max(gs[g + 1] - gs[g], 1);
  float mean = stats[g * 128 + f] / cnt;
  float ex2  = stats[g * 128 + 64 + f] / cnt;
  float msv = ms[f];
  float var = ex2 - (2.f * msv - msv * msv) * mean * mean;
  meanms[i] = msv * mean;
  scale[i] = rsqrtf(var + GN_EPS) * w[f];
}

// ---------------- GraphNorm apply + relu + residual accumulate ----------
__global__ void k_gn_apply(const float* __restrict__ Y, const int* __restrict__ batch,
                           const float* __restrict__ meanms, const float* __restrict__ scale,
                           const float* __restrict__ bias,
                           float* __restrict__ C, float* __restrict__ hsum, int n16,
                           int first, int writeC){
  int i = blockIdx.x * blockDim.x + threadIdx.x;
  if (i >= n16) return;
  int node = i >> 4, q = i & 15;
  int g = batch[node];
  float4 y = ((const float4*)Y)[i];
  float4 m = ((const float4*)(meanms + g * 64))[q];
  float4 s = ((const float4*)(scale  + g * 64))[q];
  float4 b = ((const float4*)bias)[q];
  float4 v;
  v.x = fmaxf((y.x - m.x) * s.x + b.x, 0.f);
  v.y = fmaxf((y.y - m.y) * s.y + b.y, 0.f);
  v.z = fmaxf((y.z - m.z) * s.z + b.z, 0.f);
  v.w = fmaxf((y.w - m.w) * s.w + b.w, 0.f);
  if (writeC) ((float4*)C)[i] = v;
  if (first){
    ((float4*)hsum)[i] = v;
  } else {
    float4 h = ((float4*)hsum)[i];
    h.x += v.x; h.y += v.y; h.z += v.z; h.w += v.w;
    ((float4*)hsum)[i] = h;
  }
}

// ---------------- pooling pass 1 ----------------
#define GN_NPW 32
__global__ void k_pool1(const float* __restrict__ HS, const int* __restrict__ batch,
                        const float* __restrict__ GW, const float* __restrict__ GB,
                        float* __restrict__ sumbuf, unsigned* __restrict__ maxbuf,
                        float* __restrict__ gatebuf, unsigned* __restrict__ gmaxbuf, int n){
  int wave = (int)((blockIdx.x * blockDim.x + threadIdx.x) >> 6);
  int lane = threadIdx.x & 63;
  int s = wave * GN_NPW;
  if (s >= n) return;
  int e = min(s + GN_NPW, n);
  float gwv = GW[lane];
  float gb = GB[0];
  int cur = batch[s];
  float macc = 0.f, xacc = -INFINITY, gmx = -INFINITY;
  for (int nd = s; nd < e; ++nd){
    int g = batch[nd];
    if (g != cur){
      atomicAdd(&sumbuf[cur * 64 + lane], macc);
      atomicMax(&maxbuf[cur * 64 + lane], fenc(xacc));
      if (lane == 0) atomicMax(&gmaxbuf[cur], fenc(gmx));
      macc = 0.f; xacc = -INFINITY; gmx = -INFINITY; cur = g;
    }
    float hv = HS[(size_t)nd * HDIM + lane];
    macc += hv; xacc = fmaxf(xacc, hv);
    float gv = hv * gwv;
    #pragma unroll
    for (int msk = 1; msk < 64; msk <<= 1) gv += __shfl_xor(gv, msk);
    gv += gb;
    if (lane == 0) gatebuf[nd] = gv;
    gmx = fmaxf(gmx, gv);
  }
  atomicAdd(&sumbuf[cur * 64 + lane], macc);
  atomicMax(&maxbuf[cur * 64 + lane], fenc(xacc));
  if (lane == 0) atomicMax(&gmaxbuf[cur], fenc(gmx));
}

// ---------------- pooling pass 2 ----------------
__global__ void k_pool2(const float* __restrict__ HS, const int* __restrict__ batch,
                        const float* __restrict__ gatebuf, const unsigned* __restrict__ gmaxbuf,
                        float* __restrict__ attbuf, float* __restrict__ denbuf, int n){
  int wave = (int)((blockIdx.x * blockDim.x + threadIdx.x) >> 6);
  int lane = threadIdx.x & 63;
  int s = wave * GN_NPW;
  if (s >= n) return;
  int e = min(s + GN_NPW, n);
  int cur = batch[s];
  float m = fdec(gmaxbuf[cur]);
  float aacc = 0.f, dacc = 0.f;
  for (int nd = s; nd < e; ++nd){
    int g = batch[nd];
    if (g != cur){
      atomicAdd(&attbuf[cur * 64 + lane], aacc);
      if (lane == 0) atomicAdd(&denbuf[cur], dacc);
      aacc = 0.f; dacc = 0.f; cur = g; m = fdec(gmaxbuf[cur]);
    }
    float ex = expf(gatebuf[nd] - m);
    float hv = HS[(size_t)nd * HDIM + lane];
    aacc += ex * hv; dacc += ex;
  }
  atomicAdd(&attbuf[cur * 64 + lane], aacc);
  if (lane == 0) atomicAdd(&denbuf[cur], dacc);
}

// ---------------- pooling pass 3 ----------------
__global__ void k_pool3(const float* __restrict__ attbuf, const float* __restrict__ denbuf,
                        const float* __restrict__ sumbuf, const unsigned* __restrict__ maxbuf,
                        const int* __restrict__ gs, const float* __restrict__ U,
                        const float* __restrict__ HW1, const float* __restrict__ HB1,
                        const float* __restrict__ HW2, const float* __restrict__ HB2,
                        float* __restrict__ out){
  __shared__ float z[200];
  int g = blockIdx.x;
  int tid = threadIdx.x;   // 64 threads
  float cnt = (float)max(gs[g + 1] - gs[g], 1);
  float den = denbuf[g];
  z[tid]       = attbuf[g * 64 + tid] / den;
  z[64 + tid]  = sumbuf[g * 64 + tid] / cnt;
  z[128 + tid] = fdec(maxbuf[g * 64 + tid]);
  if (tid < 3) z[192 + tid] = U[g * 3 + tid];
  __syncthreads();
  float acc = HB1[tid];
  for (int k = 0; k < 195; k++) acc += z[k] * HW1[k * 64 + tid];
  float sv = fmaxf(acc, 0.f) * HW2[tid];
  #pragma unroll
  for (int msk = 1; msk < 64; msk <<= 1) sv += __shfl_xor(sv, msk);
  if (tid == 0) out[g] = sv + HB2[0];
}

extern "C" void kernel_launch(void* const* d_in, const int* in_sizes, int n_in,
                              void* d_out, int out_size, void* d_ws, size_t ws_size,
                              hipStream_t stream){
  const float* x     = (const float*)d_in[0];
  const int*   ei    = (const int*)d_in[1];
  const int*   batch = (const int*)d_in[2];
  const float* u     = (const float*)d_in[3];
  const float* W[3][4]; const float* GNp[3][3];
  for (int l = 0; l < 3; l++){
    int base = 4 + l * 7;
    W[l][0]  = (const float*)d_in[base + 0];
    W[l][1]  = (const float*)d_in[base + 1];
    W[l][2]  = (const float*)d_in[base + 2];
    W[l][3]  = (const float*)d_in[base + 3];
    GNp[l][0]= (const float*)d_in[base + 4];
    GNp[l][1]= (const float*)d_in[base + 5];
    GNp[l][2]= (const float*)d_in[base + 6];
  }
  const float* gate_w = (const float*)d_in[25];
  const float* gate_b = (const float*)d_in[26];
  const float* hw1    = (const float*)d_in[27];
  const float* hb1    = (const float*)d_in[28];
  const float* hw2    = (const float*)d_in[29];
  const float* hb2    = (const float*)d_in[30];
  float* out = (float*)d_out;

  int N = in_sizes[0] / HDIM;
  int E = in_sizes[1] / 2;
  int B = in_sizes[3] / 3;
  const int* src = ei;
  const int* dst = ei + E;
  int NB = (N + 255) >> 8;     // <= MAXNB for N <= 131072

  char* w8 = (char*)d_ws;
  size_t NH = (size_t)N * HDIM * sizeof(float);
  auto alignup = [](size_t v){ return (v + 255) & ~(size_t)255; };
  size_t off = 0;
  float* hsum    = (float*)(w8 + off); off += alignup(NH);
  float* bufA    = (float*)(w8 + off); off += alignup(NH);
  float* bufB    = (float*)(w8 + off); off += alignup(NH);
  float* G       = (float*)(w8 + off); off += alignup(NH);
  float* gatebuf = (float*)(w8 + off); off += alignup((size_t)N * 4);
  int*   deg     = (int*)(w8 + off);   off += alignup((size_t)N * 4);
  int*   offs    = (int*)(w8 + off);   off += alignup((size_t)N * 4);
  int*   csr     = (int*)(w8 + off);   off += alignup((size_t)E * 4);
  int2*  ebuf    = (int2*)(w8 + off);  off += alignup((size_t)E * 8);
  int*   bcount  = (int*)(w8 + off);   off += alignup((size_t)(MAXNB + 1) * 4);
  int*   bbase   = (int*)(w8 + off);   off += alignup((size_t)(MAXNB + 1) * 4);
  int*   bcursor = (int*)(w8 + off);   off += alignup((size_t)(MAXNB + 1) * 4);
  float* stats   = (float*)(w8 + off); off += alignup((size_t)B * 128 * 4);
  float* meanms  = (float*)(w8 + off); off += alignup((size_t)B * 64 * 4);
  float* scale   = (float*)(w8 + off); off += alignup((size_t)B * 64 * 4);
  float* sumbuf  = (float*)(w8 + off); off += alignup((size_t)B * 64 * 4);
  unsigned* maxbuf = (unsigned*)(w8 + off); off += alignup((size_t)B * 64 * 4);
  float* attbuf  = (float*)(w8 + off); off += alignup((size_t)B * 64 * 4);
  float* denbuf  = (float*)(w8 + off); off += alignup((size_t)B * 4);
  unsigned* gmaxbuf = (unsigned*)(w8 + off); off += alignup((size_t)B * 4);
  int*   gs      = (int*)(w8 + off);   off += alignup((size_t)(B + 1) * 4);
  (void)ws_size; (void)n_in; (void)out_size;

  hipMemsetAsync(bcount, 0, (size_t)(MAXNB + 1) * 4, stream);
  hipMemsetAsync(sumbuf, 0, (size_t)B * 64 * 4, stream);
  hipMemsetAsync(maxbuf, 0, (size_t)B * 64 * 4, stream);   // 0 == below all reals in fenc order
  hipMemsetAsync(attbuf, 0, (size_t)B * 64 * 4, stream);
  hipMemsetAsync(denbuf, 0, (size_t)B * 4, stream);
  hipMemsetAsync(gmaxbuf, 0, (size_t)B * 4, stream);

  const int tb = 256;
  k_bhist<<<256, tb, 0, stream>>>(dst, bcount, E, NB);
  k_bscan<<<1, MAXNB, 0, stream>>>(bcount, bbase, bcursor, NB);
  k_breorder<<<(E + RCHUNK - 1) / RCHUNK, tb, 0, stream>>>(src, dst, bcursor, ebuf, E, NB);
  k_bucket_csr<<<NB, tb, 0, stream>>>(ebuf, bbase, deg, offs, csr, N);
  k_gstart<<<1, 256, 0, stream>>>(batch, N, gs, B);

  int nwaves = (N + GN_NPW - 1) / GN_NPW;
  int segblocks = (nwaves * 64 + tb - 1) / tb;
  int n16 = N * 16;
  int nblk64 = (N + 63) >> 6;

  const float* P = x;
  float* C = bufA;
  for (int l = 0; l < 3; l++){
    hipMemsetAsync(stats, 0, (size_t)B * 128 * 4, stream);
    k_layer<<<nblk64, 256, 0, stream>>>(P, csr, offs, deg, batch,
                                        W[l][0], W[l][1], W[l][2], W[l][3],
                                        G, stats, N);
    k_gn_finalize<<<(B * 64 + tb - 1) / tb, tb, 0, stream>>>(stats, gs, GNp[l][0], GNp[l][2],
                                                             meanms, scale, B);
    k_gn_apply<<<(n16 + tb - 1) / tb, tb, 0, stream>>>(G, batch, meanms, scale, GNp[l][1],
                                                       C, hsum, n16, l == 0 ? 1 : 0,
                                                       l == 2 ? 0 : 1);
    P = C;
    C = (l == 0) ? bufB : bufA;
  }
  k_pool1<<<segblocks, tb, 0, stream>>>(hsum, batch, gate_w, gate_b,
                                        sumbuf, maxbuf, gatebuf, gmaxbuf, N);
  k_pool2<<<segblocks, tb, 0, stream>>>(hsum, batch, gatebuf, gmaxbuf, attbuf, denbuf, N);
  k_pool3<<<B, 64, 0, stream>>>(attbuf, denbuf, sumbuf, maxbuf, gs, u,
                                hw1, hb1, hw2, hb2, out);
}

// Round 5
// 657.766 us; speedup vs baseline: 1.2129x; 1.2129x over previous
//
#include <hip/hip_runtime.h>
#include <math.h>

#define HDIM 64
#define GN_EPS 1e-5f
#define MAXNB 512          // supports N <= 131072 (bucket = 256 nodes)

__device__ __forceinline__ int lower_bound_i(const int* a, int n, int key){
  int lo = 0, hi = n;
  while (lo < hi){ int mid = (lo + hi) >> 1; if (a[mid] < key) lo = mid + 1; else hi = mid; }
  return lo;
}

// ordered-uint encoding for float atomicMax
__device__ __forceinline__ unsigned fenc(float x){
  unsigned b = __float_as_uint(x);
  return (b & 0x80000000u) ? ~b : (b | 0x80000000u);
}
__device__ __forceinline__ float fdec(unsigned u){
  unsigned b = (u & 0x80000000u) ? (u ^ 0x80000000u) : ~u;
  return __uint_as_float(b);
}

// ---------------- CSR build, pass A: bucket histogram (bucket = dst>>8) ----------
__global__ void k_bhist(const int* __restrict__ dst, int* __restrict__ bcount, int E, int NB){
  __shared__ int lh[MAXNB];
  int tid = threadIdx.x;
  for (int b = tid; b < NB; b += blockDim.x) lh[b] = 0;
  __syncthreads();
  for (int i = blockIdx.x * blockDim.x + tid; i < E; i += gridDim.x * blockDim.x)
    atomicAdd(&lh[dst[i] >> 8], 1);
  __syncthreads();
  for (int b = tid; b < NB; b += blockDim.x){ int c = lh[b]; if (c) atomicAdd(&bcount[b], c); }
}

// ---------------- pass B: scan bucket counts ----------------
__global__ void k_bscan(const int* __restrict__ bcount, int* __restrict__ bbase,
                        int* __restrict__ bcursor, int NB){
  __shared__ int sd[MAXNB];
  int tid = threadIdx.x;   // 512 threads
  int v = (tid < NB) ? bcount[tid] : 0;
  sd[tid] = v; __syncthreads();
  for (int o = 1; o < MAXNB; o <<= 1){
    int t = (tid >= o) ? sd[tid - o] : 0;
    __syncthreads();
    sd[tid] += t;
    __syncthreads();
  }
  int excl = sd[tid] - v;
  if (tid < NB){ bbase[tid] = excl; bcursor[tid] = excl; }
  if (tid == NB - 1) bbase[NB] = excl + v;
}

// ---------------- pass C: reorder edges into bucket-grouped ebuf ----------------
#define RCHUNK 8192
__global__ void k_breorder(const int* __restrict__ src, const int* __restrict__ dst,
                           int* __restrict__ bcursor, int2* __restrict__ ebuf, int E, int NB){
  __shared__ int lh[MAXNB];
  __shared__ int lbase[MAXNB];
  int tid = threadIdx.x;   // 256
  int c0 = blockIdx.x * RCHUNK;
  for (int b = tid; b < NB; b += 256) lh[b] = 0;
  __syncthreads();
  for (int j = 0; j < RCHUNK / 256; j++){
    int i = c0 + j * 256 + tid;
    if (i < E) atomicAdd(&lh[dst[i] >> 8], 1);
  }
  __syncthreads();
  for (int b = tid; b < NB; b += 256){
    int c = lh[b];
    lbase[b] = c ? atomicAdd(&bcursor[b], c) : 0;
    lh[b] = 0;
  }
  __syncthreads();
  for (int j = 0; j < RCHUNK / 256; j++){
    int i = c0 + j * 256 + tid;
    if (i < E){
      int d = dst[i]; int b = d >> 8;
      int r = atomicAdd(&lh[b], 1);
      ebuf[lbase[b] + r] = make_int2(src[i], d);
    }
  }
}

// ---------------- pass D: per-bucket counting sort -> csr/deg/offs ----------------
__global__ void k_bucket_csr(const int2* __restrict__ ebuf, const int* __restrict__ bbase,
                             int* __restrict__ deg, int* __restrict__ offs,
                             int* __restrict__ csr, int N){
  __shared__ int lh[256];
  __shared__ int lsc[256];
  int b = blockIdx.x;
  int lo = b << 8;
  int nn = min(256, N - lo);
  int tid = threadIdx.x;   // 256
  lh[tid] = 0; __syncthreads();
  int es = bbase[b], ee = bbase[b + 1];
  for (int i = es + tid; i < ee; i += 256) atomicAdd(&lh[ebuf[i].y - lo], 1);
  __syncthreads();
  int v = lh[tid];
  lsc[tid] = v; __syncthreads();
  for (int o = 1; o < 256; o <<= 1){
    int t = (tid >= o) ? lsc[tid - o] : 0;
    __syncthreads();
    lsc[tid] += t;
    __syncthreads();
  }
  int excl = lsc[tid] - v;
  if (tid < nn){ deg[lo + tid] = v; offs[lo + tid] = es + excl; }
  __syncthreads();
  lh[tid] = es + excl;     // reuse as cursor
  __syncthreads();
  for (int i = es + tid; i < ee; i += 256){
    int2 e = ebuf[i];
    int pos = atomicAdd(&lh[e.y - lo], 1);
    csr[pos] = e.x;
  }
}

// graph start offsets (batch is sorted)
__global__ void k_gstart(const int* __restrict__ batch, int n, int* __restrict__ gs, int B){
  int g = blockIdx.x * blockDim.x + threadIdx.x;
  if (g <= B) gs[g] = lower_bound_i(batch, n, g);
}

// ---------------- GIN aggregation: G[n] = P[n] + sum_{e->n} P[src] ----------------
__global__ void k_agg(const float* __restrict__ P, const int* __restrict__ csr,
                      const int* __restrict__ offs, const int* __restrict__ deg,
                      float* __restrict__ G, int n){
  int gi = blockIdx.x * blockDim.x + threadIdx.x;
  int node = gi >> 6;
  int lane = gi & 63;
  if (node >= n) return;
  int st = offs[node], cnt = deg[node];
  float self = P[(size_t)node * HDIM + lane];
  float a0 = 0.f, a1 = 0.f, a2 = 0.f, a3 = 0.f;
  for (int base = 0; base < cnt; base += 64){
    int rem = cnt - base;
    int s = (lane < rem) ? csr[st + base + lane] : 0;
    int m = min(rem, 64);
    int j = 0;
    for (; j + 4 <= m; j += 4){
      int s0 = __shfl(s, j), s1 = __shfl(s, j + 1), s2 = __shfl(s, j + 2), s3 = __shfl(s, j + 3);
      a0 += P[(size_t)s0 * HDIM + lane];
      a1 += P[(size_t)s1 * HDIM + lane];
      a2 += P[(size_t)s2 * HDIM + lane];
      a3 += P[(size_t)s3 * HDIM + lane];
    }
    for (; j < m; ++j){ int sj = __shfl(s, j); a0 += P[(size_t)sj * HDIM + lane]; }
  }
  G[(size_t)node * HDIM + lane] = self + ((a0 + a1) + (a2 + a3));
}

// ======== GIN MLP (tiled, in-place) + fused GraphNorm stats epilogue ========
// 64-node tile per 256-thread block. As: [node][feat] pitch 68 (bank-balanced).
__global__ __launch_bounds__(256, 6) void k_mlp(
    float* __restrict__ G, const int* __restrict__ batch,
    const float* __restrict__ W1, const float* __restrict__ B1,
    const float* __restrict__ W2, const float* __restrict__ B2,
    float* __restrict__ stats, int N){
  __shared__ float As[64 * 68];    // 17.0 KiB
  int tid = threadIdx.x;
  int t0 = blockIdx.x << 6;

  // ---- load tile (coalesced float4), store node-major ----
  #pragma unroll
  for (int r = 0; r < 4; r++){
    int idx = r * 256 + tid;       // 0..1023
    int node = idx >> 4;
    int f4 = idx & 15;
    int gn = t0 + node;
    float4 v = make_float4(0.f, 0.f, 0.f, 0.f);
    if (gn < N) v = ((const float4*)G)[(size_t)gn * 16 + f4];
    *(float4*)(As + node * 68 + f4 * 4) = v;
  }
  __syncthreads();

  int f0 = (tid & 15) << 2;
  int n0 = (tid >> 4) << 2;

  // ---- GEMM1: t[i][j] = sum_k As[n0+i][k] * W1[k][f0+j] ----
  float t[4][4];
  {
    float4 b1v = *(const float4*)(B1 + f0);
    #pragma unroll
    for (int i = 0; i < 4; i++){ t[i][0] = b1v.x; t[i][1] = b1v.y; t[i][2] = b1v.z; t[i][3] = b1v.w; }
  }
  #pragma unroll 8
  for (int k = 0; k < 64; ++k){
    float4 b = *(const float4*)(W1 + k * 64 + f0);
    float bv[4] = {b.x, b.y, b.z, b.w};
    float av[4] = {As[(n0 + 0) * 68 + k], As[(n0 + 1) * 68 + k],
                   As[(n0 + 2) * 68 + k], As[(n0 + 3) * 68 + k]};
    #pragma unroll
    for (int i = 0; i < 4; i++)
      #pragma unroll
      for (int j = 0; j < 4; j++) t[i][j] += av[i] * bv[j];
  }
  __syncthreads();
  // relu, write back node-major (float4 row per i)
  #pragma unroll
  for (int i = 0; i < 4; ++i)
    *(float4*)(As + (n0 + i) * 68 + f0) =
        make_float4(fmaxf(t[i][0], 0.f), fmaxf(t[i][1], 0.f),
                    fmaxf(t[i][2], 0.f), fmaxf(t[i][3], 0.f));
  __syncthreads();

  // ---- GEMM2 ----
  float o[4][4];
  {
    float4 b2v = *(const float4*)(B2 + f0);
    #pragma unroll
    for (int i = 0; i < 4; i++){ o[i][0] = b2v.x; o[i][1] = b2v.y; o[i][2] = b2v.z; o[i][3] = b2v.w; }
  }
  #pragma unroll 8
  for (int k = 0; k < 64; ++k){
    float4 b = *(const float4*)(W2 + k * 64 + f0);
    float bv[4] = {b.x, b.y, b.z, b.w};
    float av[4] = {As[(n0 + 0) * 68 + k], As[(n0 + 1) * 68 + k],
                   As[(n0 + 2) * 68 + k], As[(n0 + 3) * 68 + k]};
    #pragma unroll
    for (int i = 0; i < 4; i++)
      #pragma unroll
      for (int j = 0; j < 4; j++) o[i][j] += av[i] * bv[j];
  }

  // ---- write Y (in place) ----
  #pragma unroll
  for (int i = 0; i < 4; ++i){
    int node = t0 + n0 + i;
    if (node < N)
      *(float4*)(G + (size_t)node * HDIM + f0) = make_float4(o[i][0], o[i][1], o[i][2], o[i][3]);
  }

  // ---- stats epilogue: per-graph sum / sumsq ----
  int lastn = min(t0 + 63, N - 1);
  int g0 = batch[t0];
  int g1 = batch[lastn];
  __syncthreads();   // all GEMM2 reads of As done
  if (g0 == g1 && t0 + 63 < N){
    if (tid < 128) As[tid] = 0.f;
    __syncthreads();
    #pragma unroll
    for (int j = 0; j < 4; j++){
      float s  = o[0][j] + o[1][j] + o[2][j] + o[3][j];
      float s2 = o[0][j]*o[0][j] + o[1][j]*o[1][j] + o[2][j]*o[2][j] + o[3][j]*o[3][j];
      atomicAdd(&As[f0 + j], s);
      atomicAdd(&As[64 + f0 + j], s2);
    }
    __syncthreads();
    if (tid < 64){
      atomicAdd(&stats[g0 * 128 + tid], As[tid]);
      atomicAdd(&stats[g0 * 128 + 64 + tid], As[64 + tid]);
    }
  } else {
    #pragma unroll
    for (int i = 0; i < 4; i++){
      int node = t0 + n0 + i;
      if (node < N){
        int g = batch[node];
        #pragma unroll
        for (int j = 0; j < 4; j++){
          atomicAdd(&stats[g * 128 + f0 + j], o[i][j]);
          atomicAdd(&stats[g * 128 + 64 + f0 + j], o[i][j] * o[i][j]);
        }
      }
    }
  }
}

// ---------------- GraphNorm finalize: mean*ms and scale ----------------
__global__ void k_gn_finalize(const float* __restrict__ stats, const int* __restrict__ gs,
                              const float* __restrict__ w, const float* __restrict__ ms,
                              float* __restrict__ meanms, float* __restrict__ scale, int B){
  int i = blockIdx.x * blockDim.x + threadIdx.x;
  if (i >= B * 64) return;
  int g = i >> 6, f = i & 63;
  float cnt = (float)max(gs[g + 1] - gs[g], 1);
  float mean = stats[g * 128 + f] / cnt;
  float ex2  = stats[g * 128 + 64 + f] / cnt;
  float msv = ms[f];
  float var = ex2 - (2.f * msv - msv * msv) * mean * mean;
  meanms[i] = msv * mean;
  scale[i] = rsqrtf(var + GN_EPS) * w[f];
}

// ---------------- GraphNorm apply + relu + residual accumulate ----------
__global__ void k_gn_apply(const float* __restrict__ Y, const int* __restrict__ batch,
                           const float* __restrict__ meanms, const float* __restrict__ scale,
                           const float* __restrict__ bias,
                           float* __restrict__ C, float* __restrict__ hsum, int n16,
                           int first, int writeC){
  int i = blockIdx.x * blockDim.x + threadIdx.x;
  if (i >= n16) return;
  int node = i >> 4, q = i & 15;
  int g = batch[node];
  float4 y = ((const float4*)Y)[i];
  float4 m = ((const float4*)(meanms + g * 64))[q];
  float4 s = ((const float4*)(scale  + g * 64))[q];
  float4 b = ((const float4*)bias)[q];
  float4 v;
  v.x = fmaxf((y.x - m.x) * s.x + b.x, 0.f);
  v.y = fmaxf((y.y - m.y) * s.y + b.y, 0.f);
  v.z = fmaxf((y.z - m.z) * s.z + b.z, 0.f);
  v.w = fmaxf((y.w - m.w) * s.w + b.w, 0.f);
  if (writeC) ((float4*)C)[i] = v;
  if (first){
    ((float4*)hsum)[i] = v;
  } else {
    float4 h = ((float4*)hsum)[i];
    h.x += v.x; h.y += v.y; h.z += v.z; h.w += v.w;
    ((float4*)hsum)[i] = h;
  }
}

// ---------------- pooling pass 1 ----------------
#define GN_NPW 32
__global__ void k_pool1(const float* __restrict__ HS, const int* __restrict__ batch,
                        const float* __restrict__ GW, const float* __restrict__ GB,
                        float* __restrict__ sumbuf, unsigned* __restrict__ maxbuf,
                        float* __restrict__ gatebuf, unsigned* __restrict__ gmaxbuf, int n){
  int wave = (int)((blockIdx.x * blockDim.x + threadIdx.x) >> 6);
  int lane = threadIdx.x & 63;
  int s = wave * GN_NPW;
  if (s >= n) return;
  int e = min(s + GN_NPW, n);
  float gwv = GW[lane];
  float gb = GB[0];
  int cur = batch[s];
  float macc = 0.f, xacc = -INFINITY, gmx = -INFINITY;
  for (int nd = s; nd < e; ++nd){
    int g = batch[nd];
    if (g != cur){
      atomicAdd(&sumbuf[cur * 64 + lane], macc);
      atomicMax(&maxbuf[cur * 64 + lane], fenc(xacc));
      if (lane == 0) atomicMax(&gmaxbuf[cur], fenc(gmx));
      macc = 0.f; xacc = -INFINITY; gmx = -INFINITY; cur = g;
    }
    float hv = HS[(size_t)nd * HDIM + lane];
    macc += hv; xacc = fmaxf(xacc, hv);
    float gv = hv * gwv;
    #pragma unroll
    for (int msk = 1; msk < 64; msk <<= 1) gv += __shfl_xor(gv, msk);
    gv += gb;
    if (lane == 0) gatebuf[nd] = gv;
    gmx = fmaxf(gmx, gv);
  }
  atomicAdd(&sumbuf[cur * 64 + lane], macc);
  atomicMax(&maxbuf[cur * 64 + lane], fenc(xacc));
  if (lane == 0) atomicMax(&gmaxbuf[cur], fenc(gmx));
}

// ---------------- pooling pass 2 ----------------
__global__ void k_pool2(const float* __restrict__ HS, const int* __restrict__ batch,
                        const float* __restrict__ gatebuf, const unsigned* __restrict__ gmaxbuf,
                        float* __restrict__ attbuf, float* __restrict__ denbuf, int n){
  int wave = (int)((blockIdx.x * blockDim.x + threadIdx.x) >> 6);
  int lane = threadIdx.x & 63;
  int s = wave * GN_NPW;
  if (s >= n) return;
  int e = min(s + GN_NPW, n);
  int cur = batch[s];
  float m = fdec(gmaxbuf[cur]);
  float aacc = 0.f, dacc = 0.f;
  for (int nd = s; nd < e; ++nd){
    int g = batch[nd];
    if (g != cur){
      atomicAdd(&attbuf[cur * 64 + lane], aacc);
      if (lane == 0) atomicAdd(&denbuf[cur], dacc);
      aacc = 0.f; dacc = 0.f; cur = g; m = fdec(gmaxbuf[cur]);
    }
    float ex = expf(gatebuf[nd] - m);
    float hv = HS[(size_t)nd * HDIM + lane];
    aacc += ex * hv; dacc += ex;
  }
  atomicAdd(&attbuf[cur * 64 + lane], aacc);
  if (lane == 0) atomicAdd(&denbuf[cur], dacc);
}

// ---------------- pooling pass 3 ----------------
__global__ void k_pool3(const float* __restrict__ attbuf, const float* __restrict__ denbuf,
                        const float* __restrict__ sumbuf, const unsigned* __restrict__ maxbuf,
                        const int* __restrict__ gs, const float* __restrict__ U,
                        const float* __restrict__ HW1, const float* __restrict__ HB1,
                        const float* __restrict__ HW2, const float* __restrict__ HB2,
                        float* __restrict__ out){
  __shared__ float z[200];
  int g = blockIdx.x;
  int tid = threadIdx.x;   // 64 threads
  float cnt = (float)max(gs[g + 1] - gs[g], 1);
  float den = denbuf[g];
  z[tid]       = attbuf[g * 64 + tid] / den;
  z[64 + tid]  = sumbuf[g * 64 + tid] / cnt;
  z[128 + tid] = fdec(maxbuf[g * 64 + tid]);
  if (tid < 3) z[192 + tid] = U[g * 3 + tid];
  __syncthreads();
  float acc = HB1[tid];
  for (int k = 0; k < 195; k++) acc += z[k] * HW1[k * 64 + tid];
  float sv = fmaxf(acc, 0.f) * HW2[tid];
  #pragma unroll
  for (int msk = 1; msk < 64; msk <<= 1) sv += __shfl_xor(sv, msk);
  if (tid == 0) out[g] = sv + HB2[0];
}

extern "C" void kernel_launch(void* const* d_in, const int* in_sizes, int n_in,
                              void* d_out, int out_size, void* d_ws, size_t ws_size,
                              hipStream_t stream){
  const float* x     = (const float*)d_in[0];
  const int*   ei    = (const int*)d_in[1];
  const int*   batch = (const int*)d_in[2];
  const float* u     = (const float*)d_in[3];
  const float* W[3][4]; const float* GNp[3][3];
  for (int l = 0; l < 3; l++){
    int base = 4 + l * 7;
    W[l][0]  = (const float*)d_in[base + 0];
    W[l][1]  = (const float*)d_in[base + 1];
    W[l][2]  = (const float*)d_in[base + 2];
    W[l][3]  = (const float*)d_in[base + 3];
    GNp[l][0]= (const float*)d_in[base + 4];
    GNp[l][1]= (const float*)d_in[base + 5];
    GNp[l][2]= (const float*)d_in[base + 6];
  }
  const float* gate_w = (const float*)d_in[25];
  const float* gate_b = (const float*)d_in[26];
  const float* hw1    = (const float*)d_in[27];
  const float* hb1    = (const float*)d_in[28];
  const float* hw2    = (const float*)d_in[29];
  const float* hb2    = (const float*)d_in[30];
  float* out = (float*)d_out;

  int N = in_sizes[0] / HDIM;
  int E = in_sizes[1] / 2;
  int B = in_sizes[3] / 3;
  const int* src = ei;
  const int* dst = ei + E;
  int NB = (N + 255) >> 8;     // <= MAXNB for N <= 131072

  char* w8 = (char*)d_ws;
  size_t NH = (size_t)N * HDIM * sizeof(float);
  auto alignup = [](size_t v){ return (v + 255) & ~(size_t)255; };
  size_t off = 0;
  float* hsum    = (float*)(w8 + off); off += alignup(NH);
  float* bufA    = (float*)(w8 + off); off += alignup(NH);
  float* bufB    = (float*)(w8 + off); off += alignup(NH);
  float* G       = (float*)(w8 + off); off += alignup(NH);
  float* gatebuf = (float*)(w8 + off); off += alignup((size_t)N * 4);
  int*   deg     = (int*)(w8 + off);   off += alignup((size_t)N * 4);
  int*   offs    = (int*)(w8 + off);   off += alignup((size_t)N * 4);
  int*   csr     = (int*)(w8 + off);   off += alignup((size_t)E * 4);
  int2*  ebuf    = (int2*)(w8 + off);  off += alignup((size_t)E * 8);
  int*   bcount  = (int*)(w8 + off);   off += alignup((size_t)(MAXNB + 1) * 4);
  int*   bbase   = (int*)(w8 + off);   off += alignup((size_t)(MAXNB + 1) * 4);
  int*   bcursor = (int*)(w8 + off);   off += alignup((size_t)(MAXNB + 1) * 4);
  float* stats   = (float*)(w8 + off); off += alignup((size_t)B * 128 * 4);
  float* meanms  = (float*)(w8 + off); off += alignup((size_t)B * 64 * 4);
  float* scale   = (float*)(w8 + off); off += alignup((size_t)B * 64 * 4);
  float* sumbuf  = (float*)(w8 + off); off += alignup((size_t)B * 64 * 4);
  unsigned* maxbuf = (unsigned*)(w8 + off); off += alignup((size_t)B * 64 * 4);
  float* attbuf  = (float*)(w8 + off); off += alignup((size_t)B * 64 * 4);
  float* denbuf  = (float*)(w8 + off); off += alignup((size_t)B * 4);
  unsigned* gmaxbuf = (unsigned*)(w8 + off); off += alignup((size_t)B * 4);
  int*   gs      = (int*)(w8 + off);   off += alignup((size_t)(B + 1) * 4);
  (void)ws_size; (void)n_in; (void)out_size;

  hipMemsetAsync(bcount, 0, (size_t)(MAXNB + 1) * 4, stream);
  hipMemsetAsync(sumbuf, 0, (size_t)B * 64 * 4, stream);
  hipMemsetAsync(maxbuf, 0, (size_t)B * 64 * 4, stream);   // 0 == below all reals in fenc order
  hipMemsetAsync(attbuf, 0, (size_t)B * 64 * 4, stream);
  hipMemsetAsync(denbuf, 0, (size_t)B * 4, stream);
  hipMemsetAsync(gmaxbuf, 0, (size_t)B * 4, stream);

  const int tb = 256;
  k_bhist<<<256, tb, 0, stream>>>(dst, bcount, E, NB);
  k_bscan<<<1, MAXNB, 0, stream>>>(bcount, bbase, bcursor, NB);
  k_breorder<<<(E + RCHUNK - 1) / RCHUNK, tb, 0, stream>>>(src, dst, bcursor, ebuf, E, NB);
  k_bucket_csr<<<NB, tb, 0, stream>>>(ebuf, bbase, deg, offs, csr, N);
  k_gstart<<<1, 256, 0, stream>>>(batch, N, gs, B);

  int nwaves = (N + GN_NPW - 1) / GN_NPW;
  int segblocks = (nwaves * 64 + tb - 1) / tb;
  int n16 = N * 16;
  int nblk64 = (N + 63) >> 6;

  const float* P = x;
  float* C = bufA;
  for (int l = 0; l < 3; l++){
    unsigned aggblocks = (unsigned)(((size_t)N * HDIM + 255) / 256);
    k_agg<<<aggblocks, 256, 0, stream>>>(P, csr, offs, deg, G, N);
    hipMemsetAsync(stats, 0, (size_t)B * 128 * 4, stream);
    k_mlp<<<nblk64, 256, 0, stream>>>(G, batch, W[l][0], W[l][1], W[l][2], W[l][3], stats, N);
    k_gn_finalize<<<(B * 64 + tb - 1) / tb, tb, 0, stream>>>(stats, gs, GNp[l][0], GNp[l][2],
                                                             meanms, scale, B);
    k_gn_apply<<<(n16 + tb - 1) / tb, tb, 0, stream>>>(G, batch, meanms, scale, GNp[l][1],
                                                       C, hsum, n16, l == 0 ? 1 : 0,
                                                       l == 2 ? 0 : 1);
    P = C;
    C = (l == 0) ? bufB : bufA;
  }
  k_pool1<<<segblocks, tb, 0, stream>>>(hsum, batch, gate_w, gate_b,
                                        sumbuf, maxbuf, gatebuf, gmaxbuf, N);
  k_pool2<<<segblocks, tb, 0, stream>>>(hsum, batch, gatebuf, gmaxbuf, attbuf, denbuf, N);
  k_pool3<<<B, 64, 0, stream>>>(attbuf, denbuf, sumbuf, maxbuf, gs, u,
                                hw1, hb1, hw2, hb2, out);
}

// Round 6
// 640.765 us; speedup vs baseline: 1.2451x; 1.0265x over previous
//
#include <hip/hip_runtime.h>
#include <math.h>

#define HDIM 64
#define GN_EPS 1e-5f
#define MAXNB 512          // supports N <= 131072 (bucket = 256 nodes)
#define APITCH 72

typedef __attribute__((ext_vector_type(8))) short bf16x8;
typedef __attribute__((ext_vector_type(4))) float f32x4;

__device__ __forceinline__ int lower_bound_i(const int* a, int n, int key){
  int lo = 0, hi = n;
  while (lo < hi){ int mid = (lo + hi) >> 1; if (a[mid] < key) lo = mid + 1; else hi = mid; }
  return lo;
}

// ordered-uint encoding for float atomicMax
__device__ __forceinline__ unsigned fenc(float x){
  unsigned b = __float_as_uint(x);
  return (b & 0x80000000u) ? ~b : (b | 0x80000000u);
}
__device__ __forceinline__ float fdec(unsigned u){
  unsigned b = (u & 0x80000000u) ? (u ^ 0x80000000u) : ~u;
  return __uint_as_float(b);
}

// bf16 round-to-nearest-even helpers (bit-level, no header types)
__device__ __forceinline__ unsigned short f2bf(float f){
  unsigned u = __float_as_uint(f);
  u += 0x7fffu + ((u >> 16) & 1u);
  return (unsigned short)(u >> 16);
}
__device__ __forceinline__ float bf2f(unsigned short h){
  return __uint_as_float(((unsigned)h) << 16);
}

// ---------------- CSR build, pass A: bucket histogram (bucket = dst>>8) ----------
__global__ void k_bhist(const int* __restrict__ dst, int* __restrict__ bcount, int E, int NB){
  __shared__ int lh[MAXNB];
  int tid = threadIdx.x;
  for (int b = tid; b < NB; b += blockDim.x) lh[b] = 0;
  __syncthreads();
  for (int i = blockIdx.x * blockDim.x + tid; i < E; i += gridDim.x * blockDim.x)
    atomicAdd(&lh[dst[i] >> 8], 1);
  __syncthreads();
  for (int b = tid; b < NB; b += blockDim.x){ int c = lh[b]; if (c) atomicAdd(&bcount[b], c); }
}

// ---------------- pass B: scan bucket counts ----------------
__global__ void k_bscan(const int* __restrict__ bcount, int* __restrict__ bbase,
                        int* __restrict__ bcursor, int NB){
  __shared__ int sd[MAXNB];
  int tid = threadIdx.x;   // 512 threads
  int v = (tid < NB) ? bcount[tid] : 0;
  sd[tid] = v; __syncthreads();
  for (int o = 1; o < MAXNB; o <<= 1){
    int t = (tid >= o) ? sd[tid - o] : 0;
    __syncthreads();
    sd[tid] += t;
    __syncthreads();
  }
  int excl = sd[tid] - v;
  if (tid < NB){ bbase[tid] = excl; bcursor[tid] = excl; }
  if (tid == NB - 1) bbase[NB] = excl + v;
}

// ---------------- pass C: reorder edges into bucket-grouped ebuf ----------------
#define RCHUNK 8192
__global__ void k_breorder(const int* __restrict__ src, const int* __restrict__ dst,
                           int* __restrict__ bcursor, int2* __restrict__ ebuf, int E, int NB){
  __shared__ int lh[MAXNB];
  __shared__ int lbase[MAXNB];
  int tid = threadIdx.x;   // 256
  int c0 = blockIdx.x * RCHUNK;
  for (int b = tid; b < NB; b += 256) lh[b] = 0;
  __syncthreads();
  for (int j = 0; j < RCHUNK / 256; j++){
    int i = c0 + j * 256 + tid;
    if (i < E) atomicAdd(&lh[dst[i] >> 8], 1);
  }
  __syncthreads();
  for (int b = tid; b < NB; b += 256){
    int c = lh[b];
    lbase[b] = c ? atomicAdd(&bcursor[b], c) : 0;
    lh[b] = 0;
  }
  __syncthreads();
  for (int j = 0; j < RCHUNK / 256; j++){
    int i = c0 + j * 256 + tid;
    if (i < E){
      int d = dst[i]; int b = d >> 8;
      int r = atomicAdd(&lh[b], 1);
      ebuf[lbase[b] + r] = make_int2(src[i], d);
    }
  }
}

// ---------------- pass D: per-bucket counting sort -> csr/deg/offs ----------------
__global__ void k_bucket_csr(const int2* __restrict__ ebuf, const int* __restrict__ bbase,
                             int* __restrict__ deg, int* __restrict__ offs,
                             int* __restrict__ csr, int N){
  __shared__ int lh[256];
  __shared__ int lsc[256];
  int b = blockIdx.x;
  int lo = b << 8;
  int nn = min(256, N - lo);
  int tid = threadIdx.x;   // 256
  lh[tid] = 0; __syncthreads();
  int es = bbase[b], ee = bbase[b + 1];
  for (int i = es + tid; i < ee; i += 256) atomicAdd(&lh[ebuf[i].y - lo], 1);
  __syncthreads();
  int v = lh[tid];
  lsc[tid] = v; __syncthreads();
  for (int o = 1; o < 256; o <<= 1){
    int t = (tid >= o) ? lsc[tid - o] : 0;
    __syncthreads();
    lsc[tid] += t;
    __syncthreads();
  }
  int excl = lsc[tid] - v;
  if (tid < nn){ deg[lo + tid] = v; offs[lo + tid] = es + excl; }
  __syncthreads();
  lh[tid] = es + excl;     // reuse as cursor
  __syncthreads();
  for (int i = es + tid; i < ee; i += 256){
    int2 e = ebuf[i];
    int pos = atomicAdd(&lh[e.y - lo], 1);
    csr[pos] = e.x;
  }
}

// graph start offsets (batch is sorted)
__global__ void k_gstart(const int* __restrict__ batch, int n, int* __restrict__ gs, int B){
  int g = blockIdx.x * blockDim.x + threadIdx.x;
  if (g <= B) gs[g] = lower_bound_i(batch, n, g);
}

// ---------------- weight prep: transpose + bf16 hi/lo split ----------------
__global__ void k_wprep(const float* __restrict__ Wa0, const float* __restrict__ Wb0,
                        const float* __restrict__ Wa1, const float* __restrict__ Wb1,
                        const float* __restrict__ Wa2, const float* __restrict__ Wb2,
                        short* __restrict__ out){
  const float* Ws[6] = {Wa0, Wb0, Wa1, Wb1, Wa2, Wb2};
  const float* W = Ws[blockIdx.x];
  short* hi = out + blockIdx.x * 8192;
  short* lo = hi + 4096;
  int tid = threadIdx.x;
  for (int i = tid; i < 4096; i += 256){
    int k = i >> 6, j = i & 63;            // W[k][j], coalesced read
    float v = W[i];
    unsigned short h = f2bf(v);
    hi[j * 64 + k] = (short)h;             // transposed: Wt[j][k]
    lo[j * 64 + k] = (short)f2bf(v - bf2f(h));
  }
}

// ---------------- GIN aggregation: G[n] = P[n] + sum_{e->n} P[src] ----------------
__global__ void k_agg(const float* __restrict__ P, const int* __restrict__ csr,
                      const int* __restrict__ offs, const int* __restrict__ deg,
                      float* __restrict__ G, int n){
  int gi = blockIdx.x * blockDim.x + threadIdx.x;
  int node = gi >> 6;
  int lane = gi & 63;
  if (node >= n) return;
  int st = offs[node], cnt = deg[node];
  float self = P[(size_t)node * HDIM + lane];
  float a0 = 0.f, a1 = 0.f, a2 = 0.f, a3 = 0.f;
  for (int base = 0; base < cnt; base += 64){
    int rem = cnt - base;
    int s = (lane < rem) ? csr[st + base + lane] : 0;
    int m = min(rem, 64);
    int j = 0;
    for (; j + 4 <= m; j += 4){
      int s0 = __shfl(s, j), s1 = __shfl(s, j + 1), s2 = __shfl(s, j + 2), s3 = __shfl(s, j + 3);
      a0 += P[(size_t)s0 * HDIM + lane];
      a1 += P[(size_t)s1 * HDIM + lane];
      a2 += P[(size_t)s2 * HDIM + lane];
      a3 += P[(size_t)s3 * HDIM + lane];
    }
    for (; j < m; ++j){ int sj = __shfl(s, j); a0 += P[(size_t)sj * HDIM + lane]; }
  }
  G[(size_t)node * HDIM + lane] = self + ((a0 + a1) + (a2 + a3));
}

// ======== GIN MLP via MFMA split-bf16 (bf16x3) + fused GraphNorm stats ========
// 64-node tile, 4 waves; wave w owns rows 16w..16w+15. D = Ah*Wh + Ah*Wl + Al*Wh.
__global__ __launch_bounds__(256, 4) void k_mlp(
    float* __restrict__ G, const int* __restrict__ batch,
    const short* __restrict__ W1h, const short* __restrict__ W1l,
    const float* __restrict__ B1,
    const short* __restrict__ W2h, const short* __restrict__ W2l,
    const float* __restrict__ B2,
    float* __restrict__ stats, int N){
  __shared__ short Ah[64 * APITCH];   // 9216 B
  __shared__ short Al[64 * APITCH];   // 9216 B
  __shared__ float ssum[64], ssq[64];
  int tid = threadIdx.x;
  int t0 = blockIdx.x << 6;
  if (tid < 64){ ssum[tid] = 0.f; ssq[tid] = 0.f; }

  // ---- load tile f32 (coalesced), split into bf16 hi/lo planes ----
  #pragma unroll
  for (int r = 0; r < 4; r++){
    int idx = r * 256 + tid;            // 0..1023
    int node = idx >> 4, f4 = idx & 15;
    int gn = t0 + node;
    float4 v = make_float4(0.f, 0.f, 0.f, 0.f);
    if (gn < N) v = ((const float4*)G)[(size_t)gn * 16 + f4];
    float vv[4] = {v.x, v.y, v.z, v.w};
    short h[4], l[4];
    #pragma unroll
    for (int j = 0; j < 4; j++){
      unsigned short hh = f2bf(vv[j]);
      h[j] = (short)hh;
      l[j] = (short)f2bf(vv[j] - bf2f(hh));
    }
    *(short4*)(Ah + node * APITCH + f4 * 4) = make_short4(h[0], h[1], h[2], h[3]);
    *(short4*)(Al + node * APITCH + f4 * 4) = make_short4(l[0], l[1], l[2], l[3]);
  }
  __syncthreads();

  int wv = tid >> 6, lane = tid & 63;
  int quad = lane >> 4, l15 = lane & 15;
  int rbase = wv << 4;

  // ---- GEMM1 ----
  f32x4 acc[4];
  #pragma unroll
  for (int t = 0; t < 4; t++) acc[t] = (f32x4){0.f, 0.f, 0.f, 0.f};
  #pragma unroll
  for (int kb = 0; kb < 2; kb++){
    int kk = kb * 32 + quad * 8;
    bf16x8 a_h = *(const bf16x8*)(Ah + (rbase + l15) * APITCH + kk);
    bf16x8 a_l = *(const bf16x8*)(Al + (rbase + l15) * APITCH + kk);
    #pragma unroll
    for (int t = 0; t < 4; t++){
      bf16x8 b_h = *(const bf16x8*)(W1h + (t * 16 + l15) * 64 + kk);
      bf16x8 b_l = *(const bf16x8*)(W1l + (t * 16 + l15) * 64 + kk);
      acc[t] = __builtin_amdgcn_mfma_f32_16x16x32_bf16(a_h, b_h, acc[t], 0, 0, 0);
      acc[t] = __builtin_amdgcn_mfma_f32_16x16x32_bf16(a_h, b_l, acc[t], 0, 0, 0);
      acc[t] = __builtin_amdgcn_mfma_f32_16x16x32_bf16(a_l, b_h, acc[t], 0, 0, 0);
    }
  }
  __syncthreads();   // all GEMM1 LDS reads done; safe to overwrite planes

  // ---- bias + relu + split, write intermediate (C layout -> A layout) ----
  #pragma unroll
  for (int t = 0; t < 4; t++){
    float bb = B1[t * 16 + l15];
    #pragma unroll
    for (int rg = 0; rg < 4; rg++){
      float v = fmaxf(acc[t][rg] + bb, 0.f);
      int row = rbase + quad * 4 + rg;
      int col = t * 16 + l15;
      unsigned short hh = f2bf(v);
      Ah[row * APITCH + col] = (short)hh;
      Al[row * APITCH + col] = (short)f2bf(v - bf2f(hh));
    }
  }
  __syncthreads();

  // ---- GEMM2 ----
  f32x4 acc2[4];
  #pragma unroll
  for (int t = 0; t < 4; t++) acc2[t] = (f32x4){0.f, 0.f, 0.f, 0.f};
  #pragma unroll
  for (int kb = 0; kb < 2; kb++){
    int kk = kb * 32 + quad * 8;
    bf16x8 a_h = *(const bf16x8*)(Ah + (rbase + l15) * APITCH + kk);
    bf16x8 a_l = *(const bf16x8*)(Al + (rbase + l15) * APITCH + kk);
    #pragma unroll
    for (int t = 0; t < 4; t++){
      bf16x8 b_h = *(const bf16x8*)(W2h + (t * 16 + l15) * 64 + kk);
      bf16x8 b_l = *(const bf16x8*)(W2l + (t * 16 + l15) * 64 + kk);
      acc2[t] = __builtin_amdgcn_mfma_f32_16x16x32_bf16(a_h, b_h, acc2[t], 0, 0, 0);
      acc2[t] = __builtin_amdgcn_mfma_f32_16x16x32_bf16(a_h, b_l, acc2[t], 0, 0, 0);
      acc2[t] = __builtin_amdgcn_mfma_f32_16x16x32_bf16(a_l, b_h, acc2[t], 0, 0, 0);
    }
  }

  // ---- bias, store Y, stats ----
  int lastn = min(t0 + 63, N - 1);
  int g0 = batch[t0];
  bool uniform = (batch[lastn] == g0) && (t0 + 63 < N);
  #pragma unroll
  for (int t = 0; t < 4; t++){
    float bb = B2[t * 16 + l15];
    int f = t * 16 + l15;
    float s = 0.f, q = 0.f;
    #pragma unroll
    for (int rg = 0; rg < 4; rg++){
      float v = acc2[t][rg] + bb;
      int node = t0 + rbase + quad * 4 + rg;
      if (node < N) G[(size_t)node * HDIM + f] = v;
      if (uniform){
        s += v; q += v * v;
      } else if (node < N){
        int g = batch[node];
        atomicAdd(&stats[g * 128 + f], v);
        atomicAdd(&stats[g * 128 + 64 + f], v * v);
      }
    }
    if (uniform){
      s += __shfl_xor(s, 16); s += __shfl_xor(s, 32);
      q += __shfl_xor(q, 16); q += __shfl_xor(q, 32);
      if (quad == 0){ atomicAdd(&ssum[f], s); atomicAdd(&ssq[f], q); }
    }
  }
  __syncthreads();
  if (uniform && tid < 64){
    atomicAdd(&stats[g0 * 128 + tid], ssum[tid]);
    atomicAdd(&stats[g0 * 128 + 64 + tid], ssq[tid]);
  }
}

// ---------------- GraphNorm finalize: mean*ms and scale ----------------
__global__ void k_gn_finalize(const float* __restrict__ stats, const int* __restrict__ gs,
                              const float* __restrict__ w, const float* __restrict__ ms,
                              float* __restrict__ meanms, float* __restrict__ scale, int B){
  int i = blockIdx.x * blockDim.x + threadIdx.x;
  if (i >= B * 64) return;
  int g = i >> 6, f = i & 63;
  float cnt = (float)max(gs[g + 1] - gs[g], 1);
  float mean = stats[g * 128 + f] / cnt;
  float ex2  = stats[g * 128 + 64 + f] / cnt;
  float msv = ms[f];
  float var = ex2 - (2.f * msv - msv * msv) * mean * mean;
  meanms[i] = msv * mean;
  scale[i] = rsqrtf(var + GN_EPS) * w[f];
}

// ---------------- GraphNorm apply + relu + residual accumulate ----------
__global__ void k_gn_apply(const float* __restrict__ Y, const int* __restrict__ batch,
                           const float* __restrict__ meanms, const float* __restrict__ scale,
                           const float* __restrict__ bias,
                           float* __restrict__ C, float* __restrict__ hsum, int n16,
                           int first, int writeC){
  int i = blockIdx.x * blockDim.x + threadIdx.x;
  if (i >= n16) return;
  int node = i >> 4, q = i & 15;
  int g = batch[node];
  float4 y = ((const float4*)Y)[i];
  float4 m = ((const float4*)(meanms + g * 64))[q];
  float4 s = ((const float4*)(scale  + g * 64))[q];
  float4 b = ((const float4*)bias)[q];
  float4 v;
  v.x = fmaxf((y.x - m.x) * s.x + b.x, 0.f);
  v.y = fmaxf((y.y - m.y) * s.y + b.y, 0.f);
  v.z = fmaxf((y.z - m.z) * s.z + b.z, 0.f);
  v.w = fmaxf((y.w - m.w) * s.w + b.w, 0.f);
  if (writeC) ((float4*)C)[i] = v;
  if (first){
    ((float4*)hsum)[i] = v;
  } else {
    float4 h = ((float4*)hsum)[i];
    h.x += v.x; h.y += v.y; h.z += v.z; h.w += v.w;
    ((float4*)hsum)[i] = h;
  }
}

// ---------------- pooling pass 1 ----------------
#define GN_NPW 32
__global__ void k_pool1(const float* __restrict__ HS, const int* __restrict__ batch,
                        const float* __restrict__ GW, const float* __restrict__ GB,
                        float* __restrict__ sumbuf, unsigned* __restrict__ maxbuf,
                        float* __restrict__ gatebuf, unsigned* __restrict__ gmaxbuf, int n){
  int wave = (int)((blockIdx.x * blockDim.x + threadIdx.x) >> 6);
  int lane = threadIdx.x & 63;
  int s = wave * GN_NPW;
  if (s >= n) return;
  int e = min(s + GN_NPW, n);
  float gwv = GW[lane];
  float gb = GB[0];
  int cur = batch[s];
  float macc = 0.f, xacc = -INFINITY, gmx = -INFINITY;
  for (int nd = s; nd < e; ++nd){
    int g = batch[nd];
    if (g != cur){
      atomicAdd(&sumbuf[cur * 64 + lane], macc);
      atomicMax(&maxbuf[cur * 64 + lane], fenc(xacc));
      if (lane == 0) atomicMax(&gmaxbuf[cur], fenc(gmx));
      macc = 0.f; xacc = -INFINITY; gmx = -INFINITY; cur = g;
    }
    float hv = HS[(size_t)nd * HDIM + lane];
    macc += hv; xacc = fmaxf(xacc, hv);
    float gv = hv * gwv;
    #pragma unroll
    for (int msk = 1; msk < 64; msk <<= 1) gv += __shfl_xor(gv, msk);
    gv += gb;
    if (lane == 0) gatebuf[nd] = gv;
    gmx = fmaxf(gmx, gv);
  }
  atomicAdd(&sumbuf[cur * 64 + lane], macc);
  atomicMax(&maxbuf[cur * 64 + lane], fenc(xacc));
  if (lane == 0) atomicMax(&gmaxbuf[cur], fenc(gmx));
}

// ---------------- pooling pass 2 ----------------
__global__ void k_pool2(const float* __restrict__ HS, const int* __restrict__ batch,
                        const float* __restrict__ gatebuf, const unsigned* __restrict__ gmaxbuf,
                        float* __restrict__ attbuf, float* __restrict__ denbuf, int n){
  int wave = (int)((blockIdx.x * blockDim.x + threadIdx.x) >> 6);
  int lane = threadIdx.x & 63;
  int s = wave * GN_NPW;
  if (s >= n) return;
  int e = min(s + GN_NPW, n);
  int cur = batch[s];
  float m = fdec(gmaxbuf[cur]);
  float aacc = 0.f, dacc = 0.f;
  for (int nd = s; nd < e; ++nd){
    int g = batch[nd];
    if (g != cur){
      atomicAdd(&attbuf[cur * 64 + lane], aacc);
      if (lane == 0) atomicAdd(&denbuf[cur], dacc);
      aacc = 0.f; dacc = 0.f; cur = g; m = fdec(gmaxbuf[cur]);
    }
    float ex = expf(gatebuf[nd] - m);
    float hv = HS[(size_t)nd * HDIM + lane];
    aacc += ex * hv; dacc += ex;
  }
  atomicAdd(&attbuf[cur * 64 + lane], aacc);
  if (lane == 0) atomicAdd(&denbuf[cur], dacc);
}

// ---------------- pooling pass 3 ----------------
__global__ void k_pool3(const float* __restrict__ attbuf, const float* __restrict__ denbuf,
                        const float* __restrict__ sumbuf, const unsigned* __restrict__ maxbuf,
                        const int* __restrict__ gs, const float* __restrict__ U,
                        const float* __restrict__ HW1, const float* __restrict__ HB1,
                        const float* __restrict__ HW2, const float* __restrict__ HB2,
                        float* __restrict__ out){
  __shared__ float z[200];
  int g = blockIdx.x;
  int tid = threadIdx.x;   // 64 threads
  float cnt = (float)max(gs[g + 1] - gs[g], 1);
  float den = denbuf[g];
  z[tid]       = attbuf[g * 64 + tid] / den;
  z[64 + tid]  = sumbuf[g * 64 + tid] / cnt;
  z[128 + tid] = fdec(maxbuf[g * 64 + tid]);
  if (tid < 3) z[192 + tid] = U[g * 3 + tid];
  __syncthreads();
  float acc = HB1[tid];
  for (int k = 0; k < 195; k++) acc += z[k] * HW1[k * 64 + tid];
  float sv = fmaxf(acc, 0.f) * HW2[tid];
  #pragma unroll
  for (int msk = 1; msk < 64; msk <<= 1) sv += __shfl_xor(sv, msk);
  if (tid == 0) out[g] = sv + HB2[0];
}

extern "C" void kernel_launch(void* const* d_in, const int* in_sizes, int n_in,
                              void* d_out, int out_size, void* d_ws, size_t ws_size,
                              hipStream_t stream){
  const float* x     = (const float*)d_in[0];
  const int*   ei    = (const int*)d_in[1];
  const int*   batch = (const int*)d_in[2];
  const float* u     = (const float*)d_in[3];
  const float* W[3][4]; const float* GNp[3][3];
  for (int l = 0; l < 3; l++){
    int base = 4 + l * 7;
    W[l][0]  = (const float*)d_in[base + 0];
    W[l][1]  = (const float*)d_in[base + 1];
    W[l][2]  = (const float*)d_in[base + 2];
    W[l][3]  = (const float*)d_in[base + 3];
    GNp[l][0]= (const float*)d_in[base + 4];
    GNp[l][1]= (const float*)d_in[base + 5];
    GNp[l][2]= (const float*)d_in[base + 6];
  }
  const float* gate_w = (const float*)d_in[25];
  const float* gate_b = (const float*)d_in[26];
  const float* hw1    = (const float*)d_in[27];
  const float* hb1    = (const float*)d_in[28];
  const float* hw2    = (const float*)d_in[29];
  const float* hb2    = (const float*)d_in[30];
  float* out = (float*)d_out;

  int N = in_sizes[0] / HDIM;
  int E = in_sizes[1] / 2;
  int B = in_sizes[3] / 3;
  const int* src = ei;
  const int* dst = ei + E;
  int NB = (N + 255) >> 8;     // <= MAXNB for N <= 131072

  char* w8 = (char*)d_ws;
  size_t NH = (size_t)N * HDIM * sizeof(float);
  auto alignup = [](size_t v){ return (v + 255) & ~(size_t)255; };
  size_t off = 0;
  float* hsum    = (float*)(w8 + off); off += alignup(NH);
  float* bufA    = (float*)(w8 + off); off += alignup(NH);
  float* bufB    = (float*)(w8 + off); off += alignup(NH);
  float* G       = (float*)(w8 + off); off += alignup(NH);
  float* gatebuf = (float*)(w8 + off); off += alignup((size_t)N * 4);
  int*   deg     = (int*)(w8 + off);   off += alignup((size_t)N * 4);
  int*   offs    = (int*)(w8 + off);   off += alignup((size_t)N * 4);
  int*   csr     = (int*)(w8 + off);   off += alignup((size_t)E * 4);
  int2*  ebuf    = (int2*)(w8 + off);  off += alignup((size_t)E * 8);
  int*   bcount  = (int*)(w8 + off);   off += alignup((size_t)(MAXNB + 1) * 4);
  int*   bbase   = (int*)(w8 + off);   off += alignup((size_t)(MAXNB + 1) * 4);
  int*   bcursor = (int*)(w8 + off);   off += alignup((size_t)(MAXNB + 1) * 4);
  float* stats   = (float*)(w8 + off); off += alignup((size_t)B * 128 * 4);
  float* meanms  = (float*)(w8 + off); off += alignup((size_t)B * 64 * 4);
  float* scale   = (float*)(w8 + off); off += alignup((size_t)B * 64 * 4);
  float* sumbuf  = (float*)(w8 + off); off += alignup((size_t)B * 64 * 4);
  unsigned* maxbuf = (unsigned*)(w8 + off); off += alignup((size_t)B * 64 * 4);
  float* attbuf  = (float*)(w8 + off); off += alignup((size_t)B * 64 * 4);
  float* denbuf  = (float*)(w8 + off); off += alignup((size_t)B * 4);
  unsigned* gmaxbuf = (unsigned*)(w8 + off); off += alignup((size_t)B * 4);
  int*   gs      = (int*)(w8 + off);   off += alignup((size_t)(B + 1) * 4);
  short* wbf     = (short*)(w8 + off); off += alignup((size_t)6 * 8192 * 2);
  (void)ws_size; (void)n_in; (void)out_size;

  hipMemsetAsync(bcount, 0, (size_t)(MAXNB + 1) * 4, stream);
  hipMemsetAsync(sumbuf, 0, (size_t)B * 64 * 4, stream);
  hipMemsetAsync(maxbuf, 0, (size_t)B * 64 * 4, stream);   // 0 == below all reals in fenc order
  hipMemsetAsync(attbuf, 0, (size_t)B * 64 * 4, stream);
  hipMemsetAsync(denbuf, 0, (size_t)B * 4, stream);
  hipMemsetAsync(gmaxbuf, 0, (size_t)B * 4, stream);

  const int tb = 256;
  k_bhist<<<256, tb, 0, stream>>>(dst, bcount, E, NB);
  k_bscan<<<1, MAXNB, 0, stream>>>(bcount, bbase, bcursor, NB);
  k_breorder<<<(E + RCHUNK - 1) / RCHUNK, tb, 0, stream>>>(src, dst, bcursor, ebuf, E, NB);
  k_bucket_csr<<<NB, tb, 0, stream>>>(ebuf, bbase, deg, offs, csr, N);
  k_gstart<<<1, 256, 0, stream>>>(batch, N, gs, B);
  k_wprep<<<6, 256, 0, stream>>>(W[0][0], W[0][2], W[1][0], W[1][2], W[2][0], W[2][2], wbf);

  int nwaves = (N + GN_NPW - 1) / GN_NPW;
  int segblocks = (nwaves * 64 + tb - 1) / tb;
  int n16 = N * 16;
  int nblk64 = (N + 63) >> 6;

  const float* P = x;
  float* C = bufA;
  for (int l = 0; l < 3; l++){
    unsigned aggblocks = (unsigned)(((size_t)N * HDIM + 255) / 256);
    k_agg<<<aggblocks, 256, 0, stream>>>(P, csr, offs, deg, G, N);
    hipMemsetAsync(stats, 0, (size_t)B * 128 * 4, stream);
    const short* w1h = wbf + (size_t)(l * 2 + 0) * 8192;
    const short* w1l = w1h + 4096;
    const short* w2h = wbf + (size_t)(l * 2 + 1) * 8192;
    const short* w2l = w2h + 4096;
    k_mlp<<<nblk64, 256, 0, stream>>>(G, batch, w1h, w1l, W[l][1], w2h, w2l, W[l][3],
                                      stats, N);
    k_gn_finalize<<<(B * 64 + tb - 1) / tb, tb, 0, stream>>>(stats, gs, GNp[l][0], GNp[l][2],
                                                             meanms, scale, B);
    k_gn_apply<<<(n16 + tb - 1) / tb, tb, 0, stream>>>(G, batch, meanms, scale, GNp[l][1],
                                                       C, hsum, n16, l == 0 ? 1 : 0,
                                                       l == 2 ? 0 : 1);
    P = C;
    C = (l == 0) ? bufB : bufA;
  }
  k_pool1<<<segblocks, tb, 0, stream>>>(hsum, batch, gate_w, gate_b,
                                        sumbuf, maxbuf, gatebuf, gmaxbuf, N);
  k_pool2<<<segblocks, tb, 0, stream>>>(hsum, batch, gatebuf, gmaxbuf, attbuf, denbuf, N);
  k_pool3<<<B, 64, 0, stream>>>(attbuf, denbuf, sumbuf, maxbuf, gs, u,
                                hw1, hb1, hw2, hb2, out);
}

// Round 7
// 564.581 us; speedup vs baseline: 1.4131x; 1.1349x over previous
//
#include <hip/hip_runtime.h>
#include <math.h>

#define HDIM 64
#define GN_EPS 1e-5f
#define MAXNB 512          // supports N <= 131072 (bucket = 256 nodes)
#define APITCH 72

typedef __attribute__((ext_vector_type(8))) short bf16x8;
typedef __attribute__((ext_vector_type(4))) float f32x4;

__device__ __forceinline__ int lower_bound_i(const int* a, int n, int key){
  int lo = 0, hi = n;
  while (lo < hi){ int mid = (lo + hi) >> 1; if (a[mid] < key) lo = mid + 1; else hi = mid; }
  return lo;
}

// ordered-uint encoding for float atomicMax
__device__ __forceinline__ unsigned fenc(float x){
  unsigned b = __float_as_uint(x);
  return (b & 0x80000000u) ? ~b : (b | 0x80000000u);
}
__device__ __forceinline__ float fdec(unsigned u){
  unsigned b = (u & 0x80000000u) ? (u ^ 0x80000000u) : ~u;
  return __uint_as_float(b);
}

// bf16 round-to-nearest-even helpers
__device__ __forceinline__ unsigned short f2bf(float f){
  unsigned u = __float_as_uint(f);
  u += 0x7fffu + ((u >> 16) & 1u);
  return (unsigned short)(u >> 16);
}
__device__ __forceinline__ float bf2f(unsigned short h){
  return __uint_as_float(((unsigned)h) << 16);
}

// ======= prep: bucket histogram (blocks 0-255) + weight split (256-261) + gstart (262)
__global__ void k_prep(const int* __restrict__ dst, int* __restrict__ bcount, int E, int NB,
                       const float* __restrict__ Wa0, const float* __restrict__ Wb0,
                       const float* __restrict__ Wa1, const float* __restrict__ Wb1,
                       const float* __restrict__ Wa2, const float* __restrict__ Wb2,
                       short* __restrict__ wbf,
                       const int* __restrict__ batch, int N, int* __restrict__ gs, int B){
  int tid = threadIdx.x;
  if (blockIdx.x < 256){
    __shared__ int lh[MAXNB];
    for (int b = tid; b < NB; b += 256) lh[b] = 0;
    __syncthreads();
    for (int i = blockIdx.x * 256 + tid; i < E; i += 256 * 256)
      atomicAdd(&lh[dst[i] >> 8], 1);
    __syncthreads();
    for (int b = tid; b < NB; b += 256){ int c = lh[b]; if (c) atomicAdd(&bcount[b], c); }
  } else if (blockIdx.x < 262){
    int wi = blockIdx.x - 256;
    const float* Wsrc[6] = {Wa0, Wb0, Wa1, Wb1, Wa2, Wb2};
    const float* W = Wsrc[wi];
    short* hi = wbf + wi * 8192;
    short* lo = hi + 4096;
    for (int i = tid; i < 4096; i += 256){
      int k = i >> 6, j = i & 63;            // W[k][j], coalesced read
      float v = W[i];
      unsigned short h = f2bf(v);
      hi[j * 64 + k] = (short)h;             // transposed: Wt[j][k]
      lo[j * 64 + k] = (short)f2bf(v - bf2f(h));
    }
  } else {
    for (int g = tid; g <= B; g += 256) gs[g] = lower_bound_i(batch, N, g);
  }
}

// ---------------- pass B: scan bucket counts ----------------
__global__ void k_bscan(const int* __restrict__ bcount, int* __restrict__ bbase,
                        int* __restrict__ bcursor, int NB){
  __shared__ int sd[MAXNB];
  int tid = threadIdx.x;   // 512 threads
  int v = (tid < NB) ? bcount[tid] : 0;
  sd[tid] = v; __syncthreads();
  for (int o = 1; o < MAXNB; o <<= 1){
    int t = (tid >= o) ? sd[tid - o] : 0;
    __syncthreads();
    sd[tid] += t;
    __syncthreads();
  }
  int excl = sd[tid] - v;
  if (tid < NB){ bbase[tid] = excl; bcursor[tid] = excl; }
  if (tid == NB - 1) bbase[NB] = excl + v;
}

// ---------------- pass C: reorder edges into bucket-grouped ebuf ----------------
#define RCHUNK 8192
__global__ void k_breorder(const int* __restrict__ src, const int* __restrict__ dst,
                           int* __restrict__ bcursor, int2* __restrict__ ebuf, int E, int NB){
  __shared__ int lh[MAXNB];
  __shared__ int lbase[MAXNB];
  int tid = threadIdx.x;   // 256
  int c0 = blockIdx.x * RCHUNK;
  for (int b = tid; b < NB; b += 256) lh[b] = 0;
  __syncthreads();
  for (int j = 0; j < RCHUNK / 256; j++){
    int i = c0 + j * 256 + tid;
    if (i < E) atomicAdd(&lh[dst[i] >> 8], 1);
  }
  __syncthreads();
  for (int b = tid; b < NB; b += 256){
    int c = lh[b];
    lbase[b] = c ? atomicAdd(&bcursor[b], c) : 0;
    lh[b] = 0;
  }
  __syncthreads();
  for (int j = 0; j < RCHUNK / 256; j++){
    int i = c0 + j * 256 + tid;
    if (i < E){
      int d = dst[i]; int b = d >> 8;
      int r = atomicAdd(&lh[b], 1);
      ebuf[lbase[b] + r] = make_int2(src[i], d);
    }
  }
}

// ---------------- pass D: per-bucket counting sort -> csr/deg/offs ----------------
__global__ void k_bucket_csr(const int2* __restrict__ ebuf, const int* __restrict__ bbase,
                             int* __restrict__ deg, int* __restrict__ offs,
                             int* __restrict__ csr, int N){
  __shared__ int lh[256];
  __shared__ int lsc[256];
  int b = blockIdx.x;
  int lo = b << 8;
  int nn = min(256, N - lo);
  int tid = threadIdx.x;   // 256
  lh[tid] = 0; __syncthreads();
  int es = bbase[b], ee = bbase[b + 1];
  for (int i = es + tid; i < ee; i += 256) atomicAdd(&lh[ebuf[i].y - lo], 1);
  __syncthreads();
  int v = lh[tid];
  lsc[tid] = v; __syncthreads();
  for (int o = 1; o < 256; o <<= 1){
    int t = (tid >= o) ? lsc[tid - o] : 0;
    __syncthreads();
    lsc[tid] += t;
    __syncthreads();
  }
  int excl = lsc[tid] - v;
  if (tid < nn){ deg[lo + tid] = v; offs[lo + tid] = es + excl; }
  __syncthreads();
  lh[tid] = es + excl;     // reuse as cursor
  __syncthreads();
  for (int i = es + tid; i < ee; i += 256){
    int2 e = ebuf[i];
    int pos = atomicAdd(&lh[e.y - lo], 1);
    csr[pos] = e.x;
  }
}

// ---------------- GIN aggregation: G[n] = P[n] + sum_{e->n} P[src] ----------------
__global__ void k_agg(const float* __restrict__ P, const int* __restrict__ csr,
                      const int* __restrict__ offs, const int* __restrict__ deg,
                      float* __restrict__ G, int n){
  int gi = blockIdx.x * blockDim.x + threadIdx.x;
  int node = gi >> 6;
  int lane = gi & 63;
  if (node >= n) return;
  int st = offs[node], cnt = deg[node];
  float self = P[(size_t)node * HDIM + lane];
  float a0 = 0.f, a1 = 0.f, a2 = 0.f, a3 = 0.f;
  for (int base = 0; base < cnt; base += 64){
    int rem = cnt - base;
    int s = (lane < rem) ? csr[st + base + lane] : 0;
    int m = min(rem, 64);
    int j = 0;
    for (; j + 4 <= m; j += 4){
      int s0 = __shfl(s, j), s1 = __shfl(s, j + 1), s2 = __shfl(s, j + 2), s3 = __shfl(s, j + 3);
      a0 += P[(size_t)s0 * HDIM + lane];
      a1 += P[(size_t)s1 * HDIM + lane];
      a2 += P[(size_t)s2 * HDIM + lane];
      a3 += P[(size_t)s3 * HDIM + lane];
    }
    for (; j < m; ++j){ int sj = __shfl(s, j); a0 += P[(size_t)sj * HDIM + lane]; }
  }
  G[(size_t)node * HDIM + lane] = self + ((a0 + a1) + (a2 + a3));
}

// ======== GIN MLP via MFMA split-bf16, 2 tiles/block, weights in LDS ========
__global__ __launch_bounds__(256, 3) void k_mlp(
    float* __restrict__ G, const int* __restrict__ batch,
    const short* __restrict__ Wall,   // [w1h|w1l|w2h|w2l] 16384 shorts
    const float* __restrict__ B1, const float* __restrict__ B2,
    float* __restrict__ stats, int N){
  __shared__ short Ws[16384];         // 32 KiB
  __shared__ short Ah[64 * APITCH];   // 9216 B
  __shared__ short Al[64 * APITCH];   // 9216 B
  __shared__ float ssum[64], ssq[64];
  int tid = threadIdx.x;

  #pragma unroll
  for (int i = 0; i < 8; i++)
    ((float4*)Ws)[i * 256 + tid] = ((const float4*)Wall)[i * 256 + tid];

  int wv = tid >> 6, lane = tid & 63;
  int quad = lane >> 4, l15 = lane & 15;
  int rbase = wv << 4;
  float bb1[4], bb2[4];
  #pragma unroll
  for (int t = 0; t < 4; t++){ bb1[t] = B1[t * 16 + l15]; bb2[t] = B2[t * 16 + l15]; }

  int tile0 = blockIdx.x << 1;
  float4 r[4], r2[4];
  {
    int tb = tile0 << 6;
    #pragma unroll
    for (int ri = 0; ri < 4; ri++){
      int idx = ri * 256 + tid;
      int node = tb + (idx >> 4), f4 = idx & 15;
      r[ri] = make_float4(0.f, 0.f, 0.f, 0.f);
      if (node < N) r[ri] = ((const float4*)G)[(size_t)node * 16 + f4];
    }
  }

  for (int tt = 0; tt < 2; tt++){
    int t0 = (tile0 + tt) << 6;      // uniform per block
    if (t0 >= N) break;

    // ---- convert regs -> bf16 hi/lo LDS planes ----
    #pragma unroll
    for (int ri = 0; ri < 4; ri++){
      int idx = ri * 256 + tid;
      int node = idx >> 4, f4 = idx & 15;
      float vv[4] = {r[ri].x, r[ri].y, r[ri].z, r[ri].w};
      short h[4], l[4];
      #pragma unroll
      for (int j = 0; j < 4; j++){
        unsigned short hh = f2bf(vv[j]);
        h[j] = (short)hh;
        l[j] = (short)f2bf(vv[j] - bf2f(hh));
      }
      *(short4*)(Ah + node * APITCH + f4 * 4) = make_short4(h[0], h[1], h[2], h[3]);
      *(short4*)(Al + node * APITCH + f4 * 4) = make_short4(l[0], l[1], l[2], l[3]);
    }
    if (tid < 64){ ssum[tid] = 0.f; ssq[tid] = 0.f; }
    __syncthreads();

    // prefetch next tile (overlaps both GEMMs)
    if (tt == 0){
      int tb = (tile0 + 1) << 6;
      #pragma unroll
      for (int ri = 0; ri < 4; ri++){
        int idx = ri * 256 + tid;
        int node = tb + (idx >> 4), f4 = idx & 15;
        r2[ri] = make_float4(0.f, 0.f, 0.f, 0.f);
        if (node < N) r2[ri] = ((const float4*)G)[(size_t)node * 16 + f4];
      }
    }

    // ---- GEMM1 ----
    f32x4 acc[4];
    #pragma unroll
    for (int t = 0; t < 4; t++) acc[t] = (f32x4){0.f, 0.f, 0.f, 0.f};
    #pragma unroll
    for (int kb = 0; kb < 2; kb++){
      int kk = kb * 32 + quad * 8;
      bf16x8 a_h = *(const bf16x8*)(Ah + (rbase + l15) * APITCH + kk);
      bf16x8 a_l = *(const bf16x8*)(Al + (rbase + l15) * APITCH + kk);
      #pragma unroll
      for (int t = 0; t < 4; t++){
        bf16x8 b_h = *(const bf16x8*)(Ws + (t * 16 + l15) * 64 + kk);
        bf16x8 b_l = *(const bf16x8*)(Ws + 4096 + (t * 16 + l15) * 64 + kk);
        acc[t] = __builtin_amdgcn_mfma_f32_16x16x32_bf16(a_h, b_h, acc[t], 0, 0, 0);
        acc[t] = __builtin_amdgcn_mfma_f32_16x16x32_bf16(a_h, b_l, acc[t], 0, 0, 0);
        acc[t] = __builtin_amdgcn_mfma_f32_16x16x32_bf16(a_l, b_h, acc[t], 0, 0, 0);
      }
    }
    __syncthreads();

    // ---- bias + relu + split (C layout -> A layout) ----
    #pragma unroll
    for (int t = 0; t < 4; t++){
      #pragma unroll
      for (int rg = 0; rg < 4; rg++){
        float v = fmaxf(acc[t][rg] + bb1[t], 0.f);
        int row = rbase + quad * 4 + rg;
        int col = t * 16 + l15;
        unsigned short hh = f2bf(v);
        Ah[row * APITCH + col] = (short)hh;
        Al[row * APITCH + col] = (short)f2bf(v - bf2f(hh));
      }
    }
    __syncthreads();

    // ---- GEMM2 ----
    f32x4 acc2[4];
    #pragma unroll
    for (int t = 0; t < 4; t++) acc2[t] = (f32x4){0.f, 0.f, 0.f, 0.f};
    #pragma unroll
    for (int kb = 0; kb < 2; kb++){
      int kk = kb * 32 + quad * 8;
      bf16x8 a_h = *(const bf16x8*)(Ah + (rbase + l15) * APITCH + kk);
      bf16x8 a_l = *(const bf16x8*)(Al + (rbase + l15) * APITCH + kk);
      #pragma unroll
      for (int t = 0; t < 4; t++){
        bf16x8 b_h = *(const bf16x8*)(Ws + 8192 + (t * 16 + l15) * 64 + kk);
        bf16x8 b_l = *(const bf16x8*)(Ws + 12288 + (t * 16 + l15) * 64 + kk);
        acc2[t] = __builtin_amdgcn_mfma_f32_16x16x32_bf16(a_h, b_h, acc2[t], 0, 0, 0);
        acc2[t] = __builtin_amdgcn_mfma_f32_16x16x32_bf16(a_h, b_l, acc2[t], 0, 0, 0);
        acc2[t] = __builtin_amdgcn_mfma_f32_16x16x32_bf16(a_l, b_h, acc2[t], 0, 0, 0);
      }
    }

    // ---- bias, store Y, stats ----
    int lastn = min(t0 + 63, N - 1);
    int g0 = batch[t0];
    bool uniform = (batch[lastn] == g0) && (t0 + 63 < N);
    #pragma unroll
    for (int t = 0; t < 4; t++){
      int f = t * 16 + l15;
      float s = 0.f, q = 0.f;
      #pragma unroll
      for (int rg = 0; rg < 4; rg++){
        float v = acc2[t][rg] + bb2[t];
        int node = t0 + rbase + quad * 4 + rg;
        if (node < N) G[(size_t)node * HDIM + f] = v;
        if (uniform){
          s += v; q += v * v;
        } else if (node < N){
          int g = batch[node];
          atomicAdd(&stats[g * 128 + f], v);
          atomicAdd(&stats[g * 128 + 64 + f], v * v);
        }
      }
      if (uniform){
        s += __shfl_xor(s, 16); s += __shfl_xor(s, 32);
        q += __shfl_xor(q, 16); q += __shfl_xor(q, 32);
        if (quad == 0){ atomicAdd(&ssum[f], s); atomicAdd(&ssq[f], q); }
      }
    }
    __syncthreads();
    if (uniform && tid < 64){
      atomicAdd(&stats[g0 * 128 + tid], ssum[tid]);
      atomicAdd(&stats[g0 * 128 + 64 + tid], ssq[tid]);
    }
    #pragma unroll
    for (int ri = 0; ri < 4; ri++) r[ri] = r2[ri];
  }
}

// ------- GraphNorm apply + relu + residual accumulate (finalize inlined) -------
__global__ void k_gn_apply(const float* __restrict__ Y, const int* __restrict__ batch,
                           const float* __restrict__ stats, const int* __restrict__ gs,
                           const float* __restrict__ w, const float* __restrict__ ms,
                           const float* __restrict__ bias,
                           float* __restrict__ C, float* __restrict__ hsum, int n16,
                           int first, int writeC){
  int i = blockIdx.x * blockDim.x + threadIdx.x;
  if (i >= n16) return;
  int node = i >> 4, q = i & 15;
  int g = batch[node];
  float cnt = (float)max(gs[g + 1] - gs[g], 1);
  float4 y  = ((const float4*)Y)[i];
  float4 s1 = ((const float4*)(stats + g * 128))[q];
  float4 s2 = ((const float4*)(stats + g * 128 + 64))[q];
  float4 wv = ((const float4*)w)[q];
  float4 mv = ((const float4*)ms)[q];
  float4 bv = ((const float4*)bias)[q];
  float4 v;
  #define APPLY1(c) { \
    float mean = s1.c / cnt; float ex2 = s2.c / cnt; \
    float var = ex2 - (2.f * mv.c - mv.c * mv.c) * mean * mean; \
    float sc = rsqrtf(var + GN_EPS) * wv.c; \
    v.c = fmaxf((y.c - mv.c * mean) * sc + bv.c, 0.f); }
  APPLY1(x) APPLY1(y) APPLY1(z) APPLY1(w)
  #undef APPLY1
  if (writeC) ((float4*)C)[i] = v;
  if (first){
    ((float4*)hsum)[i] = v;
  } else {
    float4 h = ((float4*)hsum)[i];
    h.x += v.x; h.y += v.y; h.z += v.z; h.w += v.w;
    ((float4*)hsum)[i] = h;
  }
}

// ---------------- pooling pass 1 ----------------
#define GN_NPW 32
__global__ void k_pool1(const float* __restrict__ HS, const int* __restrict__ batch,
                        const float* __restrict__ GW, const float* __restrict__ GB,
                        float* __restrict__ sumbuf, unsigned* __restrict__ maxbuf,
                        float* __restrict__ gatebuf, unsigned* __restrict__ gmaxbuf, int n){
  int wave = (int)((blockIdx.x * blockDim.x + threadIdx.x) >> 6);
  int lane = threadIdx.x & 63;
  int s = wave * GN_NPW;
  if (s >= n) return;
  int e = min(s + GN_NPW, n);
  float gwv = GW[lane];
  float gb = GB[0];
  int cur = batch[s];
  float macc = 0.f, xacc = -INFINITY, gmx = -INFINITY;
  for (int nd = s; nd < e; ++nd){
    int g = batch[nd];
    if (g != cur){
      atomicAdd(&sumbuf[cur * 64 + lane], macc);
      atomicMax(&maxbuf[cur * 64 + lane], fenc(xacc));
      if (lane == 0) atomicMax(&gmaxbuf[cur], fenc(gmx));
      macc = 0.f; xacc = -INFINITY; gmx = -INFINITY; cur = g;
    }
    float hv = HS[(size_t)nd * HDIM + lane];
    macc += hv; xacc = fmaxf(xacc, hv);
    float gv = hv * gwv;
    #pragma unroll
    for (int msk = 1; msk < 64; msk <<= 1) gv += __shfl_xor(gv, msk);
    gv += gb;
    if (lane == 0) gatebuf[nd] = gv;
    gmx = fmaxf(gmx, gv);
  }
  atomicAdd(&sumbuf[cur * 64 + lane], macc);
  atomicMax(&maxbuf[cur * 64 + lane], fenc(xacc));
  if (lane == 0) atomicMax(&gmaxbuf[cur], fenc(gmx));
}

// ---------------- pooling pass 2 ----------------
__global__ void k_pool2(const float* __restrict__ HS, const int* __restrict__ batch,
                        const float* __restrict__ gatebuf, const unsigned* __restrict__ gmaxbuf,
                        float* __restrict__ attbuf, float* __restrict__ denbuf, int n){
  int wave = (int)((blockIdx.x * blockDim.x + threadIdx.x) >> 6);
  int lane = threadIdx.x & 63;
  int s = wave * GN_NPW;
  if (s >= n) return;
  int e = min(s + GN_NPW, n);
  int cur = batch[s];
  float m = fdec(gmaxbuf[cur]);
  float aacc = 0.f, dacc = 0.f;
  for (int nd = s; nd < e; ++nd){
    int g = batch[nd];
    if (g != cur){
      atomicAdd(&attbuf[cur * 64 + lane], aacc);
      if (lane == 0) atomicAdd(&denbuf[cur], dacc);
      aacc = 0.f; dacc = 0.f; cur = g; m = fdec(gmaxbuf[cur]);
    }
    float ex = expf(gatebuf[nd] - m);
    float hv = HS[(size_t)nd * HDIM + lane];
    aacc += ex * hv; dacc += ex;
  }
  atomicAdd(&attbuf[cur * 64 + lane], aacc);
  if (lane == 0) atomicAdd(&denbuf[cur], dacc);
}

// ---------------- pooling pass 3 ----------------
__global__ void k_pool3(const float* __restrict__ attbuf, const float* __restrict__ denbuf,
                        const float* __restrict__ sumbuf, const unsigned* __restrict__ maxbuf,
                        const int* __restrict__ gs, const float* __restrict__ U,
                        const float* __restrict__ HW1, const float* __restrict__ HB1,
                        const float* __restrict__ HW2, const float* __restrict__ HB2,
                        float* __restrict__ out){
  __shared__ float z[200];
  int g = blockIdx.x;
  int tid = threadIdx.x;   // 64 threads
  float cnt = (float)max(gs[g + 1] - gs[g], 1);
  float den = denbuf[g];
  z[tid]       = attbuf[g * 64 + tid] / den;
  z[64 + tid]  = sumbuf[g * 64 + tid] / cnt;
  z[128 + tid] = fdec(maxbuf[g * 64 + tid]);
  if (tid < 3) z[192 + tid] = U[g * 3 + tid];
  __syncthreads();
  float acc = HB1[tid];
  for (int k = 0; k < 195; k++) acc += z[k] * HW1[k * 64 + tid];
  float sv = fmaxf(acc, 0.f) * HW2[tid];
  #pragma unroll
  for (int msk = 1; msk < 64; msk <<= 1) sv += __shfl_xor(sv, msk);
  if (tid == 0) out[g] = sv + HB2[0];
}

extern "C" void kernel_launch(void* const* d_in, const int* in_sizes, int n_in,
                              void* d_out, int out_size, void* d_ws, size_t ws_size,
                              hipStream_t stream){
  const float* x     = (const float*)d_in[0];
  const int*   ei    = (const int*)d_in[1];
  const int*   batch = (const int*)d_in[2];
  const float* u     = (const float*)d_in[3];
  const float* W[3][4]; const float* GNp[3][3];
  for (int l = 0; l < 3; l++){
    int base = 4 + l * 7;
    W[l][0]  = (const float*)d_in[base + 0];
    W[l][1]  = (const float*)d_in[base + 1];
    W[l][2]  = (const float*)d_in[base + 2];
    W[l][3]  = (const float*)d_in[base + 3];
    GNp[l][0]= (const float*)d_in[base + 4];
    GNp[l][1]= (const float*)d_in[base + 5];
    GNp[l][2]= (const float*)d_in[base + 6];
  }
  const float* gate_w = (const float*)d_in[25];
  const float* gate_b = (const float*)d_in[26];
  const float* hw1    = (const float*)d_in[27];
  const float* hb1    = (const float*)d_in[28];
  const float* hw2    = (const float*)d_in[29];
  const float* hb2    = (const float*)d_in[30];
  float* out = (float*)d_out;

  int N = in_sizes[0] / HDIM;
  int E = in_sizes[1] / 2;
  int B = in_sizes[3] / 3;
  const int* src = ei;
  const int* dst = ei + E;
  int NB = (N + 255) >> 8;     // <= MAXNB for N <= 131072

  char* w8 = (char*)d_ws;
  size_t NH = (size_t)N * HDIM * sizeof(float);
  auto alignup = [](size_t v){ return (v + 255) & ~(size_t)255; };
  size_t off = 0;
  float* hsum    = (float*)(w8 + off); off += alignup(NH);
  float* bufA    = (float*)(w8 + off); off += alignup(NH);
  float* bufB    = (float*)(w8 + off); off += alignup(NH);
  float* G       = (float*)(w8 + off); off += alignup(NH);
  float* gatebuf = (float*)(w8 + off); off += alignup((size_t)N * 4);
  int*   deg     = (int*)(w8 + off);   off += alignup((size_t)N * 4);
  int*   offs    = (int*)(w8 + off);   off += alignup((size_t)N * 4);
  int*   csr     = (int*)(w8 + off);   off += alignup((size_t)E * 4);
  int2*  ebuf    = (int2*)(w8 + off);  off += alignup((size_t)E * 8);
  int*   bcount  = (int*)(w8 + off);   off += alignup((size_t)(MAXNB + 1) * 4);
  int*   bbase   = (int*)(w8 + off);   off += alignup((size_t)(MAXNB + 1) * 4);
  int*   bcursor = (int*)(w8 + off);   off += alignup((size_t)(MAXNB + 1) * 4);
  float* stats   = (float*)(w8 + off); off += alignup((size_t)3 * B * 128 * 4);
  // pooled zero region (one memset): sumbuf | maxbuf | attbuf | denbuf | gmaxbuf
  float* poolz   = (float*)(w8 + off);
  size_t poolz_bytes = ((size_t)B * 64 * 3 + 2 * B) * 4;
  off += alignup(poolz_bytes);
  float*    sumbuf  = poolz;
  unsigned* maxbuf  = (unsigned*)(poolz + (size_t)B * 64);
  float*    attbuf  = poolz + (size_t)2 * B * 64;
  float*    denbuf  = poolz + (size_t)3 * B * 64;
  unsigned* gmaxbuf = (unsigned*)(poolz + (size_t)3 * B * 64 + B);
  int*   gs      = (int*)(w8 + off);   off += alignup((size_t)(B + 1) * 4);
  short* wbf     = (short*)(w8 + off); off += alignup((size_t)6 * 8192 * 2);
  (void)ws_size; (void)n_in; (void)out_size;

  hipMemsetAsync(stats, 0, (size_t)3 * B * 128 * 4, stream);
  hipMemsetAsync(poolz, 0, poolz_bytes, stream);   // 0 == below all reals in fenc order
  hipMemsetAsync(bcount, 0, (size_t)(MAXNB + 1) * 4, stream);

  const int tb = 256;
  k_prep<<<263, tb, 0, stream>>>(dst, bcount, E, NB,
                                 W[0][0], W[0][2], W[1][0], W[1][2], W[2][0], W[2][2],
                                 wbf, batch, N, gs, B);
  k_bscan<<<1, MAXNB, 0, stream>>>(bcount, bbase, bcursor, NB);
  k_breorder<<<(E + RCHUNK - 1) / RCHUNK, tb, 0, stream>>>(src, dst, bcursor, ebuf, E, NB);
  k_bucket_csr<<<NB, tb, 0, stream>>>(ebuf, bbase, deg, offs, csr, N);

  int nwaves = (N + GN_NPW - 1) / GN_NPW;
  int segblocks = (nwaves * 64 + tb - 1) / tb;
  int n16 = N * 16;
  int nblk64 = (N + 63) >> 6;
  int nblk2 = (nblk64 + 1) >> 1;

  const float* P = x;
  float* C = bufA;
  for (int l = 0; l < 3; l++){
    unsigned aggblocks = (unsigned)(((size_t)N * HDIM + 255) / 256);
    k_agg<<<aggblocks, 256, 0, stream>>>(P, csr, offs, deg, G, N);
    float* lstats = stats + (size_t)l * B * 128;
    k_mlp<<<nblk2, 256, 0, stream>>>(G, batch, wbf + (size_t)l * 16384,
                                     W[l][1], W[l][3], lstats, N);
    k_gn_apply<<<(n16 + tb - 1) / tb, tb, 0, stream>>>(G, batch, lstats, gs,
                                                       GNp[l][0], GNp[l][2], GNp[l][1],
                                                       C, hsum, n16, l == 0 ? 1 : 0,
                                                       l == 2 ? 0 : 1);
    P = C;
    C = (l == 0) ? bufB : bufA;
  }
  k_pool1<<<segblocks, tb, 0, stream>>>(hsum, batch, gate_w, gate_b,
                                        sumbuf, maxbuf, gatebuf, gmaxbuf, N);
  k_pool2<<<segblocks, tb, 0, stream>>>(hsum, batch, gatebuf, gmaxbuf, attbuf, denbuf, N);
  k_pool3<<<B, 64, 0, stream>>>(attbuf, denbuf, sumbuf, maxbuf, gs, u,
                                hw1, hb1, hw2, hb2, out);
}

// Round 8
// 548.807 us; speedup vs baseline: 1.4537x; 1.0287x over previous
//
#include <hip/hip_runtime.h>
#include <math.h>

#define HDIM 64
#define GN_EPS 1e-5f
#define MAXNB 512          // supports N <= 131072 (bucket = 256 nodes)
#define APITCH 72

typedef __attribute__((ext_vector_type(8))) short bf16x8;
typedef __attribute__((ext_vector_type(4))) float f32x4;

__device__ __forceinline__ int lower_bound_i(const int* a, int n, int key){
  int lo = 0, hi = n;
  while (lo < hi){ int mid = (lo + hi) >> 1; if (a[mid] < key) lo = mid + 1; else hi = mid; }
  return lo;
}

// ordered-uint encoding for float atomicMax
__device__ __forceinline__ unsigned fenc(float x){
  unsigned b = __float_as_uint(x);
  return (b & 0x80000000u) ? ~b : (b | 0x80000000u);
}
__device__ __forceinline__ float fdec(unsigned u){
  unsigned b = (u & 0x80000000u) ? (u ^ 0x80000000u) : ~u;
  return __uint_as_float(b);
}

// bf16 round-to-nearest-even helpers
__device__ __forceinline__ unsigned short f2bf(float f){
  unsigned u = __float_as_uint(f);
  u += 0x7fffu + ((u >> 16) & 1u);
  return (unsigned short)(u >> 16);
}
__device__ __forceinline__ float bf2f(unsigned short h){
  return __uint_as_float(((unsigned)h) << 16);
}

// ======= prep: bucket histogram (blocks 0-255) + weight split (256-261) + gstart (262)
__global__ void k_prep(const int* __restrict__ dst, int* __restrict__ bcount, int E, int NB,
                       const float* __restrict__ Wa0, const float* __restrict__ Wb0,
                       const float* __restrict__ Wa1, const float* __restrict__ Wb1,
                       const float* __restrict__ Wa2, const float* __restrict__ Wb2,
                       short* __restrict__ wbf,
                       const int* __restrict__ batch, int N, int* __restrict__ gs, int B){
  int tid = threadIdx.x;
  if (blockIdx.x < 256){
    __shared__ int lh[MAXNB];
    for (int b = tid; b < NB; b += 256) lh[b] = 0;
    __syncthreads();
    for (int i = blockIdx.x * 256 + tid; i < E; i += 256 * 256)
      atomicAdd(&lh[dst[i] >> 8], 1);
    __syncthreads();
    for (int b = tid; b < NB; b += 256){ int c = lh[b]; if (c) atomicAdd(&bcount[b], c); }
  } else if (blockIdx.x < 262){
    int wi = blockIdx.x - 256;
    const float* Wsrc[6] = {Wa0, Wb0, Wa1, Wb1, Wa2, Wb2};
    const float* W = Wsrc[wi];
    short* hi = wbf + wi * 8192;
    short* lo = hi + 4096;
    for (int i = tid; i < 4096; i += 256){
      int k = i >> 6, j = i & 63;            // W[k][j], coalesced read
      float v = W[i];
      unsigned short h = f2bf(v);
      hi[j * 64 + k] = (short)h;             // transposed: Wt[j][k]
      lo[j * 64 + k] = (short)f2bf(v - bf2f(h));
    }
  } else {
    for (int g = tid; g <= B; g += 256) gs[g] = lower_bound_i(batch, N, g);
  }
}

// ---------------- pass B: scan bucket counts ----------------
__global__ void k_bscan(const int* __restrict__ bcount, int* __restrict__ bbase,
                        int* __restrict__ bcursor, int NB){
  __shared__ int sd[MAXNB];
  int tid = threadIdx.x;   // 512 threads
  int v = (tid < NB) ? bcount[tid] : 0;
  sd[tid] = v; __syncthreads();
  for (int o = 1; o < MAXNB; o <<= 1){
    int t = (tid >= o) ? sd[tid - o] : 0;
    __syncthreads();
    sd[tid] += t;
    __syncthreads();
  }
  int excl = sd[tid] - v;
  if (tid < NB){ bbase[tid] = excl; bcursor[tid] = excl; }
  if (tid == NB - 1) bbase[NB] = excl + v;
}

// ---------------- pass C: reorder edges into bucket-grouped ebuf ----------------
#define RCHUNK 8192
__global__ void k_breorder(const int* __restrict__ src, const int* __restrict__ dst,
                           int* __restrict__ bcursor, int2* __restrict__ ebuf, int E, int NB){
  __shared__ int lh[MAXNB];
  __shared__ int lbase[MAXNB];
  int tid = threadIdx.x;   // 256
  int c0 = blockIdx.x * RCHUNK;
  for (int b = tid; b < NB; b += 256) lh[b] = 0;
  __syncthreads();
  for (int j = 0; j < RCHUNK / 256; j++){
    int i = c0 + j * 256 + tid;
    if (i < E) atomicAdd(&lh[dst[i] >> 8], 1);
  }
  __syncthreads();
  for (int b = tid; b < NB; b += 256){
    int c = lh[b];
    lbase[b] = c ? atomicAdd(&bcursor[b], c) : 0;
    lh[b] = 0;
  }
  __syncthreads();
  for (int j = 0; j < RCHUNK / 256; j++){
    int i = c0 + j * 256 + tid;
    if (i < E){
      int d = dst[i]; int b = d >> 8;
      int r = atomicAdd(&lh[b], 1);
      ebuf[lbase[b] + r] = make_int2(src[i], d);
    }
  }
}

// ---------------- pass D: per-bucket counting sort -> csr/deg/offs ----------------
__global__ void k_bucket_csr(const int2* __restrict__ ebuf, const int* __restrict__ bbase,
                             int* __restrict__ deg, int* __restrict__ offs,
                             int* __restrict__ csr, int N){
  __shared__ int lh[256];
  __shared__ int lsc[256];
  int b = blockIdx.x;
  int lo = b << 8;
  int nn = min(256, N - lo);
  int tid = threadIdx.x;   // 256
  lh[tid] = 0; __syncthreads();
  int es = bbase[b], ee = bbase[b + 1];
  for (int i = es + tid; i < ee; i += 256) atomicAdd(&lh[ebuf[i].y - lo], 1);
  __syncthreads();
  int v = lh[tid];
  lsc[tid] = v; __syncthreads();
  for (int o = 1; o < 256; o <<= 1){
    int t = (tid >= o) ? lsc[tid - o] : 0;
    __syncthreads();
    lsc[tid] += t;
    __syncthreads();
  }
  int excl = lsc[tid] - v;
  if (tid < nn){ deg[lo + tid] = v; offs[lo + tid] = es + excl; }
  __syncthreads();
  lh[tid] = es + excl;     // reuse as cursor
  __syncthreads();
  for (int i = es + tid; i < ee; i += 256){
    int2 e = ebuf[i];
    int pos = atomicAdd(&lh[e.y - lo], 1);
    csr[pos] = e.x;
  }
}

// ------- GIN aggregation v2: 4 nodes/wave, 16 lanes/node, float4/lane -------
__global__ __launch_bounds__(256) void k_agg(
    const float* __restrict__ P, const int* __restrict__ csr,
    const int* __restrict__ offs, const int* __restrict__ deg,
    float* __restrict__ G, int n){
  int tid = threadIdx.x;
  int wave_id = blockIdx.x * 4 + (tid >> 6);
  int lane = tid & 63;
  int sub = lane >> 4, l16 = lane & 15;
  int node = wave_id * 4 + sub;
  bool ok = node < n;
  int st = 0, cnt = 0;
  if (ok){ st = offs[node]; cnt = deg[node]; }
  const float4* Pf4 = (const float4*)P;
  float4 a0 = make_float4(0.f, 0.f, 0.f, 0.f);
  float4 a1 = a0, a2 = a0, a3 = a0;
  if (ok) a0 = Pf4[(size_t)node * 16 + l16];      // self term
  int sbase = sub << 4;
  for (int base = 0; base < cnt; base += 16){
    int rem = cnt - base;
    int s = (l16 < rem) ? csr[st + base + l16] : 0;
    int m = min(rem, 16);
    int j = 0;
    for (; j + 4 <= m; j += 4){
      int s0 = __shfl(s, sbase | j);
      int s1 = __shfl(s, sbase | (j + 1));
      int s2 = __shfl(s, sbase | (j + 2));
      int s3 = __shfl(s, sbase | (j + 3));
      float4 v0 = Pf4[(size_t)s0 * 16 + l16];
      float4 v1 = Pf4[(size_t)s1 * 16 + l16];
      float4 v2 = Pf4[(size_t)s2 * 16 + l16];
      float4 v3 = Pf4[(size_t)s3 * 16 + l16];
      a0.x += v0.x; a0.y += v0.y; a0.z += v0.z; a0.w += v0.w;
      a1.x += v1.x; a1.y += v1.y; a1.z += v1.z; a1.w += v1.w;
      a2.x += v2.x; a2.y += v2.y; a2.z += v2.z; a2.w += v2.w;
      a3.x += v3.x; a3.y += v3.y; a3.z += v3.z; a3.w += v3.w;
    }
    for (; j < m; ++j){
      int sj = __shfl(s, sbase | j);
      float4 v = Pf4[(size_t)sj * 16 + l16];
      a0.x += v.x; a0.y += v.y; a0.z += v.z; a0.w += v.w;
    }
  }
  if (ok){
    float4 r;
    r.x = (a0.x + a1.x) + (a2.x + a3.x);
    r.y = (a0.y + a1.y) + (a2.y + a3.y);
    r.z = (a0.z + a1.z) + (a2.z + a3.z);
    r.w = (a0.w + a1.w) + (a2.w + a3.w);
    ((float4*)G)[(size_t)node * 16 + l16] = r;
  }
}

// ======== GIN MLP via MFMA split-bf16, 2 tiles/block, weights in LDS ========
__global__ __launch_bounds__(256, 3) void k_mlp(
    float* __restrict__ G, const int* __restrict__ batch,
    const short* __restrict__ Wall,   // [w1h|w1l|w2h|w2l] 16384 shorts
    const float* __restrict__ B1, const float* __restrict__ B2,
    float* __restrict__ stats, int N){
  __shared__ short Ws[16384];         // 32 KiB
  __shared__ short Ah[64 * APITCH];   // 9216 B
  __shared__ short Al[64 * APITCH];   // 9216 B
  __shared__ float ssum[64], ssq[64];
  int tid = threadIdx.x;

  #pragma unroll
  for (int i = 0; i < 8; i++)
    ((float4*)Ws)[i * 256 + tid] = ((const float4*)Wall)[i * 256 + tid];

  int wv = tid >> 6, lane = tid & 63;
  int quad = lane >> 4, l15 = lane & 15;
  int rbase = wv << 4;
  float bb1[4], bb2[4];
  #pragma unroll
  for (int t = 0; t < 4; t++){ bb1[t] = B1[t * 16 + l15]; bb2[t] = B2[t * 16 + l15]; }

  int tile0 = blockIdx.x << 1;
  float4 r[4], r2[4];
  {
    int tb = tile0 << 6;
    #pragma unroll
    for (int ri = 0; ri < 4; ri++){
      int idx = ri * 256 + tid;
      int node = tb + (idx >> 4), f4 = idx & 15;
      r[ri] = make_float4(0.f, 0.f, 0.f, 0.f);
      if (node < N) r[ri] = ((const float4*)G)[(size_t)node * 16 + f4];
    }
  }

  for (int tt = 0; tt < 2; tt++){
    int t0 = (tile0 + tt) << 6;      // uniform per block
    if (t0 >= N) break;

    // ---- convert regs -> bf16 hi/lo LDS planes ----
    #pragma unroll
    for (int ri = 0; ri < 4; ri++){
      int idx = ri * 256 + tid;
      int node = idx >> 4, f4 = idx & 15;
      float vv[4] = {r[ri].x, r[ri].y, r[ri].z, r[ri].w};
      short h[4], l[4];
      #pragma unroll
      for (int j = 0; j < 4; j++){
        unsigned short hh = f2bf(vv[j]);
        h[j] = (short)hh;
        l[j] = (short)f2bf(vv[j] - bf2f(hh));
      }
      *(short4*)(Ah + node * APITCH + f4 * 4) = make_short4(h[0], h[1], h[2], h[3]);
      *(short4*)(Al + node * APITCH + f4 * 4) = make_short4(l[0], l[1], l[2], l[3]);
    }
    if (tid < 64){ ssum[tid] = 0.f; ssq[tid] = 0.f; }
    __syncthreads();

    // prefetch next tile (overlaps both GEMMs)
    if (tt == 0){
      int tb = (tile0 + 1) << 6;
      #pragma unroll
      for (int ri = 0; ri < 4; ri++){
        int idx = ri * 256 + tid;
        int node = tb + (idx >> 4), f4 = idx & 15;
        r2[ri] = make_float4(0.f, 0.f, 0.f, 0.f);
        if (node < N) r2[ri] = ((const float4*)G)[(size_t)node * 16 + f4];
      }
    }

    // ---- GEMM1 ----
    f32x4 acc[4];
    #pragma unroll
    for (int t = 0; t < 4; t++) acc[t] = (f32x4){0.f, 0.f, 0.f, 0.f};
    #pragma unroll
    for (int kb = 0; kb < 2; kb++){
      int kk = kb * 32 + quad * 8;
      bf16x8 a_h = *(const bf16x8*)(Ah + (rbase + l15) * APITCH + kk);
      bf16x8 a_l = *(const bf16x8*)(Al + (rbase + l15) * APITCH + kk);
      #pragma unroll
      for (int t = 0; t < 4; t++){
        bf16x8 b_h = *(const bf16x8*)(Ws + (t * 16 + l15) * 64 + kk);
        bf16x8 b_l = *(const bf16x8*)(Ws + 4096 + (t * 16 + l15) * 64 + kk);
        acc[t] = __builtin_amdgcn_mfma_f32_16x16x32_bf16(a_h, b_h, acc[t], 0, 0, 0);
        acc[t] = __builtin_amdgcn_mfma_f32_16x16x32_bf16(a_h, b_l, acc[t], 0, 0, 0);
        acc[t] = __builtin_amdgcn_mfma_f32_16x16x32_bf16(a_l, b_h, acc[t], 0, 0, 0);
      }
    }
    __syncthreads();

    // ---- bias + relu + split (C layout -> A layout) ----
    #pragma unroll
    for (int t = 0; t < 4; t++){
      #pragma unroll
      for (int rg = 0; rg < 4; rg++){
        float v = fmaxf(acc[t][rg] + bb1[t], 0.f);
        int row = rbase + quad * 4 + rg;
        int col = t * 16 + l15;
        unsigned short hh = f2bf(v);
        Ah[row * APITCH + col] = (short)hh;
        Al[row * APITCH + col] = (short)f2bf(v - bf2f(hh));
      }
    }
    __syncthreads();

    // ---- GEMM2 ----
    f32x4 acc2[4];
    #pragma unroll
    for (int t = 0; t < 4; t++) acc2[t] = (f32x4){0.f, 0.f, 0.f, 0.f};
    #pragma unroll
    for (int kb = 0; kb < 2; kb++){
      int kk = kb * 32 + quad * 8;
      bf16x8 a_h = *(const bf16x8*)(Ah + (rbase + l15) * APITCH + kk);
      bf16x8 a_l = *(const bf16x8*)(Al + (rbase + l15) * APITCH + kk);
      #pragma unroll
      for (int t = 0; t < 4; t++){
        bf16x8 b_h = *(const bf16x8*)(Ws + 8192 + (t * 16 + l15) * 64 + kk);
        bf16x8 b_l = *(const bf16x8*)(Ws + 12288 + (t * 16 + l15) * 64 + kk);
        acc2[t] = __builtin_amdgcn_mfma_f32_16x16x32_bf16(a_h, b_h, acc2[t], 0, 0, 0);
        acc2[t] = __builtin_amdgcn_mfma_f32_16x16x32_bf16(a_h, b_l, acc2[t], 0, 0, 0);
        acc2[t] = __builtin_amdgcn_mfma_f32_16x16x32_bf16(a_l, b_h, acc2[t], 0, 0, 0);
      }
    }

    // ---- bias, store Y, stats ----
    int lastn = min(t0 + 63, N - 1);
    int g0 = batch[t0];
    bool uniform = (batch[lastn] == g0) && (t0 + 63 < N);
    #pragma unroll
    for (int t = 0; t < 4; t++){
      int f = t * 16 + l15;
      float s = 0.f, q = 0.f;
      #pragma unroll
      for (int rg = 0; rg < 4; rg++){
        float v = acc2[t][rg] + bb2[t];
        int node = t0 + rbase + quad * 4 + rg;
        if (node < N) G[(size_t)node * HDIM + f] = v;
        if (uniform){
          s += v; q += v * v;
        } else if (node < N){
          int g = batch[node];
          atomicAdd(&stats[g * 128 + f], v);
          atomicAdd(&stats[g * 128 + 64 + f], v * v);
        }
      }
      if (uniform){
        s += __shfl_xor(s, 16); s += __shfl_xor(s, 32);
        q += __shfl_xor(q, 16); q += __shfl_xor(q, 32);
        if (quad == 0){ atomicAdd(&ssum[f], s); atomicAdd(&ssq[f], q); }
      }
    }
    __syncthreads();
    if (uniform && tid < 64){
      atomicAdd(&stats[g0 * 128 + tid], ssum[tid]);
      atomicAdd(&stats[g0 * 128 + 64 + tid], ssq[tid]);
    }
    #pragma unroll
    for (int ri = 0; ri < 4; ri++) r[ri] = r2[ri];
  }
}

// ------- GraphNorm apply + relu + residual accumulate (finalize inlined) -------
__global__ void k_gn_apply(const float* __restrict__ Y, const int* __restrict__ batch,
                           const float* __restrict__ stats, const int* __restrict__ gs,
                           const float* __restrict__ w, const float* __restrict__ ms,
                           const float* __restrict__ bias,
                           float* __restrict__ C, float* __restrict__ hsum, int n16,
                           int first, int writeC){
  int i = blockIdx.x * blockDim.x + threadIdx.x;
  if (i >= n16) return;
  int node = i >> 4, q = i & 15;
  int g = batch[node];
  float cnt = (float)max(gs[g + 1] - gs[g], 1);
  float4 y  = ((const float4*)Y)[i];
  float4 s1 = ((const float4*)(stats + g * 128))[q];
  float4 s2 = ((const float4*)(stats + g * 128 + 64))[q];
  float4 wv = ((const float4*)w)[q];
  float4 mv = ((const float4*)ms)[q];
  float4 bv = ((const float4*)bias)[q];
  float4 v;
  #define APPLY1(c) { \
    float mean = s1.c / cnt; float ex2 = s2.c / cnt; \
    float var = ex2 - (2.f * mv.c - mv.c * mv.c) * mean * mean; \
    float sc = rsqrtf(var + GN_EPS) * wv.c; \
    v.c = fmaxf((y.c - mv.c * mean) * sc + bv.c, 0.f); }
  APPLY1(x) APPLY1(y) APPLY1(z) APPLY1(w)
  #undef APPLY1
  if (writeC) ((float4*)C)[i] = v;
  if (first){
    ((float4*)hsum)[i] = v;
  } else {
    float4 h = ((float4*)hsum)[i];
    h.x += v.x; h.y += v.y; h.z += v.z; h.w += v.w;
    ((float4*)hsum)[i] = h;
  }
}

// ---------------- pooling pass 1 ----------------
#define GN_NPW 32
__global__ void k_pool1(const float* __restrict__ HS, const int* __restrict__ batch,
                        const float* __restrict__ GW, const float* __restrict__ GB,
                        float* __restrict__ sumbuf, unsigned* __restrict__ maxbuf,
                        float* __restrict__ gatebuf, unsigned* __restrict__ gmaxbuf, int n){
  int wave = (int)((blockIdx.x * blockDim.x + threadIdx.x) >> 6);
  int lane = threadIdx.x & 63;
  int s = wave * GN_NPW;
  if (s >= n) return;
  int e = min(s + GN_NPW, n);
  float gwv = GW[lane];
  float gb = GB[0];
  int cur = batch[s];
  float macc = 0.f, xacc = -INFINITY, gmx = -INFINITY;
  for (int nd = s; nd < e; ++nd){
    int g = batch[nd];
    if (g != cur){
      atomicAdd(&sumbuf[cur * 64 + lane], macc);
      atomicMax(&maxbuf[cur * 64 + lane], fenc(xacc));
      if (lane == 0) atomicMax(&gmaxbuf[cur], fenc(gmx));
      macc = 0.f; xacc = -INFINITY; gmx = -INFINITY; cur = g;
    }
    float hv = HS[(size_t)nd * HDIM + lane];
    macc += hv; xacc = fmaxf(xacc, hv);
    float gv = hv * gwv;
    #pragma unroll
    for (int msk = 1; msk < 64; msk <<= 1) gv += __shfl_xor(gv, msk);
    gv += gb;
    if (lane == 0) gatebuf[nd] = gv;
    gmx = fmaxf(gmx, gv);
  }
  atomicAdd(&sumbuf[cur * 64 + lane], macc);
  atomicMax(&maxbuf[cur * 64 + lane], fenc(xacc));
  if (lane == 0) atomicMax(&gmaxbuf[cur], fenc(gmx));
}

// ---------------- pooling pass 2 ----------------
__global__ void k_pool2(const float* __restrict__ HS, const int* __restrict__ batch,
                        const float* __restrict__ gatebuf, const unsigned* __restrict__ gmaxbuf,
                        float* __restrict__ attbuf, float* __restrict__ denbuf, int n){
  int wave = (int)((blockIdx.x * blockDim.x + threadIdx.x) >> 6);
  int lane = threadIdx.x & 63;
  int s = wave * GN_NPW;
  if (s >= n) return;
  int e = min(s + GN_NPW, n);
  int cur = batch[s];
  float m = fdec(gmaxbuf[cur]);
  float aacc = 0.f, dacc = 0.f;
  for (int nd = s; nd < e; ++nd){
    int g = batch[nd];
    if (g != cur){
      atomicAdd(&attbuf[cur * 64 + lane], aacc);
      if (lane == 0) atomicAdd(&denbuf[cur], dacc);
      aacc = 0.f; dacc = 0.f; cur = g; m = fdec(gmaxbuf[cur]);
    }
    float ex = expf(gatebuf[nd] - m);
    float hv = HS[(size_t)nd * HDIM + lane];
    aacc += ex * hv; dacc += ex;
  }
  atomicAdd(&attbuf[cur * 64 + lane], aacc);
  if (lane == 0) atomicAdd(&denbuf[cur], dacc);
}

// ---------------- pooling pass 3 ----------------
__global__ void k_pool3(const float* __restrict__ attbuf, const float* __restrict__ denbuf,
                        const float* __restrict__ sumbuf, const unsigned* __restrict__ maxbuf,
                        const int* __restrict__ gs, const float* __restrict__ U,
                        const float* __restrict__ HW1, const float* __restrict__ HB1,
                        const float* __restrict__ HW2, const float* __restrict__ HB2,
                        float* __restrict__ out){
  __shared__ float z[200];
  int g = blockIdx.x;
  int tid = threadIdx.x;   // 64 threads
  float cnt = (float)max(gs[g + 1] - gs[g], 1);
  float den = denbuf[g];
  z[tid]       = attbuf[g * 64 + tid] / den;
  z[64 + tid]  = sumbuf[g * 64 + tid] / cnt;
  z[128 + tid] = fdec(maxbuf[g * 64 + tid]);
  if (tid < 3) z[192 + tid] = U[g * 3 + tid];
  __syncthreads();
  float acc = HB1[tid];
  for (int k = 0; k < 195; k++) acc += z[k] * HW1[k * 64 + tid];
  float sv = fmaxf(acc, 0.f) * HW2[tid];
  #pragma unroll
  for (int msk = 1; msk < 64; msk <<= 1) sv += __shfl_xor(sv, msk);
  if (tid == 0) out[g] = sv + HB2[0];
}

extern "C" void kernel_launch(void* const* d_in, const int* in_sizes, int n_in,
                              void* d_out, int out_size, void* d_ws, size_t ws_size,
                              hipStream_t stream){
  const float* x     = (const float*)d_in[0];
  const int*   ei    = (const int*)d_in[1];
  const int*   batch = (const int*)d_in[2];
  const float* u     = (const float*)d_in[3];
  const float* W[3][4]; const float* GNp[3][3];
  for (int l = 0; l < 3; l++){
    int base = 4 + l * 7;
    W[l][0]  = (const float*)d_in[base + 0];
    W[l][1]  = (const float*)d_in[base + 1];
    W[l][2]  = (const float*)d_in[base + 2];
    W[l][3]  = (const float*)d_in[base + 3];
    GNp[l][0]= (const float*)d_in[base + 4];
    GNp[l][1]= (const float*)d_in[base + 5];
    GNp[l][2]= (const float*)d_in[base + 6];
  }
  const float* gate_w = (const float*)d_in[25];
  const float* gate_b = (const float*)d_in[26];
  const float* hw1    = (const float*)d_in[27];
  const float* hb1    = (const float*)d_in[28];
  const float* hw2    = (const float*)d_in[29];
  const float* hb2    = (const float*)d_in[30];
  float* out = (float*)d_out;

  int N = in_sizes[0] / HDIM;
  int E = in_sizes[1] / 2;
  int B = in_sizes[3] / 3;
  const int* src = ei;
  const int* dst = ei + E;
  int NB = (N + 255) >> 8;     // <= MAXNB for N <= 131072

  char* w8 = (char*)d_ws;
  size_t NH = (size_t)N * HDIM * sizeof(float);
  auto alignup = [](size_t v){ return (v + 255) & ~(size_t)255; };
  size_t off = 0;
  float* hsum    = (float*)(w8 + off); off += alignup(NH);
  float* bufA    = (float*)(w8 + off); off += alignup(NH);
  float* bufB    = (float*)(w8 + off); off += alignup(NH);
  float* G       = (float*)(w8 + off); off += alignup(NH);
  float* gatebuf = (float*)(w8 + off); off += alignup((size_t)N * 4);
  int*   deg     = (int*)(w8 + off);   off += alignup((size_t)N * 4);
  int*   offs    = (int*)(w8 + off);   off += alignup((size_t)N * 4);
  int*   csr     = (int*)(w8 + off);   off += alignup((size_t)E * 4);
  int2*  ebuf    = (int2*)(w8 + off);  off += alignup((size_t)E * 8);
  int*   bcount  = (int*)(w8 + off);   off += alignup((size_t)(MAXNB + 1) * 4);
  int*   bbase   = (int*)(w8 + off);   off += alignup((size_t)(MAXNB + 1) * 4);
  int*   bcursor = (int*)(w8 + off);   off += alignup((size_t)(MAXNB + 1) * 4);
  float* stats   = (float*)(w8 + off); off += alignup((size_t)3 * B * 128 * 4);
  // pooled zero region (one memset): sumbuf | maxbuf | attbuf | denbuf | gmaxbuf
  float* poolz   = (float*)(w8 + off);
  size_t poolz_bytes = ((size_t)B * 64 * 3 + 2 * B) * 4;
  off += alignup(poolz_bytes);
  float*    sumbuf  = poolz;
  unsigned* maxbuf  = (unsigned*)(poolz + (size_t)B * 64);
  float*    attbuf  = poolz + (size_t)2 * B * 64;
  float*    denbuf  = poolz + (size_t)3 * B * 64;
  unsigned* gmaxbuf = (unsigned*)(poolz + (size_t)3 * B * 64 + B);
  int*   gs      = (int*)(w8 + off);   off += alignup((size_t)(B + 1) * 4);
  short* wbf     = (short*)(w8 + off); off += alignup((size_t)6 * 8192 * 2);
  (void)ws_size; (void)n_in; (void)out_size;

  hipMemsetAsync(stats, 0, (size_t)3 * B * 128 * 4, stream);
  hipMemsetAsync(poolz, 0, poolz_bytes, stream);   // 0 == below all reals in fenc order
  hipMemsetAsync(bcount, 0, (size_t)(MAXNB + 1) * 4, stream);

  const int tb = 256;
  k_prep<<<263, tb, 0, stream>>>(dst, bcount, E, NB,
                                 W[0][0], W[0][2], W[1][0], W[1][2], W[2][0], W[2][2],
                                 wbf, batch, N, gs, B);
  k_bscan<<<1, MAXNB, 0, stream>>>(bcount, bbase, bcursor, NB);
  k_breorder<<<(E + RCHUNK - 1) / RCHUNK, tb, 0, stream>>>(src, dst, bcursor, ebuf, E, NB);
  k_bucket_csr<<<NB, tb, 0, stream>>>(ebuf, bbase, deg, offs, csr, N);

  int nwaves = (N + GN_NPW - 1) / GN_NPW;
  int segblocks = (nwaves * 64 + tb - 1) / tb;
  int n16 = N * 16;
  int nblk64 = (N + 63) >> 6;
  int nblk2 = (nblk64 + 1) >> 1;
  int aggwaves = (N + 3) >> 2;
  int aggblocks = (aggwaves + 3) >> 2;   // 4 waves per block

  const float* P = x;
  float* C = bufA;
  for (int l = 0; l < 3; l++){
    k_agg<<<aggblocks, 256, 0, stream>>>(P, csr, offs, deg, G, N);
    float* lstats = stats + (size_t)l * B * 128;
    k_mlp<<<nblk2, 256, 0, stream>>>(G, batch, wbf + (size_t)l * 16384,
                                     W[l][1], W[l][3], lstats, N);
    k_gn_apply<<<(n16 + tb - 1) / tb, tb, 0, stream>>>(G, batch, lstats, gs,
                                                       GNp[l][0], GNp[l][2], GNp[l][1],
                                                       C, hsum, n16, l == 0 ? 1 : 0,
                                                       l == 2 ? 0 : 1);
    P = C;
    C = (l == 0) ? bufB : bufA;
  }
  k_pool1<<<segblocks, tb, 0, stream>>>(hsum, batch, gate_w, gate_b,
                                        sumbuf, maxbuf, gatebuf, gmaxbuf, N);
  k_pool2<<<segblocks, tb, 0, stream>>>(hsum, batch, gatebuf, gmaxbuf, attbuf, denbuf, N);
  k_pool3<<<B, 64, 0, stream>>>(attbuf, denbuf, sumbuf, maxbuf, gs, u,
                                hw1, hb1, hw2, hb2, out);
}

// Round 9
// 496.055 us; speedup vs baseline: 1.6083x; 1.1063x over previous
//
#include <hip/hip_runtime.h>
#include <math.h>

#define HDIM 64
#define GN_EPS 1e-5f
#define MAXNB 512          // supports N <= 131072 (bucket = 256 nodes)
#define APITCH 72

typedef __attribute__((ext_vector_type(8))) short bf16x8;
typedef __attribute__((ext_vector_type(4))) float f32x4;

__device__ __forceinline__ int lower_bound_i(const int* a, int n, int key){
  int lo = 0, hi = n;
  while (lo < hi){ int mid = (lo + hi) >> 1; if (a[mid] < key) lo = mid + 1; else hi = mid; }
  return lo;
}

// ordered-uint encoding for float atomicMax
__device__ __forceinline__ unsigned fenc(float x){
  unsigned b = __float_as_uint(x);
  return (b & 0x80000000u) ? ~b : (b | 0x80000000u);
}
__device__ __forceinline__ float fdec(unsigned u){
  unsigned b = (u & 0x80000000u) ? (u ^ 0x80000000u) : ~u;
  return __uint_as_float(b);
}

// bf16 round-to-nearest-even helpers
__device__ __forceinline__ unsigned short f2bf(float f){
  unsigned u = __float_as_uint(f);
  u += 0x7fffu + ((u >> 16) & 1u);
  return (unsigned short)(u >> 16);
}
__device__ __forceinline__ float bf2f(unsigned short h){
  return __uint_as_float(((unsigned)h) << 16);
}

// accumulate 8 bf16 (packed in uint4) into 8 f32
__device__ __forceinline__ void addbf(float* a, uint4 v){
  a[0] += __uint_as_float(v.x << 16);
  a[1] += __uint_as_float(v.x & 0xffff0000u);
  a[2] += __uint_as_float(v.y << 16);
  a[3] += __uint_as_float(v.y & 0xffff0000u);
  a[4] += __uint_as_float(v.z << 16);
  a[5] += __uint_as_float(v.z & 0xffff0000u);
  a[6] += __uint_as_float(v.w << 16);
  a[7] += __uint_as_float(v.w & 0xffff0000u);
}

// ======= prep: bucket histogram (blocks 0-255) + weight split (256-261) + gstart (262)
__global__ void k_prep(const int* __restrict__ dst, int* __restrict__ bcount, int E, int NB,
                       const float* __restrict__ Wa0, const float* __restrict__ Wb0,
                       const float* __restrict__ Wa1, const float* __restrict__ Wb1,
                       const float* __restrict__ Wa2, const float* __restrict__ Wb2,
                       short* __restrict__ wbf,
                       const int* __restrict__ batch, int N, int* __restrict__ gs, int B){
  int tid = threadIdx.x;
  if (blockIdx.x < 256){
    __shared__ int lh[MAXNB];
    for (int b = tid; b < NB; b += 256) lh[b] = 0;
    __syncthreads();
    for (int i = blockIdx.x * 256 + tid; i < E; i += 256 * 256)
      atomicAdd(&lh[dst[i] >> 8], 1);
    __syncthreads();
    for (int b = tid; b < NB; b += 256){ int c = lh[b]; if (c) atomicAdd(&bcount[b], c); }
  } else if (blockIdx.x < 262){
    int wi = blockIdx.x - 256;
    const float* Wsrc[6] = {Wa0, Wb0, Wa1, Wb1, Wa2, Wb2};
    const float* W = Wsrc[wi];
    short* hi = wbf + wi * 8192;
    short* lo = hi + 4096;
    for (int i = tid; i < 4096; i += 256){
      int k = i >> 6, j = i & 63;            // W[k][j], coalesced read
      float v = W[i];
      unsigned short h = f2bf(v);
      hi[j * 64 + k] = (short)h;             // transposed: Wt[j][k]
      lo[j * 64 + k] = (short)f2bf(v - bf2f(h));
    }
  } else {
    for (int g = tid; g <= B; g += 256) gs[g] = lower_bound_i(batch, N, g);
  }
}

// ---------------- convert x -> bf16 ----------------
__global__ void k_cvt(const float* __restrict__ x, unsigned short* __restrict__ xb, int n16){
  int i = blockIdx.x * blockDim.x + threadIdx.x;
  if (i >= n16) return;
  float4 v = ((const float4*)x)[i];
  ushort4 o;
  o.x = f2bf(v.x); o.y = f2bf(v.y); o.z = f2bf(v.z); o.w = f2bf(v.w);
  ((ushort4*)xb)[i] = o;
}

// ---------------- pass B: scan bucket counts ----------------
__global__ void k_bscan(const int* __restrict__ bcount, int* __restrict__ bbase,
                        int* __restrict__ bcursor, int NB){
  __shared__ int sd[MAXNB];
  int tid = threadIdx.x;   // 512 threads
  int v = (tid < NB) ? bcount[tid] : 0;
  sd[tid] = v; __syncthreads();
  for (int o = 1; o < MAXNB; o <<= 1){
    int t = (tid >= o) ? sd[tid - o] : 0;
    __syncthreads();
    sd[tid] += t;
    __syncthreads();
  }
  int excl = sd[tid] - v;
  if (tid < NB){ bbase[tid] = excl; bcursor[tid] = excl; }
  if (tid == NB - 1) bbase[NB] = excl + v;
}

// ---------------- pass C: reorder edges into bucket-grouped ebuf ----------------
#define RCHUNK 8192
__global__ void k_breorder(const int* __restrict__ src, const int* __restrict__ dst,
                           int* __restrict__ bcursor, int2* __restrict__ ebuf, int E, int NB){
  __shared__ int lh[MAXNB];
  __shared__ int lbase[MAXNB];
  int tid = threadIdx.x;   // 256
  int c0 = blockIdx.x * RCHUNK;
  for (int b = tid; b < NB; b += 256) lh[b] = 0;
  __syncthreads();
  for (int j = 0; j < RCHUNK / 256; j++){
    int i = c0 + j * 256 + tid;
    if (i < E) atomicAdd(&lh[dst[i] >> 8], 1);
  }
  __syncthreads();
  for (int b = tid; b < NB; b += 256){
    int c = lh[b];
    lbase[b] = c ? atomicAdd(&bcursor[b], c) : 0;
    lh[b] = 0;
  }
  __syncthreads();
  for (int j = 0; j < RCHUNK / 256; j++){
    int i = c0 + j * 256 + tid;
    if (i < E){
      int d = dst[i]; int b = d >> 8;
      int r = atomicAdd(&lh[b], 1);
      ebuf[lbase[b] + r] = make_int2(src[i], d);
    }
  }
}

// ---------------- pass D: per-bucket counting sort -> csr/deg/offs ----------------
__global__ void k_bucket_csr(const int2* __restrict__ ebuf, const int* __restrict__ bbase,
                             int* __restrict__ deg, int* __restrict__ offs,
                             int* __restrict__ csr, int N){
  __shared__ int lh[256];
  __shared__ int lsc[256];
  int b = blockIdx.x;
  int lo = b << 8;
  int nn = min(256, N - lo);
  int tid = threadIdx.x;   // 256
  lh[tid] = 0; __syncthreads();
  int es = bbase[b], ee = bbase[b + 1];
  for (int i = es + tid; i < ee; i += 256) atomicAdd(&lh[ebuf[i].y - lo], 1);
  __syncthreads();
  int v = lh[tid];
  lsc[tid] = v; __syncthreads();
  for (int o = 1; o < 256; o <<= 1){
    int t = (tid >= o) ? lsc[tid - o] : 0;
    __syncthreads();
    lsc[tid] += t;
    __syncthreads();
  }
  int excl = lsc[tid] - v;
  if (tid < nn){ deg[lo + tid] = v; offs[lo + tid] = es + excl; }
  __syncthreads();
  lh[tid] = es + excl;     // reuse as cursor
  __syncthreads();
  for (int i = es + tid; i < ee; i += 256){
    int2 e = ebuf[i];
    int pos = atomicAdd(&lh[e.y - lo], 1);
    csr[pos] = e.x;
  }
}

// ------- GIN aggregation v3: bf16 source, 8 nodes/wave, 8 lanes/node, 16B/lane -------
__global__ __launch_bounds__(256) void k_agg(
    const unsigned short* __restrict__ Pb, const int* __restrict__ csr,
    const int* __restrict__ offs, const int* __restrict__ deg,
    float* __restrict__ G, int n){
  int tid = threadIdx.x;
  int wave_id = blockIdx.x * 4 + (tid >> 6);
  int lane = tid & 63;
  int sub = lane >> 3, l8 = lane & 7;
  int node = wave_id * 8 + sub;
  bool ok = node < n;
  int st = 0, cnt = 0;
  if (ok){ st = offs[node]; cnt = deg[node]; }
  const uint4* Pv = (const uint4*)Pb;    // 16 B = 8 bf16
  float a[8];
  #pragma unroll
  for (int k = 0; k < 8; k++) a[k] = 0.f;
  if (ok) addbf(a, Pv[(size_t)node * 8 + l8]);   // self term
  int sbase = sub << 3;
  for (int base = 0; base < cnt; base += 8){
    int rem = cnt - base;
    int s = (l8 < rem) ? csr[st + base + l8] : 0;
    int m = min(rem, 8);
    int j = 0;
    for (; j + 4 <= m; j += 4){
      int s0 = __shfl(s, sbase | j);
      int s1 = __shfl(s, sbase | (j + 1));
      int s2 = __shfl(s, sbase | (j + 2));
      int s3 = __shfl(s, sbase | (j + 3));
      uint4 v0 = Pv[(size_t)s0 * 8 + l8];
      uint4 v1 = Pv[(size_t)s1 * 8 + l8];
      uint4 v2 = Pv[(size_t)s2 * 8 + l8];
      uint4 v3 = Pv[(size_t)s3 * 8 + l8];
      addbf(a, v0); addbf(a, v1); addbf(a, v2); addbf(a, v3);
    }
    for (; j < m; ++j){
      int sj = __shfl(s, sbase | j);
      addbf(a, Pv[(size_t)sj * 8 + l8]);
    }
  }
  if (ok){
    float4* Gp = (float4*)(G + (size_t)node * HDIM + l8 * 8);
    Gp[0] = make_float4(a[0], a[1], a[2], a[3]);
    Gp[1] = make_float4(a[4], a[5], a[6], a[7]);
  }
}

// ======== GIN MLP via MFMA split-bf16, 2 tiles/block, weights in LDS ========
__global__ __launch_bounds__(256, 3) void k_mlp(
    float* __restrict__ G, const int* __restrict__ batch,
    const short* __restrict__ Wall,   // [w1h|w1l|w2h|w2l] 16384 shorts
    const float* __restrict__ B1, const float* __restrict__ B2,
    float* __restrict__ stats, int N){
  __shared__ short Ws[16384];         // 32 KiB
  __shared__ short Ah[64 * APITCH];   // 9216 B
  __shared__ short Al[64 * APITCH];   // 9216 B
  __shared__ float ssum[64], ssq[64];
  int tid = threadIdx.x;

  #pragma unroll
  for (int i = 0; i < 8; i++)
    ((float4*)Ws)[i * 256 + tid] = ((const float4*)Wall)[i * 256 + tid];

  int wv = tid >> 6, lane = tid & 63;
  int quad = lane >> 4, l15 = lane & 15;
  int rbase = wv << 4;
  float bb1[4], bb2[4];
  #pragma unroll
  for (int t = 0; t < 4; t++){ bb1[t] = B1[t * 16 + l15]; bb2[t] = B2[t * 16 + l15]; }

  int tile0 = blockIdx.x << 1;
  float4 r[4], r2[4];
  {
    int tb = tile0 << 6;
    #pragma unroll
    for (int ri = 0; ri < 4; ri++){
      int idx = ri * 256 + tid;
      int node = tb + (idx >> 4), f4 = idx & 15;
      r[ri] = make_float4(0.f, 0.f, 0.f, 0.f);
      if (node < N) r[ri] = ((const float4*)G)[(size_t)node * 16 + f4];
    }
  }

  for (int tt = 0; tt < 2; tt++){
    int t0 = (tile0 + tt) << 6;      // uniform per block
    if (t0 >= N) break;

    // ---- convert regs -> bf16 hi/lo LDS planes ----
    #pragma unroll
    for (int ri = 0; ri < 4; ri++){
      int idx = ri * 256 + tid;
      int node = idx >> 4, f4 = idx & 15;
      float vv[4] = {r[ri].x, r[ri].y, r[ri].z, r[ri].w};
      short h[4], l[4];
      #pragma unroll
      for (int j = 0; j < 4; j++){
        unsigned short hh = f2bf(vv[j]);
        h[j] = (short)hh;
        l[j] = (short)f2bf(vv[j] - bf2f(hh));
      }
      *(short4*)(Ah + node * APITCH + f4 * 4) = make_short4(h[0], h[1], h[2], h[3]);
      *(short4*)(Al + node * APITCH + f4 * 4) = make_short4(l[0], l[1], l[2], l[3]);
    }
    if (tid < 64){ ssum[tid] = 0.f; ssq[tid] = 0.f; }
    __syncthreads();

    // prefetch next tile (overlaps both GEMMs)
    if (tt == 0){
      int tb = (tile0 + 1) << 6;
      #pragma unroll
      for (int ri = 0; ri < 4; ri++){
        int idx = ri * 256 + tid;
        int node = tb + (idx >> 4), f4 = idx & 15;
        r2[ri] = make_float4(0.f, 0.f, 0.f, 0.f);
        if (node < N) r2[ri] = ((const float4*)G)[(size_t)node * 16 + f4];
      }
    }

    // ---- GEMM1 ----
    f32x4 acc[4];
    #pragma unroll
    for (int t = 0; t < 4; t++) acc[t] = (f32x4){0.f, 0.f, 0.f, 0.f};
    #pragma unroll
    for (int kb = 0; kb < 2; kb++){
      int kk = kb * 32 + quad * 8;
      bf16x8 a_h = *(const bf16x8*)(Ah + (rbase + l15) * APITCH + kk);
      bf16x8 a_l = *(const bf16x8*)(Al + (rbase + l15) * APITCH + kk);
      #pragma unroll
      for (int t = 0; t < 4; t++){
        bf16x8 b_h = *(const bf16x8*)(Ws + (t * 16 + l15) * 64 + kk);
        bf16x8 b_l = *(const bf16x8*)(Ws + 4096 + (t * 16 + l15) * 64 + kk);
        acc[t] = __builtin_amdgcn_mfma_f32_16x16x32_bf16(a_h, b_h, acc[t], 0, 0, 0);
        acc[t] = __builtin_amdgcn_mfma_f32_16x16x32_bf16(a_h, b_l, acc[t], 0, 0, 0);
        acc[t] = __builtin_amdgcn_mfma_f32_16x16x32_bf16(a_l, b_h, acc[t], 0, 0, 0);
      }
    }
    __syncthreads();

    // ---- bias + relu + split (C layout -> A layout) ----
    #pragma unroll
    for (int t = 0; t < 4; t++){
      #pragma unroll
      for (int rg = 0; rg < 4; rg++){
        float v = fmaxf(acc[t][rg] + bb1[t], 0.f);
        int row = rbase + quad * 4 + rg;
        int col = t * 16 + l15;
        unsigned short hh = f2bf(v);
        Ah[row * APITCH + col] = (short)hh;
        Al[row * APITCH + col] = (short)f2bf(v - bf2f(hh));
      }
    }
    __syncthreads();

    // ---- GEMM2 ----
    f32x4 acc2[4];
    #pragma unroll
    for (int t = 0; t < 4; t++) acc2[t] = (f32x4){0.f, 0.f, 0.f, 0.f};
    #pragma unroll
    for (int kb = 0; kb < 2; kb++){
      int kk = kb * 32 + quad * 8;
      bf16x8 a_h = *(const bf16x8*)(Ah + (rbase + l15) * APITCH + kk);
      bf16x8 a_l = *(const bf16x8*)(Al + (rbase + l15) * APITCH + kk);
      #pragma unroll
      for (int t = 0; t < 4; t++){
        bf16x8 b_h = *(const bf16x8*)(Ws + 8192 + (t * 16 + l15) * 64 + kk);
        bf16x8 b_l = *(const bf16x8*)(Ws + 12288 + (t * 16 + l15) * 64 + kk);
        acc2[t] = __builtin_amdgcn_mfma_f32_16x16x32_bf16(a_h, b_h, acc2[t], 0, 0, 0);
        acc2[t] = __builtin_amdgcn_mfma_f32_16x16x32_bf16(a_h, b_l, acc2[t], 0, 0, 0);
        acc2[t] = __builtin_amdgcn_mfma_f32_16x16x32_bf16(a_l, b_h, acc2[t], 0, 0, 0);
      }
    }

    // ---- bias, store Y, stats ----
    int lastn = min(t0 + 63, N - 1);
    int g0 = batch[t0];
    bool uniform = (batch[lastn] == g0) && (t0 + 63 < N);
    #pragma unroll
    for (int t = 0; t < 4; t++){
      int f = t * 16 + l15;
      float s = 0.f, q = 0.f;
      #pragma unroll
      for (int rg = 0; rg < 4; rg++){
        float v = acc2[t][rg] + bb2[t];
        int node = t0 + rbase + quad * 4 + rg;
        if (node < N) G[(size_t)node * HDIM + f] = v;
        if (uniform){
          s += v; q += v * v;
        } else if (node < N){
          int g = batch[node];
          atomicAdd(&stats[g * 128 + f], v);
          atomicAdd(&stats[g * 128 + 64 + f], v * v);
        }
      }
      if (uniform){
        s += __shfl_xor(s, 16); s += __shfl_xor(s, 32);
        q += __shfl_xor(q, 16); q += __shfl_xor(q, 32);
        if (quad == 0){ atomicAdd(&ssum[f], s); atomicAdd(&ssq[f], q); }
      }
    }
    __syncthreads();
    if (uniform && tid < 64){
      atomicAdd(&stats[g0 * 128 + tid], ssum[tid]);
      atomicAdd(&stats[g0 * 128 + 64 + tid], ssq[tid]);
    }
    #pragma unroll
    for (int ri = 0; ri < 4; ri++) r[ri] = r2[ri];
  }
}

// ------- GraphNorm apply + relu + residual accumulate (finalize inlined) -------
// C written as bf16 (feeds next layer's gather); hsum stays f32.
__global__ void k_gn_apply(const float* __restrict__ Y, const int* __restrict__ batch,
                           const float* __restrict__ stats, const int* __restrict__ gs,
                           const float* __restrict__ w, const float* __restrict__ ms,
                           const float* __restrict__ bias,
                           unsigned short* __restrict__ Cb, float* __restrict__ hsum, int n16,
                           int first, int writeC){
  int i = blockIdx.x * blockDim.x + threadIdx.x;
  if (i >= n16) return;
  int node = i >> 4, q = i & 15;
  int g = batch[node];
  float cnt = (float)max(gs[g + 1] - gs[g], 1);
  float4 y  = ((const float4*)Y)[i];
  float4 s1 = ((const float4*)(stats + g * 128))[q];
  float4 s2 = ((const float4*)(stats + g * 128 + 64))[q];
  float4 wv = ((const float4*)w)[q];
  float4 mv = ((const float4*)ms)[q];
  float4 bv = ((const float4*)bias)[q];
  float4 v;
  #define APPLY1(c) { \
    float mean = s1.c / cnt; float ex2 = s2.c / cnt; \
    float var = ex2 - (2.f * mv.c - mv.c * mv.c) * mean * mean; \
    float sc = rsqrtf(var + GN_EPS) * wv.c; \
    v.c = fmaxf((y.c - mv.c * mean) * sc + bv.c, 0.f); }
  APPLY1(x) APPLY1(y) APPLY1(z) APPLY1(w)
  #undef APPLY1
  if (writeC){
    ushort4 o;
    o.x = f2bf(v.x); o.y = f2bf(v.y); o.z = f2bf(v.z); o.w = f2bf(v.w);
    ((ushort4*)Cb)[i] = o;
  }
  if (first){
    ((float4*)hsum)[i] = v;
  } else {
    float4 h = ((float4*)hsum)[i];
    h.x += v.x; h.y += v.y; h.z += v.z; h.w += v.w;
    ((float4*)hsum)[i] = h;
  }
}

// ---------------- pooling pass 1 ----------------
#define GN_NPW 32
__global__ void k_pool1(const float* __restrict__ HS, const int* __restrict__ batch,
                        const float* __restrict__ GW, const float* __restrict__ GB,
                        float* __restrict__ sumbuf, unsigned* __restrict__ maxbuf,
                        float* __restrict__ gatebuf, unsigned* __restrict__ gmaxbuf, int n){
  int wave = (int)((blockIdx.x * blockDim.x + threadIdx.x) >> 6);
  int lane = threadIdx.x & 63;
  int s = wave * GN_NPW;
  if (s >= n) return;
  int e = min(s + GN_NPW, n);
  float gwv = GW[lane];
  float gb = GB[0];
  int cur = batch[s];
  float macc = 0.f, xacc = -INFINITY, gmx = -INFINITY;
  for (int nd = s; nd < e; ++nd){
    int g = batch[nd];
    if (g != cur){
      atomicAdd(&sumbuf[cur * 64 + lane], macc);
      atomicMax(&maxbuf[cur * 64 + lane], fenc(xacc));
      if (lane == 0) atomicMax(&gmaxbuf[cur], fenc(gmx));
      macc = 0.f; xacc = -INFINITY; gmx = -INFINITY; cur = g;
    }
    float hv = HS[(size_t)nd * HDIM + lane];
    macc += hv; xacc = fmaxf(xacc, hv);
    float gv = hv * gwv;
    #pragma unroll
    for (int msk = 1; msk < 64; msk <<= 1) gv += __shfl_xor(gv, msk);
    gv += gb;
    if (lane == 0) gatebuf[nd] = gv;
    gmx = fmaxf(gmx, gv);
  }
  atomicAdd(&sumbuf[cur * 64 + lane], macc);
  atomicMax(&maxbuf[cur * 64 + lane], fenc(xacc));
  if (lane == 0) atomicMax(&gmaxbuf[cur], fenc(gmx));
}

// ---------------- pooling pass 2 ----------------
__global__ void k_pool2(const float* __restrict__ HS, const int* __restrict__ batch,
                        const float* __restrict__ gatebuf, const unsigned* __restrict__ gmaxbuf,
                        float* __restrict__ attbuf, float* __restrict__ denbuf, int n){
  int wave = (int)((blockIdx.x * blockDim.x + threadIdx.x) >> 6);
  int lane = threadIdx.x & 63;
  int s = wave * GN_NPW;
  if (s >= n) return;
  int e = min(s + GN_NPW, n);
  int cur = batch[s];
  float m = fdec(gmaxbuf[cur]);
  float aacc = 0.f, dacc = 0.f;
  for (int nd = s; nd < e; ++nd){
    int g = batch[nd];
    if (g != cur){
      atomicAdd(&attbuf[cur * 64 + lane], aacc);
      if (lane == 0) atomicAdd(&denbuf[cur], dacc);
      aacc = 0.f; dacc = 0.f; cur = g; m = fdec(gmaxbuf[cur]);
    }
    float ex = expf(gatebuf[nd] - m);
    float hv = HS[(size_t)nd * HDIM + lane];
    aacc += ex * hv; dacc += ex;
  }
  atomicAdd(&attbuf[cur * 64 + lane], aacc);
  if (lane == 0) atomicAdd(&denbuf[cur], dacc);
}

// ---------------- pooling pass 3 ----------------
__global__ void k_pool3(const float* __restrict__ attbuf, const float* __restrict__ denbuf,
                        const float* __restrict__ sumbuf, const unsigned* __restrict__ maxbuf,
                        const int* __restrict__ gs, const float* __restrict__ U,
                        const float* __restrict__ HW1, const float* __restrict__ HB1,
                        const float* __restrict__ HW2, const float* __restrict__ HB2,
                        float* __restrict__ out){
  __shared__ float z[200];
  int g = blockIdx.x;
  int tid = threadIdx.x;   // 64 threads
  float cnt = (float)max(gs[g + 1] - gs[g], 1);
  float den = denbuf[g];
  z[tid]       = attbuf[g * 64 + tid] / den;
  z[64 + tid]  = sumbuf[g * 64 + tid] / cnt;
  z[128 + tid] = fdec(maxbuf[g * 64 + tid]);
  if (tid < 3) z[192 + tid] = U[g * 3 + tid];
  __syncthreads();
  float acc = HB1[tid];
  for (int k = 0; k < 195; k++) acc += z[k] * HW1[k * 64 + tid];
  float sv = fmaxf(acc, 0.f) * HW2[tid];
  #pragma unroll
  for (int msk = 1; msk < 64; msk <<= 1) sv += __shfl_xor(sv, msk);
  if (tid == 0) out[g] = sv + HB2[0];
}

extern "C" void kernel_launch(void* const* d_in, const int* in_sizes, int n_in,
                              void* d_out, int out_size, void* d_ws, size_t ws_size,
                              hipStream_t stream){
  const float* x     = (const float*)d_in[0];
  const int*   ei    = (const int*)d_in[1];
  const int*   batch = (const int*)d_in[2];
  const float* u     = (const float*)d_in[3];
  const float* W[3][4]; const float* GNp[3][3];
  for (int l = 0; l < 3; l++){
    int base = 4 + l * 7;
    W[l][0]  = (const float*)d_in[base + 0];
    W[l][1]  = (const float*)d_in[base + 1];
    W[l][2]  = (const float*)d_in[base + 2];
    W[l][3]  = (const float*)d_in[base + 3];
    GNp[l][0]= (const float*)d_in[base + 4];
    GNp[l][1]= (const float*)d_in[base + 5];
    GNp[l][2]= (const float*)d_in[base + 6];
  }
  const float* gate_w = (const float*)d_in[25];
  const float* gate_b = (const float*)d_in[26];
  const float* hw1    = (const float*)d_in[27];
  const float* hb1    = (const float*)d_in[28];
  const float* hw2    = (const float*)d_in[29];
  const float* hb2    = (const float*)d_in[30];
  float* out = (float*)d_out;

  int N = in_sizes[0] / HDIM;
  int E = in_sizes[1] / 2;
  int B = in_sizes[3] / 3;
  const int* src = ei;
  const int* dst = ei + E;
  int NB = (N + 255) >> 8;     // <= MAXNB for N <= 131072

  char* w8 = (char*)d_ws;
  size_t NH = (size_t)N * HDIM * sizeof(float);
  size_t NHb = (size_t)N * HDIM * sizeof(short);
  auto alignup = [](size_t v){ return (v + 255) & ~(size_t)255; };
  size_t off = 0;
  float* hsum    = (float*)(w8 + off); off += alignup(NH);
  float* G       = (float*)(w8 + off); off += alignup(NH);
  unsigned short* xb   = (unsigned short*)(w8 + off); off += alignup(NHb);
  unsigned short* bufA = (unsigned short*)(w8 + off); off += alignup(NHb);
  unsigned short* bufB = (unsigned short*)(w8 + off); off += alignup(NHb);
  float* gatebuf = (float*)(w8 + off); off += alignup((size_t)N * 4);
  int*   deg     = (int*)(w8 + off);   off += alignup((size_t)N * 4);
  int*   offs    = (int*)(w8 + off);   off += alignup((size_t)N * 4);
  int*   csr     = (int*)(w8 + off);   off += alignup((size_t)E * 4);
  int2*  ebuf    = (int2*)(w8 + off);  off += alignup((size_t)E * 8);
  int*   bcount  = (int*)(w8 + off);   off += alignup((size_t)(MAXNB + 1) * 4);
  int*   bbase   = (int*)(w8 + off);   off += alignup((size_t)(MAXNB + 1) * 4);
  int*   bcursor = (int*)(w8 + off);   off += alignup((size_t)(MAXNB + 1) * 4);
  float* stats   = (float*)(w8 + off); off += alignup((size_t)3 * B * 128 * 4);
  // pooled zero region (one memset): sumbuf | maxbuf | attbuf | denbuf | gmaxbuf
  float* poolz   = (float*)(w8 + off);
  size_t poolz_bytes = ((size_t)B * 64 * 3 + 2 * B) * 4;
  off += alignup(poolz_bytes);
  float*    sumbuf  = poolz;
  unsigned* maxbuf  = (unsigned*)(poolz + (size_t)B * 64);
  float*    attbuf  = poolz + (size_t)2 * B * 64;
  float*    denbuf  = poolz + (size_t)3 * B * 64;
  unsigned* gmaxbuf = (unsigned*)(poolz + (size_t)3 * B * 64 + B);
  int*   gs      = (int*)(w8 + off);   off += alignup((size_t)(B + 1) * 4);
  short* wbf     = (short*)(w8 + off); off += alignup((size_t)6 * 8192 * 2);
  (void)ws_size; (void)n_in; (void)out_size;

  hipMemsetAsync(stats, 0, (size_t)3 * B * 128 * 4, stream);
  hipMemsetAsync(poolz, 0, poolz_bytes, stream);   // 0 == below all reals in fenc order
  hipMemsetAsync(bcount, 0, (size_t)(MAXNB + 1) * 4, stream);

  const int tb = 256;
  int n16 = N * 16;
  k_prep<<<263, tb, 0, stream>>>(dst, bcount, E, NB,
                                 W[0][0], W[0][2], W[1][0], W[1][2], W[2][0], W[2][2],
                                 wbf, batch, N, gs, B);
  k_cvt<<<(n16 + tb - 1) / tb, tb, 0, stream>>>(x, xb, n16);
  k_bscan<<<1, MAXNB, 0, stream>>>(bcount, bbase, bcursor, NB);
  k_breorder<<<(E + RCHUNK - 1) / RCHUNK, tb, 0, stream>>>(src, dst, bcursor, ebuf, E, NB);
  k_bucket_csr<<<NB, tb, 0, stream>>>(ebuf, bbase, deg, offs, csr, N);

  int nwaves = (N + GN_NPW - 1) / GN_NPW;
  int segblocks = (nwaves * 64 + tb - 1) / tb;
  int nblk64 = (N + 63) >> 6;
  int nblk2 = (nblk64 + 1) >> 1;
  int aggwaves = (N + 7) >> 3;
  int aggblocks = (aggwaves + 3) >> 2;   // 4 waves per block

  const unsigned short* P = xb;
  unsigned short* C = bufA;
  for (int l = 0; l < 3; l++){
    k_agg<<<aggblocks, 256, 0, stream>>>(P, csr, offs, deg, G, N);
    float* lstats = stats + (size_t)l * B * 128;
    k_mlp<<<nblk2, 256, 0, stream>>>(G, batch, wbf + (size_t)l * 16384,
                                     W[l][1], W[l][3], lstats, N);
    k_gn_apply<<<(n16 + tb - 1) / tb, tb, 0, stream>>>(G, batch, lstats, gs,
                                                       GNp[l][0], GNp[l][2], GNp[l][1],
                                                       C, hsum, n16, l == 0 ? 1 : 0,
                                                       l == 2 ? 0 : 1);
    P = C;
    C = (l == 0) ? bufB : bufA;
  }
  k_pool1<<<segblocks, tb, 0, stream>>>(hsum, batch, gate_w, gate_b,
                                        sumbuf, maxbuf, gatebuf, gmaxbuf, N);
  k_pool2<<<segblocks, tb, 0, stream>>>(hsum, batch, gatebuf, gmaxbuf, attbuf, denbuf, N);
  k_pool3<<<B, 64, 0, stream>>>(attbuf, denbuf, sumbuf, maxbuf, gs, u,
                                hw1, hb1, hw2, hb2, out);
}

// Round 11
// 486.847 us; speedup vs baseline: 1.6387x; 1.0189x over previous
//
#include <hip/hip_runtime.h>
#include <hip/hip_cooperative_groups.h>
#include <math.h>

namespace cg = cooperative_groups;

#define HDIM 64
#define GN_EPS 1e-5f
#define MAXNB 512          // supports N <= 131072 (bucket = 256 nodes)
#define APITCH 72
#define RCHUNK 8192

typedef __attribute__((ext_vector_type(8))) short bf16x8;
typedef __attribute__((ext_vector_type(4))) float f32x4;

__device__ __forceinline__ int lower_bound_i(const int* a, int n, int key){
  int lo = 0, hi = n;
  while (lo < hi){ int mid = (lo + hi) >> 1; if (a[mid] < key) lo = mid + 1; else hi = mid; }
  return lo;
}
__device__ __forceinline__ unsigned fenc(float x){
  unsigned b = __float_as_uint(x);
  return (b & 0x80000000u) ? ~b : (b | 0x80000000u);
}
__device__ __forceinline__ float fdec(unsigned u){
  unsigned b = (u & 0x80000000u) ? (u ^ 0x80000000u) : ~u;
  return __uint_as_float(b);
}
__device__ __forceinline__ unsigned short f2bf(float f){
  unsigned u = __float_as_uint(f);
  u += 0x7fffu + ((u >> 16) & 1u);
  return (unsigned short)(u >> 16);
}
__device__ __forceinline__ float bf2f(unsigned short h){
  return __uint_as_float(((unsigned)h) << 16);
}
__device__ __forceinline__ void addbf(float* a, uint4 v){
  a[0] += __uint_as_float(v.x << 16);
  a[1] += __uint_as_float(v.x & 0xffff0000u);
  a[2] += __uint_as_float(v.y << 16);
  a[3] += __uint_as_float(v.y & 0xffff0000u);
  a[4] += __uint_as_float(v.z << 16);
  a[5] += __uint_as_float(v.z & 0xffff0000u);
  a[6] += __uint_as_float(v.w << 16);
  a[7] += __uint_as_float(v.w & 0xffff0000u);
}

// ============================================================================
// Cooperative path
// ============================================================================
struct BuildArgs {
  const int* src; const int* dst; int E; int NB;
  const float* W0; const float* W1; const float* W2;
  const float* W3; const float* W4; const float* W5;
  short* wbf;
  const int* batch; int N; int* gs; int B;
  int* bcount; int* bbase; int* bcursor;
  int2* ebuf; int* deg; int* offs; int* csr;
  const float* x; unsigned short* xb; int n16;
  float* stats; int statsN; float* poolz; int poolzN;
};

__global__ void k_build(BuildArgs a){
  cg::grid_group grid = cg::this_grid();
  __shared__ int sA[512];
  __shared__ int sB[512];
  int tid = threadIdx.x;
  int gsz = (int)gridDim.x;
  int gstart = blockIdx.x * 256 + tid;
  int gstride = gsz * 256;

  // ---- phase 0: zeros + weight split + gs + x->bf16 ----
  for (int i = gstart; i <= MAXNB; i += gstride) a.bcount[i] = 0;
  for (int i = gstart; i < a.statsN; i += gstride) a.stats[i] = 0.f;
  for (int i = gstart; i < a.poolzN; i += gstride) a.poolz[i] = 0.f;
  if (blockIdx.x < 6){
    const float* Wsrc = (blockIdx.x == 0) ? a.W0 : (blockIdx.x == 1) ? a.W1 :
                        (blockIdx.x == 2) ? a.W2 : (blockIdx.x == 3) ? a.W3 :
                        (blockIdx.x == 4) ? a.W4 : a.W5;
    short* hi = a.wbf + blockIdx.x * 8192;
    short* lo = hi + 4096;
    for (int i = tid; i < 4096; i += 256){
      int k = i >> 6, j = i & 63;
      float v = Wsrc[i];
      unsigned short h = f2bf(v);
      hi[j * 64 + k] = (short)h;            // transposed Wt[j][k]
      lo[j * 64 + k] = (short)f2bf(v - bf2f(h));
    }
  } else if (blockIdx.x == 6){
    for (int g = tid; g <= a.B; g += 256) a.gs[g] = lower_bound_i(a.batch, a.N, g);
  }
  for (int i = gstart; i < a.n16; i += gstride){
    float4 v = ((const float4*)a.x)[i];
    ushort4 o;
    o.x = f2bf(v.x); o.y = f2bf(v.y); o.z = f2bf(v.z); o.w = f2bf(v.w);
    ((ushort4*)a.xb)[i] = o;
  }
  grid.sync();

  // ---- phase 1: bucket histogram ----
  for (int b = tid; b < a.NB; b += 256) sA[b] = 0;
  __syncthreads();
  for (int i = gstart; i < a.E; i += gstride) atomicAdd(&sA[a.dst[i] >> 8], 1);
  __syncthreads();
  for (int b = tid; b < a.NB; b += 256){ int c = sA[b]; if (c) atomicAdd(&a.bcount[b], c); }
  grid.sync();

  // ---- phase 2: scan (block 0 only) ----
  if (blockIdx.x == 0){
    int v0 = (2 * tid     < a.NB) ? a.bcount[2 * tid]     : 0;
    int v1 = (2 * tid + 1 < a.NB) ? a.bcount[2 * tid + 1] : 0;
    int L = v0 + v1;
    sB[tid] = L; __syncthreads();
    for (int o = 1; o < 256; o <<= 1){
      int tv = (tid >= o) ? sB[tid - o] : 0;
      __syncthreads();
      sB[tid] += tv;
      __syncthreads();
    }
    int run = sB[tid] - L;
    if (2 * tid < a.NB){ a.bbase[2 * tid] = run; a.bcursor[2 * tid] = run; }
    run += v0;
    if (2 * tid + 1 < a.NB){ a.bbase[2 * tid + 1] = run; a.bcursor[2 * tid + 1] = run; }
    if (tid == 255) a.bbase[a.NB] = sB[255];
  }
  grid.sync();

  // ---- phase 3: reorder edges into bucket-grouped ebuf ----
  int nch = (a.E + RCHUNK - 1) / RCHUNK;
  for (int ci = blockIdx.x; ci < nch; ci += gsz){
    int c0 = ci * RCHUNK;
    for (int b = tid; b < a.NB; b += 256) sA[b] = 0;
    __syncthreads();
    for (int j = 0; j < RCHUNK / 256; j++){
      int i = c0 + j * 256 + tid;
      if (i < a.E) atomicAdd(&sA[a.dst[i] >> 8], 1);
    }
    __syncthreads();
    for (int b = tid; b < a.NB; b += 256){
      int c = sA[b];
      sB[b] = c ? atomicAdd(&a.bcursor[b], c) : 0;
      sA[b] = 0;
    }
    __syncthreads();
    for (int j = 0; j < RCHUNK / 256; j++){
      int i = c0 + j * 256 + tid;
      if (i < a.E){
        int d = a.dst[i]; int b = d >> 8;
        int rr = atomicAdd(&sA[b], 1);
        a.ebuf[sB[b] + rr] = make_int2(a.src[i], d);
      }
    }
    __syncthreads();
  }
  grid.sync();

  // ---- phase 4: per-bucket counting sort -> csr/deg/offs ----
  for (int b = blockIdx.x; b < a.NB; b += gsz){
    int lo = b << 8;
    int nn = min(256, a.N - lo);
    sA[tid] = 0; __syncthreads();
    int es = a.bbase[b], ee = a.bbase[b + 1];
    for (int i = es + tid; i < ee; i += 256) atomicAdd(&sA[a.ebuf[i].y - lo], 1);
    __syncthreads();
    int v = sA[tid];
    sB[tid] = v; __syncthreads();
    for (int o = 1; o < 256; o <<= 1){
      int tv = (tid >= o) ? sB[tid - o] : 0;
      __syncthreads();
      sB[tid] += tv;
      __syncthreads();
    }
    int excl = sB[tid] - v;
    if (tid < nn){ a.deg[lo + tid] = v; a.offs[lo + tid] = es + excl; }
    __syncthreads();
    sA[tid] = es + excl;
    __syncthreads();
    for (int i = es + tid; i < ee; i += 256){
      int2 e = a.ebuf[i];
      int pos = atomicAdd(&sA[e.y - lo], 1);
      a.csr[pos] = e.x;
    }
    __syncthreads();
  }
}

struct TrunkArgs {
  const unsigned short* xb;
  unsigned short* bufA; unsigned short* bufB;
  float* G; float* hsum;
  const int* csr; const int* offs; const int* deg; const int* batch; const int* gs;
  const short* wbf;
  const float* B1a; const float* B1b; const float* B1c;
  const float* B2a; const float* B2b; const float* B2c;
  const float* gnw0; const float* gnw1; const float* gnw2;
  const float* gnb0; const float* gnb1; const float* gnb2;
  const float* gnm0; const float* gnm1; const float* gnm2;
  float* stats; int N; int n16; int B;
  const float* gw; const float* gb; const float* u;
  const float* hw1; const float* hb1; const float* hw2; const float* hb2;
  float* sumbuf; unsigned* maxbuf; float* attbuf; float* denbuf; unsigned* gmaxbuf;
  float* gatebuf; float* out;
};

__global__ __launch_bounds__(256, 3) void k_trunk(TrunkArgs a){
  cg::grid_group grid = cg::this_grid();
  __shared__ __align__(16) char smem[51712];
  short* Ws  = (short*)smem;                    // 32768 B (4 planes, xor-swizzled)
  short* Ah  = (short*)(smem + 32768);          // 9216 B
  short* Al  = (short*)(smem + 32768 + 9216);   // 9216 B
  float* ssum = (float*)(smem + 32768 + 18432);
  float* ssq  = ssum + 64;
  int tid = threadIdx.x;
  int wv = tid >> 6, lane = tid & 63;
  int gsz = (int)gridDim.x;
  int N = a.N;
  int ntile = (N + 63) >> 6;

  const unsigned short* P = a.xb;
  unsigned short* Cb = a.bufA;

  for (int l = 0; l < 3; l++){
    // ---------- agg ----------
    {
      int sub = lane >> 3, l8 = lane & 7, sbase = sub << 3;
      const uint4* Pv = (const uint4*)P;
      int wid = blockIdx.x * 4 + wv;
      int wstep = gsz * 4 * 8;
      for (int nb = wid * 8; nb < N; nb += wstep){
        int node = nb + sub;
        bool ok = node < N;
        int st = 0, cnt = 0;
        if (ok){ st = a.offs[node]; cnt = a.deg[node]; }
        float acc8[8];
        #pragma unroll
        for (int k = 0; k < 8; k++) acc8[k] = 0.f;
        if (ok) addbf(acc8, Pv[(size_t)node * 8 + l8]);
        for (int base = 0; base < cnt; base += 8){
          int rem = cnt - base;
          int s = (l8 < rem) ? a.csr[st + base + l8] : 0;
          int m = min(rem, 8);
          int j = 0;
          for (; j + 4 <= m; j += 4){
            int s0 = __shfl(s, sbase | j);
            int s1 = __shfl(s, sbase | (j + 1));
            int s2 = __shfl(s, sbase | (j + 2));
            int s3 = __shfl(s, sbase | (j + 3));
            uint4 v0 = Pv[(size_t)s0 * 8 + l8];
            uint4 v1 = Pv[(size_t)s1 * 8 + l8];
            uint4 v2 = Pv[(size_t)s2 * 8 + l8];
            uint4 v3 = Pv[(size_t)s3 * 8 + l8];
            addbf(acc8, v0); addbf(acc8, v1); addbf(acc8, v2); addbf(acc8, v3);
          }
          for (; j < m; ++j){
            int sj = __shfl(s, sbase | j);
            addbf(acc8, Pv[(size_t)sj * 8 + l8]);
          }
        }
        if (ok){
          float4* Gp = (float4*)(a.G + (size_t)node * HDIM + l8 * 8);
          Gp[0] = make_float4(acc8[0], acc8[1], acc8[2], acc8[3]);
          Gp[1] = make_float4(acc8[4], acc8[5], acc8[6], acc8[7]);
        }
      }
    }
    grid.sync();

    // ---------- mlp (MFMA split-bf16) + GN stats ----------
    {
      const short* Wall = a.wbf + (size_t)l * 16384;
      for (int j = tid; j < 2048; j += 256){
        int p = j >> 9, rem = j & 511, rr = rem >> 3, c8 = rem & 7;
        bf16x8 v = ((const bf16x8*)Wall)[j];
        *(bf16x8*)(Ws + p * 4096 + rr * 64 + ((c8 ^ (rr & 7)) << 3)) = v;
      }
      int quad = lane >> 4, l15 = lane & 15;
      int rbase = wv << 4;
      int h7 = l15 & 7;
      const float* B1 = (l == 0) ? a.B1a : (l == 1) ? a.B1b : a.B1c;
      const float* B2 = (l == 0) ? a.B2a : (l == 1) ? a.B2b : a.B2c;
      float bb1[4], bb2[4];
      #pragma unroll
      for (int t4 = 0; t4 < 4; t4++){ bb1[t4] = B1[t4 * 16 + l15]; bb2[t4] = B2[t4 * 16 + l15]; }
      float* lstats = a.stats + (size_t)l * a.B * 128;

      int t = blockIdx.x;
      float4 r[4], r2[4];
      #pragma unroll
      for (int ri = 0; ri < 4; ri++){ r[ri] = make_float4(0.f,0.f,0.f,0.f); r2[ri] = r[ri]; }
      if (t < ntile){
        int tb = t << 6;
        #pragma unroll
        for (int ri = 0; ri < 4; ri++){
          int idx = ri * 256 + tid;
          int node = tb + (idx >> 4), f4 = idx & 15;
          if (node < N) r[ri] = ((const float4*)a.G)[(size_t)node * 16 + f4];
        }
      }
      while (t < ntile){
        int t0 = t << 6;
        #pragma unroll
        for (int ri = 0; ri < 4; ri++){
          int idx = ri * 256 + tid;
          int nodeL = idx >> 4, f4 = idx & 15;
          float vv[4] = {r[ri].x, r[ri].y, r[ri].z, r[ri].w};
          short hh[4], ll[4];
          #pragma unroll
          for (int j = 0; j < 4; j++){
            unsigned short hv = f2bf(vv[j]);
            hh[j] = (short)hv;
            ll[j] = (short)f2bf(vv[j] - bf2f(hv));
          }
          *(short4*)(Ah + nodeL * APITCH + f4 * 4) = make_short4(hh[0], hh[1], hh[2], hh[3]);
          *(short4*)(Al + nodeL * APITCH + f4 * 4) = make_short4(ll[0], ll[1], ll[2], ll[3]);
        }
        if (tid < 64){ ssum[tid] = 0.f; ssq[tid] = 0.f; }
        __syncthreads();

        int tn = t + gsz;
        #pragma unroll
        for (int ri = 0; ri < 4; ri++) r2[ri] = make_float4(0.f,0.f,0.f,0.f);
        if (tn < ntile){
          int tb = tn << 6;
          #pragma unroll
          for (int ri = 0; ri < 4; ri++){
            int idx = ri * 256 + tid;
            int node = tb + (idx >> 4), f4 = idx & 15;
            if (node < N) r2[ri] = ((const float4*)a.G)[(size_t)node * 16 + f4];
          }
        }

        f32x4 acc[4];
        #pragma unroll
        for (int t4 = 0; t4 < 4; t4++) acc[t4] = (f32x4){0.f, 0.f, 0.f, 0.f};
        #pragma unroll
        for (int kb = 0; kb < 2; kb++){
          int kk = kb * 32 + quad * 8;
          int swz = ((kb * 4 + quad) ^ h7) << 3;
          bf16x8 a_h = *(const bf16x8*)(Ah + (rbase + l15) * APITCH + kk);
          bf16x8 a_l = *(const bf16x8*)(Al + (rbase + l15) * APITCH + kk);
          #pragma unroll
          for (int t4 = 0; t4 < 4; t4++){
            int row = t4 * 16 + l15;
            bf16x8 b_h = *(const bf16x8*)(Ws + row * 64 + swz);
            bf16x8 b_l = *(const bf16x8*)(Ws + 4096 + row * 64 + swz);
            acc[t4] = __builtin_amdgcn_mfma_f32_16x16x32_bf16(a_h, b_h, acc[t4], 0, 0, 0);
            acc[t4] = __builtin_amdgcn_mfma_f32_16x16x32_bf16(a_h, b_l, acc[t4], 0, 0, 0);
            acc[t4] = __builtin_amdgcn_mfma_f32_16x16x32_bf16(a_l, b_h, acc[t4], 0, 0, 0);
          }
        }
        __syncthreads();

        #pragma unroll
        for (int t4 = 0; t4 < 4; t4++){
          #pragma unroll
          for (int rg = 0; rg < 4; rg++){
            float v = fmaxf(acc[t4][rg] + bb1[t4], 0.f);
            int row = rbase + quad * 4 + rg;
            int col = t4 * 16 + l15;
            unsigned short hv = f2bf(v);
            Ah[row * APITCH + col] = (short)hv;
            Al[row * APITCH + col] = (short)f2bf(v - bf2f(hv));
          }
        }
        __syncthreads();

        f32x4 acc2[4];
        #pragma unroll
        for (int t4 = 0; t4 < 4; t4++) acc2[t4] = (f32x4){0.f, 0.f, 0.f, 0.f};
        #pragma unroll
        for (int kb = 0; kb < 2; kb++){
          int kk = kb * 32 + quad * 8;
          int swz = ((kb * 4 + quad) ^ h7) << 3;
          bf16x8 a_h = *(const bf16x8*)(Ah + (rbase + l15) * APITCH + kk);
          bf16x8 a_l = *(const bf16x8*)(Al + (rbase + l15) * APITCH + kk);
          #pragma unroll
          for (int t4 = 0; t4 < 4; t4++){
            int row = t4 * 16 + l15;
            bf16x8 b_h = *(const bf16x8*)(Ws + 8192 + row * 64 + swz);
            bf16x8 b_l = *(const bf16x8*)(Ws + 12288 + row * 64 + swz);
            acc2[t4] = __builtin_amdgcn_mfma_f32_16x16x32_bf16(a_h, b_h, acc2[t4], 0, 0, 0);
            acc2[t4] = __builtin_amdgcn_mfma_f32_16x16x32_bf16(a_h, b_l, acc2[t4], 0, 0, 0);
            acc2[t4] = __builtin_amdgcn_mfma_f32_16x16x32_bf16(a_l, b_h, acc2[t4], 0, 0, 0);
          }
        }

        int lastn = min(t0 + 63, N - 1);
        int g0 = a.batch[t0];
        bool uniform = (a.batch[lastn] == g0) && (t0 + 63 < N);
        #pragma unroll
        for (int t4 = 0; t4 < 4; t4++){
          int f = t4 * 16 + l15;
          float s = 0.f, q = 0.f;
          #pragma unroll
          for (int rg = 0; rg < 4; rg++){
            float v = acc2[t4][rg] + bb2[t4];
            int node = t0 + rbase + quad * 4 + rg;
            if (node < N) a.G[(size_t)node * HDIM + f] = v;
            if (uniform){
              s += v; q += v * v;
            } else if (node < N){
              int g = a.batch[node];
              atomicAdd(&lstats[g * 128 + f], v);
              atomicAdd(&lstats[g * 128 + 64 + f], v * v);
            }
          }
          if (uniform){
            s += __shfl_xor(s, 16); s += __shfl_xor(s, 32);
            q += __shfl_xor(q, 16); q += __shfl_xor(q, 32);
            if (quad == 0){ atomicAdd(&ssum[f], s); atomicAdd(&ssq[f], q); }
          }
        }
        __syncthreads();
        if (uniform && tid < 64){
          atomicAdd(&lstats[g0 * 128 + tid], ssum[tid]);
          atomicAdd(&lstats[g0 * 128 + 64 + tid], ssq[tid]);
        }
        #pragma unroll
        for (int ri = 0; ri < 4; ri++) r[ri] = r2[ri];
        t = tn;
      }
    }
    grid.sync();

    // ---------- GraphNorm apply + relu + residual ----------
    {
      const float* wv_ = (l == 0) ? a.gnw0 : (l == 1) ? a.gnw1 : a.gnw2;
      const float* bv_ = (l == 0) ? a.gnb0 : (l == 1) ? a.gnb1 : a.gnb2;
      const float* mv_ = (l == 0) ? a.gnm0 : (l == 1) ? a.gnm1 : a.gnm2;
      const float* lstats = a.stats + (size_t)l * a.B * 128;
      int first = (l == 0) ? 1 : 0;
      int writeC = (l == 2) ? 0 : 1;
      for (int i = blockIdx.x * 256 + tid; i < a.n16; i += gsz * 256){
        int node = i >> 4, q = i & 15;
        int g = a.batch[node];
        float cnt = (float)max(a.gs[g + 1] - a.gs[g], 1);
        float4 y  = ((const float4*)a.G)[i];
        float4 s1 = ((const float4*)(lstats + g * 128))[q];
        float4 s2 = ((const float4*)(lstats + g * 128 + 64))[q];
        float4 wq = ((const float4*)wv_)[q];
        float4 mq = ((const float4*)mv_)[q];
        float4 bq = ((const float4*)bv_)[q];
        float4 v;
        #define APPLY1(c) { \
          float mean = s1.c / cnt; float ex2 = s2.c / cnt; \
          float var = ex2 - (2.f * mq.c - mq.c * mq.c) * mean * mean; \
          float sc = rsqrtf(var + GN_EPS) * wq.c; \
          v.c = fmaxf((y.c - mq.c * mean) * sc + bq.c, 0.f); }
        APPLY1(x) APPLY1(y) APPLY1(z) APPLY1(w)
        #undef APPLY1
        if (writeC){
          ushort4 o;
          o.x = f2bf(v.x); o.y = f2bf(v.y); o.z = f2bf(v.z); o.w = f2bf(v.w);
          ((ushort4*)Cb)[i] = o;
        }
        if (first){
          ((float4*)a.hsum)[i] = v;
        } else {
          float4 h = ((float4*)a.hsum)[i];
          h.x += v.x; h.y += v.y; h.z += v.z; h.w += v.w;
          ((float4*)a.hsum)[i] = h;
        }
      }
    }
    grid.sync();
    P = Cb;
    Cb = (l == 0) ? a.bufB : a.bufA;
  }

  // ---------- pool1 ----------
  {
    int nchunk = (N + 31) >> 5;
    int wid = blockIdx.x * 4 + wv;
    float gwv = a.gw[lane];
    float gb = a.gb[0];
    for (int c = wid; c < nchunk; c += gsz * 4){
      int s = c << 5, e = min(s + 32, N);
      int cur = a.batch[s];
      float macc = 0.f, xacc = -INFINITY, gmx = -INFINITY;
      for (int nd = s; nd < e; ++nd){
        int g = a.batch[nd];
        if (g != cur){
          atomicAdd(&a.sumbuf[cur * 64 + lane], macc);
          atomicMax(&a.maxbuf[cur * 64 + lane], fenc(xacc));
          if (lane == 0) atomicMax(&a.gmaxbuf[cur], fenc(gmx));
          macc = 0.f; xacc = -INFINITY; gmx = -INFINITY; cur = g;
        }
        float hv = a.hsum[(size_t)nd * HDIM + lane];
        macc += hv; xacc = fmaxf(xacc, hv);
        float gv = hv * gwv;
        #pragma unroll
        for (int msk = 1; msk < 64; msk <<= 1) gv += __shfl_xor(gv, msk);
        gv += gb;
        if (lane == 0) a.gatebuf[nd] = gv;
        gmx = fmaxf(gmx, gv);
      }
      atomicAdd(&a.sumbuf[cur * 64 + lane], macc);
      atomicMax(&a.maxbuf[cur * 64 + lane], fenc(xacc));
      if (lane == 0) atomicMax(&a.gmaxbuf[cur], fenc(gmx));
    }
  }
  grid.sync();

  // ---------- pool2 ----------
  {
    int nchunk = (N + 31) >> 5;
    int wid = blockIdx.x * 4 + wv;
    for (int c = wid; c < nchunk; c += gsz * 4){
      int s = c << 5, e = min(s + 32, N);
      int cur = a.batch[s];
      float m = fdec(a.gmaxbuf[cur]);
      float aacc = 0.f, dacc = 0.f;
      for (int nd = s; nd < e; ++nd){
        int g = a.batch[nd];
        if (g != cur){
          atomicAdd(&a.attbuf[cur * 64 + lane], aacc);
          if (lane == 0) atomicAdd(&a.denbuf[cur], dacc);
          aacc = 0.f; dacc = 0.f; cur = g; m = fdec(a.gmaxbuf[cur]);
        }
        float ex = expf(a.gatebuf[nd] - m);
        float hv = a.hsum[(size_t)nd * HDIM + lane];
        aacc += ex * hv; dacc += ex;
      }
      atomicAdd(&a.attbuf[cur * 64 + lane], aacc);
      if (lane == 0) atomicAdd(&a.denbuf[cur], dacc);
    }
  }
  grid.sync();

  // ---------- pool3 ----------
  {
    float* z = (float*)smem;
    int g = blockIdx.x;
    if (g < a.B){
      float cnt = (float)max(a.gs[g + 1] - a.gs[g], 1);
      if (tid < 64){
        float den = a.denbuf[g];
        z[tid]       = a.attbuf[g * 64 + tid] / den;
        z[64 + tid]  = a.sumbuf[g * 64 + tid] / cnt;
        z[128 + tid] = fdec(a.maxbuf[g * 64 + tid]);
        if (tid < 3) z[192 + tid] = a.u[g * 3 + tid];
      }
      __syncthreads();
      if (tid < 64){
        float acc = a.hb1[tid];
        for (int k = 0; k < 195; k++) acc += z[k] * a.hw1[k * 64 + tid];
        float sv = fmaxf(acc, 0.f) * a.hw2[tid];
        #pragma unroll
        for (int msk = 1; msk < 64; msk <<= 1) sv += __shfl_xor(sv, msk);
        if (tid == 0) a.out[g] = sv + a.hb2[0];
      }
    }
  }
}

// ============================================================================
// Standard (fallback) path — R9 proven kernels (+ swizzled Ws in k_mlp)
// ============================================================================
__global__ void k_prep(const int* __restrict__ dst, int* __restrict__ bcount, int E, int NB,
                       const float* __restrict__ Wa0, const float* __restrict__ Wb0,
                       const float* __restrict__ Wa1, const float* __restrict__ Wb1,
                       const float* __restrict__ Wa2, const float* __restrict__ Wb2,
                       short* __restrict__ wbf,
                       const int* __restrict__ batch, int N, int* __restrict__ gs, int B){
  int tid = threadIdx.x;
  if (blockIdx.x < 256){
    __shared__ int lh[MAXNB];
    for (int b = tid; b < NB; b += 256) lh[b] = 0;
    __syncthreads();
    for (int i = blockIdx.x * 256 + tid; i < E; i += 256 * 256)
      atomicAdd(&lh[dst[i] >> 8], 1);
    __syncthreads();
    for (int b = tid; b < NB; b += 256){ int c = lh[b]; if (c) atomicAdd(&bcount[b], c); }
  } else if (blockIdx.x < 262){
    int wi = blockIdx.x - 256;
    const float* Wsrc[6] = {Wa0, Wb0, Wa1, Wb1, Wa2, Wb2};
    const float* W = Wsrc[wi];
    short* hi = wbf + wi * 8192;
    short* lo = hi + 4096;
    for (int i = tid; i < 4096; i += 256){
      int k = i >> 6, j = i & 63;
      float v = W[i];
      unsigned short h = f2bf(v);
      hi[j * 64 + k] = (short)h;
      lo[j * 64 + k] = (short)f2bf(v - bf2f(h));
    }
  } else {
    for (int g = tid; g <= B; g += 256) gs[g] = lower_bound_i(batch, N, g);
  }
}

__global__ void k_cvt(const float* __restrict__ x, unsigned short* __restrict__ xb, int n16){
  int i = blockIdx.x * blockDim.x + threadIdx.x;
  if (i >= n16) return;
  float4 v = ((const float4*)x)[i];
  ushort4 o;
  o.x = f2bf(v.x); o.y = f2bf(v.y); o.z = f2bf(v.z); o.w = f2bf(v.w);
  ((ushort4*)xb)[i] = o;
}

__global__ void k_bscan(const int* __restrict__ bcount, int* __restrict__ bbase,
                        int* __restrict__ bcursor, int NB){
  __shared__ int sd[MAXNB];
  int tid = threadIdx.x;
  int v = (tid < NB) ? bcount[tid] : 0;
  sd[tid] = v; __syncthreads();
  for (int o = 1; o < MAXNB; o <<= 1){
    int t = (tid >= o) ? sd[tid - o] : 0;
    __syncthreads();
    sd[tid] += t;
    __syncthreads();
  }
  int excl = sd[tid] - v;
  if (tid < NB){ bbase[tid] = excl; bcursor[tid] = excl; }
  if (tid == NB - 1) bbase[NB] = excl + v;
}

__global__ void k_breorder(const int* __restrict__ src, const int* __restrict__ dst,
                           int* __restrict__ bcursor, int2* __restrict__ ebuf, int E, int NB){
  __shared__ int lh[MAXNB];
  __shared__ int lbase[MAXNB];
  int tid = threadIdx.x;
  int c0 = blockIdx.x * RCHUNK;
  for (int b = tid; b < NB; b += 256) lh[b] = 0;
  __syncthreads();
  for (int j = 0; j < RCHUNK / 256; j++){
    int i = c0 + j * 256 + tid;
    if (i < E) atomicAdd(&lh[dst[i] >> 8], 1);
  }
  __syncthreads();
  for (int b = tid; b < NB; b += 256){
    int c = lh[b];
    lbase[b] = c ? atomicAdd(&bcursor[b], c) : 0;
    lh[b] = 0;
  }
  __syncthreads();
  for (int j = 0; j < RCHUNK / 256; j++){
    int i = c0 + j * 256 + tid;
    if (i < E){
      int d = dst[i]; int b = d >> 8;
      int r = atomicAdd(&lh[b], 1);
      ebuf[lbase[b] + r] = make_int2(src[i], d);
    }
  }
}

__global__ void k_bucket_csr(const int2* __restrict__ ebuf, const int* __restrict__ bbase,
                             int* __restrict__ deg, int* __restrict__ offs,
                             int* __restrict__ csr, int N){
  __shared__ int lh[256];
  __shared__ int lsc[256];
  int b = blockIdx.x;
  int lo = b << 8;
  int nn = min(256, N - lo);
  int tid = threadIdx.x;
  lh[tid] = 0; __syncthreads();
  int es = bbase[b], ee = bbase[b + 1];
  for (int i = es + tid; i < ee; i += 256) atomicAdd(&lh[ebuf[i].y - lo], 1);
  __syncthreads();
  int v = lh[tid];
  lsc[tid] = v; __syncthreads();
  for (int o = 1; o < 256; o <<= 1){
    int t = (tid >= o) ? lsc[tid - o] : 0;
    __syncthreads();
    lsc[tid] += t;
    __syncthreads();
  }
  int excl = lsc[tid] - v;
  if (tid < nn){ deg[lo + tid] = v; offs[lo + tid] = es + excl; }
  __syncthreads();
  lh[tid] = es + excl;
  __syncthreads();
  for (int i = es + tid; i < ee; i += 256){
    int2 e = ebuf[i];
    int pos = atomicAdd(&lh[e.y - lo], 1);
    csr[pos] = e.x;
  }
}

__global__ __launch_bounds__(256) void k_agg(
    const unsigned short* __restrict__ Pb, const int* __restrict__ csr,
    const int* __restrict__ offs, const int* __restrict__ deg,
    float* __restrict__ G, int n){
  int tid = threadIdx.x;
  int wave_id = blockIdx.x * 4 + (tid >> 6);
  int lane = tid & 63;
  int sub = lane >> 3, l8 = lane & 7;
  int node = wave_id * 8 + sub;
  bool ok = node < n;
  int st = 0, cnt = 0;
  if (ok){ st = offs[node]; cnt = deg[node]; }
  const uint4* Pv = (const uint4*)Pb;
  float a[8];
  #pragma unroll
  for (int k = 0; k < 8; k++) a[k] = 0.f;
  if (ok) addbf(a, Pv[(size_t)node * 8 + l8]);
  int sbase = sub << 3;
  for (int base = 0; base < cnt; base += 8){
    int rem = cnt - base;
    int s = (l8 < rem) ? csr[st + base + l8] : 0;
    int m = min(rem, 8);
    int j = 0;
    for (; j + 4 <= m; j += 4){
      int s0 = __shfl(s, sbase | j);
      int s1 = __shfl(s, sbase | (j + 1));
      int s2 = __shfl(s, sbase | (j + 2));
      int s3 = __shfl(s, sbase | (j + 3));
      uint4 v0 = Pv[(size_t)s0 * 8 + l8];
      uint4 v1 = Pv[(size_t)s1 * 8 + l8];
      uint4 v2 = Pv[(size_t)s2 * 8 + l8];
      uint4 v3 = Pv[(size_t)s3 * 8 + l8];
      addbf(a, v0); addbf(a, v1); addbf(a, v2); addbf(a, v3);
    }
    for (; j < m; ++j){
      int sj = __shfl(s, sbase | j);
      addbf(a, Pv[(size_t)sj * 8 + l8]);
    }
  }
  if (ok){
    float4* Gp = (float4*)(G + (size_t)node * HDIM + l8 * 8);
    Gp[0] = make_float4(a[0], a[1], a[2], a[3]);
    Gp[1] = make_float4(a[4], a[5], a[6], a[7]);
  }
}

__global__ __launch_bounds__(256, 3) void k_mlp(
    float* __restrict__ G, const int* __restrict__ batch,
    const short* __restrict__ Wall,
    const float* __restrict__ B1, const float* __restrict__ B2,
    float* __restrict__ stats, int N){
  __shared__ short Ws[16384];
  __shared__ short Ah[64 * APITCH];
  __shared__ short Al[64 * APITCH];
  __shared__ float ssum[64], ssq[64];
  int tid = threadIdx.x;

  for (int j = tid; j < 2048; j += 256){
    int p = j >> 9, rem = j & 511, rr = rem >> 3, c8 = rem & 7;
    bf16x8 v = ((const bf16x8*)Wall)[j];
    *(bf16x8*)(Ws + p * 4096 + rr * 64 + ((c8 ^ (rr & 7)) << 3)) = v;
  }

  int wv = tid >> 6, lane = tid & 63;
  int quad = lane >> 4, l15 = lane & 15;
  int rbase = wv << 4;
  int h7 = l15 & 7;
  float bb1[4], bb2[4];
  #pragma unroll
  for (int t = 0; t < 4; t++){ bb1[t] = B1[t * 16 + l15]; bb2[t] = B2[t * 16 + l15]; }

  int tile0 = blockIdx.x << 1;
  float4 r[4], r2[4];
  {
    int tb = tile0 << 6;
    #pragma unroll
    for (int ri = 0; ri < 4; ri++){
      int idx = ri * 256 + tid;
      int node = tb + (idx >> 4), f4 = idx & 15;
      r[ri] = make_float4(0.f, 0.f, 0.f, 0.f);
      if (node < N) r[ri] = ((const float4*)G)[(size_t)node * 16 + f4];
    }
  }

  for (int tt = 0; tt < 2; tt++){
    int t0 = (tile0 + tt) << 6;
    if (t0 >= N) break;

    #pragma unroll
    for (int ri = 0; ri < 4; ri++){
      int idx = ri * 256 + tid;
      int node = idx >> 4, f4 = idx & 15;
      float vv[4] = {r[ri].x, r[ri].y, r[ri].z, r[ri].w};
      short h[4], l[4];
      #pragma unroll
      for (int j = 0; j < 4; j++){
        unsigned short hh = f2bf(vv[j]);
        h[j] = (short)hh;
        l[j] = (short)f2bf(vv[j] - bf2f(hh));
      }
      *(short4*)(Ah + node * APITCH + f4 * 4) = make_short4(h[0], h[1], h[2], h[3]);
      *(short4*)(Al + node * APITCH + f4 * 4) = make_short4(l[0], l[1], l[2], l[3]);
    }
    if (tid < 64){ ssum[tid] = 0.f; ssq[tid] = 0.f; }
    __syncthreads();

    if (tt == 0){
      int tb = (tile0 + 1) << 6;
      #pragma unroll
      for (int ri = 0; ri < 4; ri++){
        int idx = ri * 256 + tid;
        int node = tb + (idx >> 4), f4 = idx & 15;
        r2[ri] = make_float4(0.f, 0.f, 0.f, 0.f);
        if (node < N) r2[ri] = ((const float4*)G)[(size_t)node * 16 + f4];
      }
    }

    f32x4 acc[4];
    #pragma unroll
    for (int t = 0; t < 4; t++) acc[t] = (f32x4){0.f, 0.f, 0.f, 0.f};
    #pragma unroll
    for (int kb = 0; kb < 2; kb++){
      int kk = kb * 32 + quad * 8;
      int swz = ((kb * 4 + quad) ^ h7) << 3;
      bf16x8 a_h = *(const bf16x8*)(Ah + (rbase + l15) * APITCH + kk);
      bf16x8 a_l = *(const bf16x8*)(Al + (rbase + l15) * APITCH + kk);
      #pragma unroll
      for (int t = 0; t < 4; t++){
        int row = t * 16 + l15;
        bf16x8 b_h = *(const bf16x8*)(Ws + row * 64 + swz);
        bf16x8 b_l = *(const bf16x8*)(Ws + 4096 + row * 64 + swz);
        acc[t] = __builtin_amdgcn_mfma_f32_16x16x32_bf16(a_h, b_h, acc[t], 0, 0, 0);
        acc[t] = __builtin_amdgcn_mfma_f32_16x16x32_bf16(a_h, b_l, acc[t], 0, 0, 0);
        acc[t] = __builtin_amdgcn_mfma_f32_16x16x32_bf16(a_l, b_h, acc[t], 0, 0, 0);
      }
    }
    __syncthreads();

    #pragma unroll
    for (int t = 0; t < 4; t++){
      #pragma unroll
      for (int rg = 0; rg < 4; rg++){
        float v = fmaxf(acc[t][rg] + bb1[t], 0.f);
        int row = rbase + quad * 4 + rg;
        int col = t * 16 + l15;
        unsigned short hh = f2bf(v);
        Ah[row * APITCH + col] = (short)hh;
        Al[row * APITCH + col] = (short)f2bf(v - bf2f(hh));
      }
    }
    __syncthreads();

    f32x4 acc2[4];
    #pragma unroll
    for (int t = 0; t < 4; t++) acc2[t] = (f32x4){0.f, 0.f, 0.f, 0.f};
    #pragma unroll
    for (int kb = 0; kb < 2; kb++){
      int kk = kb * 32 + quad * 8;
      int swz = ((kb * 4 + quad) ^ h7) << 3;
      bf16x8 a_h = *(const bf16x8*)(Ah + (rbase + l15) * APITCH + kk);
      bf16x8 a_l = *(const bf16x8*)(Al + (rbase + l15) * APITCH + kk);
      #pragma unroll
      for (int t = 0; t < 4; t++){
        int row = t * 16 + l15;
        bf16x8 b_h = *(const bf16x8*)(Ws + 8192 + row * 64 + swz);
        bf16x8 b_l = *(const bf16x8*)(Ws + 12288 + row * 64 + swz);
        acc2[t] = __builtin_amdgcn_mfma_f32_16x16x32_bf16(a_h, b_h, acc2[t], 0, 0, 0);
        acc2[t] = __builtin_amdgcn_mfma_f32_16x16x32_bf16(a_h, b_l, acc2[t], 0, 0, 0);
        acc2[t] = __builtin_amdgcn_mfma_f32_16x16x32_bf16(a_l, b_h, acc2[t], 0, 0, 0);
      }
    }

    int lastn = min(t0 + 63, N - 1);
    int g0 = batch[t0];
    bool uniform = (batch[lastn] == g0) && (t0 + 63 < N);
    #pragma unroll
    for (int t = 0; t < 4; t++){
      int f = t * 16 + l15;
      float s = 0.f, q = 0.f;
      #pragma unroll
      for (int rg = 0; rg < 4; rg++){
        float v = acc2[t][rg] + bb2[t];
        int node = t0 + rbase + quad * 4 + rg;
        if (node < N) G[(size_t)node * HDIM + f] = v;
        if (uniform){
          s += v; q += v * v;
        } else if (node < N){
          int g = batch[node];
          atomicAdd(&stats[g * 128 + f], v);
          atomicAdd(&stats[g * 128 + 64 + f], v * v);
        }
      }
      if (uniform){
        s += __shfl_xor(s, 16); s += __shfl_xor(s, 32);
        q += __shfl_xor(q, 16); q += __shfl_xor(q, 32);
        if (quad == 0){ atomicAdd(&ssum[f], s); atomicAdd(&ssq[f], q); }
      }
    }
    __syncthreads();
    if (uniform && tid < 64){
      atomicAdd(&stats[g0 * 128 + tid], ssum[tid]);
      atomicAdd(&stats[g0 * 128 + 64 + tid], ssq[tid]);
    }
    #pragma unroll
    for (int ri = 0; ri < 4; ri++) r[ri] = r2[ri];
  }
}

__global__ void k_gn_apply(const float* __restrict__ Y, const int* __restrict__ batch,
                           const float* __restrict__ stats, const int* __restrict__ gs,
                           const float* __restrict__ w, const float* __restrict__ ms,
                           const float* __restrict__ bias,
                           unsigned short* __restrict__ Cb, float* __restrict__ hsum, int n16,
                           int first, int writeC){
  int i = blockIdx.x * blockDim.x + threadIdx.x;
  if (i >= n16) return;
  int node = i >> 4, q = i & 15;
  int g = batch[node];
  float cnt = (float)max(gs[g + 1] - gs[g], 1);
  float4 y  = ((const float4*)Y)[i];
  float4 s1 = ((const float4*)(stats + g * 128))[q];
  float4 s2 = ((const float4*)(stats + g * 128 + 64))[q];
  float4 wv = ((const float4*)w)[q];
  float4 mv = ((const float4*)ms)[q];
  float4 bv = ((const float4*)bias)[q];
  float4 v;
  #define APPLY1(c) { \
    float mean = s1.c / cnt; float ex2 = s2.c / cnt; \
    float var = ex2 - (2.f * mv.c - mv.c * mv.c) * mean * mean; \
    float sc = rsqrtf(var + GN_EPS) * wv.c; \
    v.c = fmaxf((y.c - mv.c * mean) * sc + bv.c, 0.f); }
  APPLY1(x) APPLY1(y) APPLY1(z) APPLY1(w)
  #undef APPLY1
  if (writeC){
    ushort4 o;
    o.x = f2bf(v.x); o.y = f2bf(v.y); o.z = f2bf(v.z); o.w = f2bf(v.w);
    ((ushort4*)Cb)[i] = o;
  }
  if (first){
    ((float4*)hsum)[i] = v;
  } else {
    float4 h = ((float4*)hsum)[i];
    h.x += v.x; h.y += v.y; h.z += v.z; h.w += v.w;
    ((float4*)hsum)[i] = h;
  }
}

#define GN_NPW 32
__global__ void k_pool1(const float* __restrict__ HS, const int* __restrict__ batch,
                        const float* __restrict__ GW, const float* __restrict__ GB,
                        float* __restrict__ sumbuf, unsigned* __restrict__ maxbuf,
                        float* __restrict__ gatebuf, unsigned* __restrict__ gmaxbuf, int n){
  int wave = (int)((blockIdx.x * blockDim.x + threadIdx.x) >> 6);
  int lane = threadIdx.x & 63;
  int s = wave * GN_NPW;
  if (s >= n) return;
  int e = min(s + GN_NPW, n);
  float gwv = GW[lane];
  float gb = GB[0];
  int cur = batch[s];
  float macc = 0.f, xacc = -INFINITY, gmx = -INFINITY;
  for (int nd = s; nd < e; ++nd){
    int g = batch[nd];
    if (g != cur){
      atomicAdd(&sumbuf[cur * 64 + lane], macc);
      atomicMax(&maxbuf[cur * 64 + lane], fenc(xacc));
      if (lane == 0) atomicMax(&gmaxbuf[cur], fenc(gmx));
      macc = 0.f; xacc = -INFINITY; gmx = -INFINITY; cur = g;
    }
    float hv = HS[(size_t)nd * HDIM + lane];
    macc += hv; xacc = fmaxf(xacc, hv);
    float gv = hv * gwv;
    #pragma unroll
    for (int msk = 1; msk < 64; msk <<= 1) gv += __shfl_xor(gv, msk);
    gv += gb;
    if (lane == 0) gatebuf[nd] = gv;
    gmx = fmaxf(gmx, gv);
  }
  atomicAdd(&sumbuf[cur * 64 + lane], macc);
  atomicMax(&maxbuf[cur * 64 + lane], fenc(xacc));
  if (lane == 0) atomicMax(&gmaxbuf[cur], fenc(gmx));
}

__global__ void k_pool2(const float* __restrict__ HS, const int* __restrict__ batch,
                        const float* __restrict__ gatebuf, const unsigned* __restrict__ gmaxbuf,
                        float* __restrict__ attbuf, float* __restrict__ denbuf, int n){
  int wave = (int)((blockIdx.x * blockDim.x + threadIdx.x) >> 6);
  int lane = threadIdx.x & 63;
  int s = wave * GN_NPW;
  if (s >= n) return;
  int e = min(s + GN_NPW, n);
  int cur = batch[s];
  float m = fdec(gmaxbuf[cur]);
  float aacc = 0.f, dacc = 0.f;
  for (int nd = s; nd < e; ++nd){
    int g = batch[nd];
    if (g != cur){
      atomicAdd(&attbuf[cur * 64 + lane], aacc);
      if (lane == 0) atomicAdd(&denbuf[cur], dacc);
      aacc = 0.f; dacc = 0.f; cur = g; m = fdec(gmaxbuf[cur]);
    }
    float ex = expf(gatebuf[nd] - m);
    float hv = HS[(size_t)nd * HDIM + lane];
    aacc += ex * hv; dacc += ex;
  }
  atomicAdd(&attbuf[cur * 64 + lane], aacc);
  if (lane == 0) atomicAdd(&denbuf[cur], dacc);
}

__global__ void k_pool3(const float* __restrict__ attbuf, const float* __restrict__ denbuf,
                        const float* __restrict__ sumbuf, const unsigned* __restrict__ maxbuf,
                        const int* __restrict__ gs, const float* __restrict__ U,
                        const float* __restrict__ HW1, const float* __restrict__ HB1,
                        const float* __restrict__ HW2, const float* __restrict__ HB2,
                        float* __restrict__ out){
  __shared__ float z[200];
  int g = blockIdx.x;
  int tid = threadIdx.x;
  float cnt = (float)max(gs[g + 1] - gs[g], 1);
  float den = denbuf[g];
  z[tid]       = attbuf[g * 64 + tid] / den;
  z[64 + tid]  = sumbuf[g * 64 + tid] / cnt;
  z[128 + tid] = fdec(maxbuf[g * 64 + tid]);
  if (tid < 3) z[192 + tid] = U[g * 3 + tid];
  __syncthreads();
  float acc = HB1[tid];
  for (int k = 0; k < 195; k++) acc += z[k] * HW1[k * 64 + tid];
  float sv = fmaxf(acc, 0.f) * HW2[tid];
  #pragma unroll
  for (int msk = 1; msk < 64; msk <<= 1) sv += __shfl_xor(sv, msk);
  if (tid == 0) out[g] = sv + HB2[0];
}

extern "C" void kernel_launch(void* const* d_in, const int* in_sizes, int n_in,
                              void* d_out, int out_size, void* d_ws, size_t ws_size,
                              hipStream_t stream){
  const float* x     = (const float*)d_in[0];
  const int*   ei    = (const int*)d_in[1];
  const int*   batch = (const int*)d_in[2];
  const float* u     = (const float*)d_in[3];
  const float* W[3][4]; const float* GNp[3][3];
  for (int l = 0; l < 3; l++){
    int base = 4 + l * 7;
    W[l][0]  = (const float*)d_in[base + 0];
    W[l][1]  = (const float*)d_in[base + 1];
    W[l][2]  = (const float*)d_in[base + 2];
    W[l][3]  = (const float*)d_in[base + 3];
    GNp[l][0]= (const float*)d_in[base + 4];
    GNp[l][1]= (const float*)d_in[base + 5];
    GNp[l][2]= (const float*)d_in[base + 6];
  }
  const float* gate_w = (const float*)d_in[25];
  const float* gate_b = (const float*)d_in[26];
  const float* hw1    = (const float*)d_in[27];
  const float* hb1    = (const float*)d_in[28];
  const float* hw2    = (const float*)d_in[29];
  const float* hb2    = (const float*)d_in[30];
  float* out = (float*)d_out;

  int N = in_sizes[0] / HDIM;
  int E = in_sizes[1] / 2;
  int B = in_sizes[3] / 3;
  const int* src = ei;
  const int* dst = ei + E;
  int NB = (N + 255) >> 8;
  int n16 = N * 16;

  char* w8 = (char*)d_ws;
  size_t NH = (size_t)N * HDIM * sizeof(float);
  size_t NHb = (size_t)N * HDIM * sizeof(short);
  auto alignup = [](size_t v){ return (v + 255) & ~(size_t)255; };
  size_t off = 0;
  float* hsum    = (float*)(w8 + off); off += alignup(NH);
  float* G       = (float*)(w8 + off); off += alignup(NH);
  unsigned short* xb   = (unsigned short*)(w8 + off); off += alignup(NHb);
  unsigned short* bufA = (unsigned short*)(w8 + off); off += alignup(NHb);
  unsigned short* bufB = (unsigned short*)(w8 + off); off += alignup(NHb);
  float* gatebuf = (float*)(w8 + off); off += alignup((size_t)N * 4);
  int*   deg     = (int*)(w8 + off);   off += alignup((size_t)N * 4);
  int*   offs    = (int*)(w8 + off);   off += alignup((size_t)N * 4);
  int*   csr     = (int*)(w8 + off);   off += alignup((size_t)E * 4);
  int2*  ebuf    = (int2*)(w8 + off);  off += alignup((size_t)E * 8);
  int*   bcount  = (int*)(w8 + off);   off += alignup((size_t)(MAXNB + 1) * 4);
  int*   bbase   = (int*)(w8 + off);   off += alignup((size_t)(MAXNB + 1) * 4);
  int*   bcursor = (int*)(w8 + off);   off += alignup((size_t)(MAXNB + 1) * 4);
  float* stats   = (float*)(w8 + off); off += alignup((size_t)3 * B * 128 * 4);
  float* poolz   = (float*)(w8 + off);
  int poolzN = B * 64 * 3 + 2 * B;
  off += alignup((size_t)poolzN * 4);
  float*    sumbuf  = poolz;
  unsigned* maxbuf  = (unsigned*)(poolz + (size_t)B * 64);
  float*    attbuf  = poolz + (size_t)2 * B * 64;
  float*    denbuf  = poolz + (size_t)3 * B * 64;
  unsigned* gmaxbuf = (unsigned*)(poolz + (size_t)3 * B * 64 + B);
  int*   gs      = (int*)(w8 + off);   off += alignup((size_t)(B + 1) * 4);
  short* wbf     = (short*)(w8 + off); off += alignup((size_t)6 * 8192 * 2);
  (void)ws_size; (void)n_in; (void)out_size;

  // ---- decide cooperative viability from queries (no trial launches) ----
  int dev = 0; hipGetDevice(&dev);
  int coopAttr = 0, nCU = 0;
  hipDeviceGetAttribute(&coopAttr, hipDeviceAttributeCooperativeLaunch, dev);
  hipDeviceGetAttribute(&nCU, hipDeviceAttributeMultiprocessorCount, dev);
  int mbB = 0, mbT = 0;
  hipOccupancyMaxActiveBlocksPerMultiprocessor(&mbB, k_build, 256, 0);
  hipOccupancyMaxActiveBlocksPerMultiprocessor(&mbT, k_trunk, 256, 0);
  bool coop = coopAttr && nCU > 0 && mbB >= 1 && mbT >= 3 &&
              (long)mbT * nCU >= (long)B && (long)mbB * nCU >= 8;

  bool done = false;
  if (coop){
    BuildArgs ba;
    ba.src = src; ba.dst = dst; ba.E = E; ba.NB = NB;
    ba.W0 = W[0][0]; ba.W1 = W[0][2]; ba.W2 = W[1][0];
    ba.W3 = W[1][2]; ba.W4 = W[2][0]; ba.W5 = W[2][2];
    ba.wbf = wbf;
    ba.batch = batch; ba.N = N; ba.gs = gs; ba.B = B;
    ba.bcount = bcount; ba.bbase = bbase; ba.bcursor = bcursor;
    ba.ebuf = ebuf; ba.deg = deg; ba.offs = offs; ba.csr = csr;
    ba.x = x; ba.xb = xb; ba.n16 = n16;
    ba.stats = stats; ba.statsN = 3 * B * 128; ba.poolz = poolz; ba.poolzN = poolzN;

    TrunkArgs ta;
    ta.xb = xb; ta.bufA = bufA; ta.bufB = bufB; ta.G = G; ta.hsum = hsum;
    ta.csr = csr; ta.offs = offs; ta.deg = deg; ta.batch = batch; ta.gs = gs;
    ta.wbf = wbf;
    ta.B1a = W[0][1]; ta.B1b = W[1][1]; ta.B1c = W[2][1];
    ta.B2a = W[0][3]; ta.B2b = W[1][3]; ta.B2c = W[2][3];
    ta.gnw0 = GNp[0][0]; ta.gnw1 = GNp[1][0]; ta.gnw2 = GNp[2][0];
    ta.gnb0 = GNp[0][1]; ta.gnb1 = GNp[1][1]; ta.gnb2 = GNp[2][1];
    ta.gnm0 = GNp[0][2]; ta.gnm1 = GNp[1][2]; ta.gnm2 = GNp[2][2];
    ta.stats = stats; ta.N = N; ta.n16 = n16; ta.B = B;
    ta.gw = gate_w; ta.gb = gate_b; ta.u = u;
    ta.hw1 = hw1; ta.hb1 = hb1; ta.hw2 = hw2; ta.hb2 = hb2;
    ta.sumbuf = sumbuf; ta.maxbuf = maxbuf; ta.attbuf = attbuf;
    ta.denbuf = denbuf; ta.gmaxbuf = gmaxbuf;
    ta.gatebuf = gatebuf; ta.out = out;

    int gridB = mbB * nCU; if (gridB > 1024) gridB = 1024;
    int gridT = mbT * nCU; if (gridT > 1024) gridT = 1024;
    void* bp[] = { &ba };
    void* tp[] = { &ta };
    hipError_t e = hipLaunchCooperativeKernel((const void*)k_build, dim3(gridB), dim3(256),
                                              bp, 0, stream);
    if (e == hipSuccess)
      e = hipLaunchCooperativeKernel((const void*)k_trunk, dim3(gridT), dim3(256),
                                     tp, 0, stream);
    done = (e == hipSuccess);
  }

  if (!done){
    // -------- standard fallback path (R9 structure) --------
    hipMemsetAsync(stats, 0, (size_t)3 * B * 128 * 4, stream);
    hipMemsetAsync(poolz, 0, (size_t)poolzN * 4, stream);
    hipMemsetAsync(bcount, 0, (size_t)(MAXNB + 1) * 4, stream);

    const int tb = 256;
    k_prep<<<263, tb, 0, stream>>>(dst, bcount, E, NB,
                                   W[0][0], W[0][2], W[1][0], W[1][2], W[2][0], W[2][2],
                                   wbf, batch, N, gs, B);
    k_cvt<<<(n16 + tb - 1) / tb, tb, 0, stream>>>(x, xb, n16);
    k_bscan<<<1, MAXNB, 0, stream>>>(bcount, bbase, bcursor, NB);
    k_breorder<<<(E + RCHUNK - 1) / RCHUNK, tb, 0, stream>>>(src, dst, bcursor, ebuf, E, NB);
    k_bucket_csr<<<NB, tb, 0, stream>>>(ebuf, bbase, deg, offs, csr, N);

    int nwaves = (N + GN_NPW - 1) / GN_NPW;
    int segblocks = (nwaves * 64 + tb - 1) / tb;
    int nblk64 = (N + 63) >> 6;
    int nblk2 = (nblk64 + 1) >> 1;
    int aggwaves = (N + 7) >> 3;
    int aggblocks = (aggwaves + 3) >> 2;

    const unsigned short* P = xb;
    unsigned short* C = bufA;
    for (int l = 0; l < 3; l++){
      k_agg<<<aggblocks, 256, 0, stream>>>(P, csr, offs, deg, G, N);
      float* lstats = stats + (size_t)l * B * 128;
      k_mlp<<<nblk2, 256, 0, stream>>>(G, batch, wbf + (size_t)l * 16384,
                                       W[l][1], W[l][3], lstats, N);
      k_gn_apply<<<(n16 + tb - 1) / tb, tb, 0, stream>>>(G, batch, lstats, gs,
                                                         GNp[l][0], GNp[l][2], GNp[l][1],
                                                         C, hsum, n16, l == 0 ? 1 : 0,
                                                         l == 2 ? 0 : 1);
      P = C;
      C = (l == 0) ? bufB : bufA;
    }
    k_pool1<<<segblocks, tb, 0, stream>>>(hsum, batch, gate_w, gate_b,
                                          sumbuf, maxbuf, gatebuf, gmaxbuf, N);
    k_pool2<<<segblocks, tb, 0, stream>>>(hsum, batch, gatebuf, gmaxbuf, attbuf, denbuf, N);
    k_pool3<<<B, 64, 0, stream>>>(attbuf, denbuf, sumbuf, maxbuf, gs, u,
                                  hw1, hb1, hw2, hb2, out);
  }
}